// Round 1
// baseline (7224.896 us; speedup 1.0000x reference)
//
#include <hip/hip_runtime.h>

// ChebConv K=6, sym norm, lambda_max=2 => L_hat = -D^{-1/2} A D^{-1/2}
// N=100000, E=1600000, F=64.
// Pipeline: deg -> dinv -> w[e] ; Tx0=x ; Tx1=prop(x) ; Txk = 2*prop(Tx_{k-1}) - Tx_{k-2}
// out = relu(b + sum_k Txk @ W[k]), accumulated directly into d_out.

constexpr int F = 64;

__global__ void deg_kernel(const int* __restrict__ row, float* __restrict__ deg, int E) {
    int e = blockIdx.x * blockDim.x + threadIdx.x;
    if (e < E) atomicAdd(&deg[row[e]], 1.0f);
}

__global__ void dinv_kernel(float* __restrict__ deg, int N) {
    int i = blockIdx.x * blockDim.x + threadIdx.x;
    if (i < N) {
        float d = deg[i];
        deg[i] = d > 0.0f ? rsqrtf(d) : 0.0f;
    }
}

__global__ void w_kernel(const int* __restrict__ row, const int* __restrict__ col,
                         const float* __restrict__ dinv, float* __restrict__ w, int E) {
    int e = blockIdx.x * blockDim.x + threadIdx.x;
    if (e < E) w[e] = -dinv[row[e]] * dinv[col[e]];
}

// dst = -src (dst may alias src)
__global__ void neg_kernel(float4* __restrict__ dst, const float4* __restrict__ src, int n4) {
    int i = blockIdx.x * blockDim.x + threadIdx.x;
    if (i < n4) {
        float4 v = src[i];
        dst[i] = make_float4(-v.x, -v.y, -v.z, -v.w);
    }
}

// dst[col[e], :] += scale * w[e] * h[row[e], :]   (16 lanes per edge, float4 each)
__global__ void scatter_kernel(const int* __restrict__ row, const int* __restrict__ col,
                               const float* __restrict__ w, const float* __restrict__ h,
                               float* __restrict__ dst, float scale, int E) {
    int idx = blockIdx.x * blockDim.x + threadIdx.x;
    int e = idx >> 4;
    if (e >= E) return;
    int f = (idx & 15) * 4;
    int r = row[e], c = col[e];
    float we = w[e] * scale;
    const float4 hv = *(const float4*)(h + (size_t)r * F + f);
    float* d = dst + (size_t)c * F + f;
    atomicAdd(d + 0, we * hv.x);
    atomicAdd(d + 1, we * hv.y);
    atomicAdd(d + 2, we * hv.z);
    atomicAdd(d + 3, we * hv.w);
}

// acc[n, lane] (+)= sum_i h[n,i] * Wk[i,lane]  (+ b[lane] when init)
// One wave per node-row; W (64x64) staged in LDS; row broadcast via shfl.
template <int NPB>
__global__ void gemm_kernel(const float* __restrict__ h, const float* __restrict__ Wk,
                            const float* __restrict__ b, float* __restrict__ acc,
                            int N, int init) {
    __shared__ float Ws[F * F];
    for (int t = threadIdx.x; t < F * F; t += blockDim.x) Ws[t] = Wk[t];
    __syncthreads();
    int wave = threadIdx.x >> 6, lane = threadIdx.x & 63;
    int base = blockIdx.x * NPB;
    int end = base + NPB < N ? base + NPB : N;
    for (int n = base + wave; n < end; n += 4) {
        float xl = h[(size_t)n * F + lane];
        float s0 = 0.f, s1 = 0.f, s2 = 0.f, s3 = 0.f;
#pragma unroll
        for (int i = 0; i < F; i += 4) {
            s0 += __shfl(xl, i + 0) * Ws[(i + 0) * F + lane];
            s1 += __shfl(xl, i + 1) * Ws[(i + 1) * F + lane];
            s2 += __shfl(xl, i + 2) * Ws[(i + 2) * F + lane];
            s3 += __shfl(xl, i + 3) * Ws[(i + 3) * F + lane];
        }
        float s = (s0 + s1) + (s2 + s3);
        size_t o = (size_t)n * F + lane;
        if (init) acc[o] = s + b[lane];
        else acc[o] += s;
    }
}

__global__ void relu_kernel(float4* __restrict__ out, int n4) {
    int i = blockIdx.x * blockDim.x + threadIdx.x;
    if (i < n4) {
        float4 v = out[i];
        v.x = fmaxf(v.x, 0.f);
        v.y = fmaxf(v.y, 0.f);
        v.z = fmaxf(v.z, 0.f);
        v.w = fmaxf(v.w, 0.f);
        out[i] = v;
    }
}

extern "C" void kernel_launch(void* const* d_in, const int* in_sizes, int n_in,
                              void* d_out, int out_size, void* d_ws, size_t ws_size,
                              hipStream_t stream) {
    const float* x = (const float*)d_in[0];
    const int* ei = (const int*)d_in[1];
    const float* W = (const float*)d_in[2];
    const float* b = (const float*)d_in[3];

    const int N = in_sizes[0] / F;
    const int E = in_sizes[1] / 2;
    const int K = in_sizes[2] / (F * F);
    const int* row = ei;       // sources j
    const int* col = ei + E;   // targets i

    float* deg  = (float*)d_ws;                 // N
    float* w    = deg + N;                      // E
    float* bufA = w + E;                        // N*F
    float* bufB = bufA + (size_t)N * F;         // N*F
    float* acc  = (float*)d_out;                // N*F

    const int n4 = N * F / 4;
    const int B = 256;

    // edge weights
    hipMemsetAsync(deg, 0, (size_t)N * sizeof(float), stream);
    deg_kernel<<<(E + B - 1) / B, B, 0, stream>>>(row, deg, E);
    dinv_kernel<<<(N + B - 1) / B, B, 0, stream>>>(deg, N);
    w_kernel<<<(E + B - 1) / B, B, 0, stream>>>(row, col, deg, w, E);

    const int ggrid = (N + 63) / 64;
    const int sgrid = (E * 16 + B - 1) / B;

    // k = 0: acc = b + x @ W0
    gemm_kernel<64><<<ggrid, B, 0, stream>>>(x, W, b, acc, N, 1);

    // k = 1: Tx1 = prop(x)
    hipMemsetAsync(bufA, 0, (size_t)N * F * sizeof(float), stream);
    scatter_kernel<<<sgrid, B, 0, stream>>>(row, col, w, x, bufA, 1.0f, E);
    gemm_kernel<64><<<ggrid, B, 0, stream>>>(bufA, W + F * F, b, acc, N, 0);

    // k >= 2: Tx_k = 2*prop(Tx_{k-1}) - Tx_{k-2}, written over Tx_{k-2}'s buffer
    const float* Tm2 = x;
    float* Tm1 = bufA;
    for (int k = 2; k < K; ++k) {
        float* dst = (k == 2) ? bufB : (float*)Tm2;
        neg_kernel<<<(n4 + B - 1) / B, B, 0, stream>>>((float4*)dst, (const float4*)Tm2, n4);
        scatter_kernel<<<sgrid, B, 0, stream>>>(row, col, w, Tm1, dst, 2.0f, E);
        gemm_kernel<64><<<ggrid, B, 0, stream>>>(dst, W + (size_t)k * F * F, b, acc, N, 0);
        Tm2 = Tm1;
        Tm1 = dst;
    }

    relu_kernel<<<(n4 + B - 1) / B, B, 0, stream>>>((float4*)acc, n4);
}

// Round 2
// 1735.633 us; speedup vs baseline: 4.1627x; 4.1627x over previous
//
#include <hip/hip_runtime.h>

// ChebConv K=6, sym norm, lambda_max=2 => L_hat = -D^{-1/2} A D^{-1/2}
// N=100000, E=1600000, F=64.
// R2: pull-based propagation over device-built CSR (counting sort by dst).
// No float atomics. GEMM (shfl-broadcast) + recurrence + bias + relu fused
// into the prop kernels. w_e = -dinv[src]*dinv[dst] computed on the fly.

constexpr int F = 64;

// out-degree (float, for dinv) from row; in-degree counts (int) from col
__global__ void deg_cnt_kernel(const int* __restrict__ row, const int* __restrict__ col,
                               float* __restrict__ deg, int* __restrict__ cnt, int E) {
    int e = blockIdx.x * blockDim.x + threadIdx.x;
    if (e < E) {
        atomicAdd(&deg[row[e]], 1.0f);
        atomicAdd(&cnt[col[e]], 1);
    }
}

__global__ void dinv_kernel(float* __restrict__ deg, int N) {
    int i = blockIdx.x * blockDim.x + threadIdx.x;
    if (i < N) {
        float d = deg[i];
        deg[i] = d > 0.0f ? rsqrtf(d) : 0.0f;
    }
}

// single-block exclusive scan of cnt[0..N) -> rowptr[0..N], cursor copy
__global__ void scan_kernel(const int* __restrict__ cnt, int* __restrict__ rowptr,
                            int* __restrict__ cursor, int N) {
    __shared__ int partial[1024];
    const int tid = threadIdx.x;
    const int chunk = (N + 1023) / 1024;
    const int begin = tid * chunk;
    const int end = (begin + chunk < N) ? begin + chunk : N;
    int sum = 0;
    for (int i = begin; i < end; ++i) sum += cnt[i];
    partial[tid] = sum;
    __syncthreads();
    for (int off = 1; off < 1024; off <<= 1) {
        int v = (tid >= off) ? partial[tid - off] : 0;
        __syncthreads();
        partial[tid] += v;
        __syncthreads();
    }
    int run = (tid == 0) ? 0 : partial[tid - 1];
    for (int i = begin; i < end; ++i) {
        rowptr[i] = run;
        cursor[i] = run;
        run += cnt[i];
    }
    if (end == N) rowptr[N] = run;  // == E (all qualifying threads write same value)
}

// counting-sort fill: csr_src grouped by destination
__global__ void fill_kernel(const int* __restrict__ row, const int* __restrict__ col,
                            int* __restrict__ cursor, int* __restrict__ csr_src, int E) {
    int e = blockIdx.x * blockDim.x + threadIdx.x;
    if (e < E) {
        int pos = atomicAdd(&cursor[col[e]], 1);
        csr_src[pos] = row[e];
    }
}

// k0+k1 fused: Tx1 = prop(x) -> dst; out = b + x@W0 + Tx1@W1
template <int WPB>
__global__ void prop_first_kernel(const int* __restrict__ rowptr, const int* __restrict__ csr_src,
                                  const float* __restrict__ dinv, const float* __restrict__ x,
                                  float* __restrict__ dst, const float* __restrict__ W01,
                                  const float* __restrict__ b, float* __restrict__ out, int N) {
    __shared__ float Ws[2 * F * F];
    for (int t = threadIdx.x; t < 2 * F * F; t += blockDim.x) Ws[t] = W01[t];
    __syncthreads();
    const int lane = threadIdx.x & 63;
    const int n = blockIdx.x * WPB + (threadIdx.x >> 6);
    if (n >= N) return;
    const int s = rowptr[n], e = rowptr[n + 1];
    float acc = 0.f;
    int i = s;
    for (; i + 1 < e; i += 2) {
        int s0 = csr_src[i], s1 = csr_src[i + 1];
        float a0 = dinv[s0] * x[(size_t)s0 * F + lane];
        float a1 = dinv[s1] * x[(size_t)s1 * F + lane];
        acc += a0 + a1;
    }
    if (i < e) acc += dinv[csr_src[i]] * x[(size_t)csr_src[i] * F + lane];
    const float t1 = -dinv[n] * acc;  // Tx1 row element
    const size_t o = (size_t)n * F + lane;
    dst[o] = t1;
    const float x0 = x[o];  // Tx0 row element
    float s0 = b[lane], s1 = 0.f, s2 = 0.f, s3 = 0.f;
#pragma unroll
    for (int j = 0; j < F; j += 4) {
        s0 += __shfl(x0, j + 0) * Ws[(j + 0) * F + lane];
        s1 += __shfl(x0, j + 1) * Ws[(j + 1) * F + lane];
        s2 += __shfl(x0, j + 2) * Ws[(j + 2) * F + lane];
        s3 += __shfl(x0, j + 3) * Ws[(j + 3) * F + lane];
    }
#pragma unroll
    for (int j = 0; j < F; j += 4) {
        s0 += __shfl(t1, j + 0) * Ws[F * F + (j + 0) * F + lane];
        s1 += __shfl(t1, j + 1) * Ws[F * F + (j + 1) * F + lane];
        s2 += __shfl(t1, j + 2) * Ws[F * F + (j + 2) * F + lane];
        s3 += __shfl(t1, j + 3) * Ws[F * F + (j + 3) * F + lane];
    }
    out[o] = (s0 + s1) + (s2 + s3);
}

// k>=2: t = 2*prop(h) - prev -> dst (dst may alias prev); out += t@Wk; optional relu
template <int WPB>
__global__ void prop_step_kernel(const int* __restrict__ rowptr, const int* __restrict__ csr_src,
                                 const float* __restrict__ dinv, const float* __restrict__ h,
                                 const float* __restrict__ prev, float* __restrict__ dst,
                                 const float* __restrict__ Wk, float* __restrict__ out,
                                 int N, int final_relu) {
    __shared__ float Ws[F * F];
    for (int t = threadIdx.x; t < F * F; t += blockDim.x) Ws[t] = Wk[t];
    __syncthreads();
    const int lane = threadIdx.x & 63;
    const int n = blockIdx.x * WPB + (threadIdx.x >> 6);
    if (n >= N) return;
    const int s = rowptr[n], e = rowptr[n + 1];
    float acc = 0.f;
    int i = s;
    for (; i + 1 < e; i += 2) {
        int s0 = csr_src[i], s1 = csr_src[i + 1];
        float a0 = dinv[s0] * h[(size_t)s0 * F + lane];
        float a1 = dinv[s1] * h[(size_t)s1 * F + lane];
        acc += a0 + a1;
    }
    if (i < e) acc += dinv[csr_src[i]] * h[(size_t)csr_src[i] * F + lane];
    const size_t o = (size_t)n * F + lane;
    const float t = -2.0f * dinv[n] * acc - prev[o];
    dst[o] = t;
    float s0 = 0.f, s1 = 0.f, s2 = 0.f, s3 = 0.f;
#pragma unroll
    for (int j = 0; j < F; j += 4) {
        s0 += __shfl(t, j + 0) * Ws[(j + 0) * F + lane];
        s1 += __shfl(t, j + 1) * Ws[(j + 1) * F + lane];
        s2 += __shfl(t, j + 2) * Ws[(j + 2) * F + lane];
        s3 += __shfl(t, j + 3) * Ws[(j + 3) * F + lane];
    }
    float r = out[o] + (s0 + s1) + (s2 + s3);
    if (final_relu) r = fmaxf(r, 0.f);
    out[o] = r;
}

extern "C" void kernel_launch(void* const* d_in, const int* in_sizes, int n_in,
                              void* d_out, int out_size, void* d_ws, size_t ws_size,
                              hipStream_t stream) {
    const float* x = (const float*)d_in[0];
    const int* ei = (const int*)d_in[1];
    const float* W = (const float*)d_in[2];
    const float* b = (const float*)d_in[3];

    const int N = in_sizes[0] / F;
    const int E = in_sizes[1] / 2;
    const int* row = ei;      // sources j
    const int* col = ei + E;  // targets i

    // workspace layout
    float* deg    = (float*)d_ws;              // N (becomes dinv)
    int*   cnt    = (int*)(deg + N);           // N
    int*   rowptr = cnt + N;                   // N+1
    int*   cursor = rowptr + N + 1;            // N
    int*   csr    = cursor + N;                // E
    float* bufA   = (float*)(csr + E);         // N*F
    float* bufB   = bufA + (size_t)N * F;      // N*F
    float* out    = (float*)d_out;             // N*F

    const int B = 256;
    constexpr int WPB = 4;  // waves per block
    const int pgrid = (N + WPB - 1) / WPB;

    // build dinv + CSR (counting sort by destination)
    hipMemsetAsync(deg, 0, (size_t)2 * N * sizeof(float), stream);  // deg + cnt
    deg_cnt_kernel<<<(E + B - 1) / B, B, 0, stream>>>(row, col, deg, cnt, E);
    dinv_kernel<<<(N + B - 1) / B, B, 0, stream>>>(deg, N);
    scan_kernel<<<1, 1024, 0, stream>>>(cnt, rowptr, cursor, N);
    fill_kernel<<<(E + B - 1) / B, B, 0, stream>>>(row, col, cursor, csr, E);

    // k=0,1 fused: out = b + x@W0 + Tx1@W1, Tx1 -> bufA
    prop_first_kernel<WPB><<<pgrid, WPB * 64, 0, stream>>>(rowptr, csr, deg, x, bufA, W, b, out, N);
    // k=2: Tx2 = 2*prop(Tx1) - x -> bufB
    prop_step_kernel<WPB><<<pgrid, WPB * 64, 0, stream>>>(rowptr, csr, deg, bufA, x, bufB,
                                                          W + 2 * F * F, out, N, 0);
    // k=3: Tx3 = 2*prop(Tx2) - Tx1 -> bufA (in-place over prev is safe)
    prop_step_kernel<WPB><<<pgrid, WPB * 64, 0, stream>>>(rowptr, csr, deg, bufB, bufA, bufA,
                                                          W + 3 * F * F, out, N, 0);
    // k=4: Tx4 = 2*prop(Tx3) - Tx2 -> bufB
    prop_step_kernel<WPB><<<pgrid, WPB * 64, 0, stream>>>(rowptr, csr, deg, bufA, bufB, bufB,
                                                          W + 4 * F * F, out, N, 0);
    // k=5: Tx5 = 2*prop(Tx4) - Tx3 -> bufA, + relu
    prop_step_kernel<WPB><<<pgrid, WPB * 64, 0, stream>>>(rowptr, csr, deg, bufB, bufA, bufA,
                                                          W + 5 * F * F, out, N, 1);
}

// Round 3
// 1541.858 us; speedup vs baseline: 4.6858x; 1.1257x over previous
//
#include <hip/hip_runtime.h>

// ChebConv K=6, sym norm, lambda_max=2 => L_hat = -D^{-1/2} A D^{-1/2}
// N=100000, E=1600000, F=64.
// R3: recurrence kept in pre-scaled space S_k = dinv (.) Tx_k:
//   S_k = -2*dinv^2 * sum_in S_{k-1}[src] - S_{k-2}   (in-place ping-pong)
//   Tx_k (for the fused GEMM) = S_k * rdinv, rdinv = sqrt(deg)
// -> single random 256B gather per edge, index prefetch via lane-cooperative
//    coalesced loads + __shfl broadcast, 4 gathers in flight.

constexpr int F = 64;

__global__ void deg_cnt_kernel(const int* __restrict__ row, const int* __restrict__ col,
                               float* __restrict__ deg, int* __restrict__ cnt, int E) {
    int e = blockIdx.x * blockDim.x + threadIdx.x;
    if (e < E) {
        atomicAdd(&deg[row[e]], 1.0f);
        atomicAdd(&cnt[col[e]], 1);
    }
}

// deg -> dinv, dinv^2, rdinv
__global__ void dinv_kernel(const float* __restrict__ deg, float* __restrict__ dinv,
                            float* __restrict__ dinv2, float* __restrict__ rdinv, int N) {
    int i = blockIdx.x * blockDim.x + threadIdx.x;
    if (i < N) {
        float d = deg[i];
        bool ok = d > 0.0f;
        dinv[i]  = ok ? rsqrtf(d) : 0.0f;
        dinv2[i] = ok ? 1.0f / d : 0.0f;
        rdinv[i] = ok ? sqrtf(d) : 0.0f;
    }
}

// single-block exclusive scan of cnt[0..N) -> rowptr[0..N], cursor copy
__global__ void scan_kernel(const int* __restrict__ cnt, int* __restrict__ rowptr,
                            int* __restrict__ cursor, int N) {
    __shared__ int partial[1024];
    const int tid = threadIdx.x;
    const int chunk = (N + 1023) / 1024;
    const int begin = tid * chunk;
    const int end = (begin + chunk < N) ? begin + chunk : N;
    int sum = 0;
    for (int i = begin; i < end; ++i) sum += cnt[i];
    partial[tid] = sum;
    __syncthreads();
    for (int off = 1; off < 1024; off <<= 1) {
        int v = (tid >= off) ? partial[tid - off] : 0;
        __syncthreads();
        partial[tid] += v;
        __syncthreads();
    }
    int run = (tid == 0) ? 0 : partial[tid - 1];
    for (int i = begin; i < end; ++i) {
        rowptr[i] = run;
        cursor[i] = run;
        run += cnt[i];
    }
    if (end == N) rowptr[N] = run;
}

__global__ void fill_kernel(const int* __restrict__ row, const int* __restrict__ col,
                            int* __restrict__ cursor, int* __restrict__ csr_src, int E) {
    int e = blockIdx.x * blockDim.x + threadIdx.x;
    if (e < E) {
        int pos = atomicAdd(&cursor[col[e]], 1);
        csr_src[pos] = row[e];
    }
}

// S0 = dinv (.) x
__global__ void sx_kernel(const float* __restrict__ dinv, const float* __restrict__ x,
                          float* __restrict__ S0, int NF) {
    int i = blockIdx.x * blockDim.x + threadIdx.x;
    if (i < NF) S0[i] = dinv[i >> 6] * x[i];
}

// gather sum over in-edges: u[lane] = sum S[src, lane]
__device__ __forceinline__ float gather_sum(const int* __restrict__ csr, int s, int e,
                                            const float* __restrict__ Sl, int lane) {
    float a0 = 0.f, a1 = 0.f, a2 = 0.f, a3 = 0.f;
    for (int base = s; base < e; base += 64) {
        int m = e - base;
        if (m > 64) m = 64;
        int idx = (base + lane < e) ? csr[base + lane] : 0;
        int j = 0;
        for (; j + 3 < m; j += 4) {
            int i0 = __shfl(idx, j), i1 = __shfl(idx, j + 1);
            int i2 = __shfl(idx, j + 2), i3 = __shfl(idx, j + 3);
            a0 += Sl[(size_t)i0 * F];
            a1 += Sl[(size_t)i1 * F];
            a2 += Sl[(size_t)i2 * F];
            a3 += Sl[(size_t)i3 * F];
        }
        for (; j < m; ++j) a0 += Sl[(size_t)__shfl(idx, j) * F];
    }
    return (a0 + a1) + (a2 + a3);
}

// k0+k1 fused: S1 = -dinv^2 * gather(S0); out = b + x@W0 + Tx1@W1, Tx1 = S1*rdinv
template <int WPB>
__global__ void prop_first_kernel(const int* __restrict__ rowptr, const int* __restrict__ csr,
                                  const float* __restrict__ dinv, const float* __restrict__ x,
                                  const float* __restrict__ S0, float* __restrict__ S1,
                                  const float* __restrict__ W01, const float* __restrict__ b,
                                  float* __restrict__ out, int N) {
    __shared__ float Ws[2 * F * F];
    for (int t = threadIdx.x; t < 2 * F * F; t += blockDim.x) Ws[t] = W01[t];
    __syncthreads();
    const int lane = threadIdx.x & 63;
    const int n = blockIdx.x * WPB + (threadIdx.x >> 6);
    if (n >= N) return;
    const int s = rowptr[n], e = rowptr[n + 1];
    const float u = gather_sum(csr, s, e, S0 + lane, lane);
    const float dv = dinv[n];
    const float t1 = -dv * u;          // Tx1 row element
    const size_t o = (size_t)n * F + lane;
    S1[o] = dv * t1;                   // = -dinv^2 * u
    const float x0 = x[o];
    float s0 = b[lane], s1 = 0.f, s2 = 0.f, s3 = 0.f;
#pragma unroll
    for (int j = 0; j < F; j += 4) {
        s0 += __shfl(x0, j + 0) * Ws[(j + 0) * F + lane];
        s1 += __shfl(x0, j + 1) * Ws[(j + 1) * F + lane];
        s2 += __shfl(x0, j + 2) * Ws[(j + 2) * F + lane];
        s3 += __shfl(x0, j + 3) * Ws[(j + 3) * F + lane];
    }
#pragma unroll
    for (int j = 0; j < F; j += 4) {
        s0 += __shfl(t1, j + 0) * Ws[F * F + (j + 0) * F + lane];
        s1 += __shfl(t1, j + 1) * Ws[F * F + (j + 1) * F + lane];
        s2 += __shfl(t1, j + 2) * Ws[F * F + (j + 2) * F + lane];
        s3 += __shfl(t1, j + 3) * Ws[F * F + (j + 3) * F + lane];
    }
    out[o] = (s0 + s1) + (s2 + s3);
}

// k>=2: snew = -2*dinv^2 * gather(Sprev) - Sown[o]; Sown[o] = snew (in place);
// t = snew*rdinv (or analytic pattern for deg-0 rows); out += t@Wk; optional relu
template <int WPB>
__global__ void prop_step_kernel(const int* __restrict__ rowptr, const int* __restrict__ csr,
                                 const float* __restrict__ dinv2, const float* __restrict__ rdinv,
                                 const float* __restrict__ x, const float* __restrict__ Sprev,
                                 float* __restrict__ Sown, const float* __restrict__ Wk,
                                 float* __restrict__ out, int N, float zcoef, int final_relu) {
    __shared__ float Ws[F * F];
    for (int t = threadIdx.x; t < F * F; t += blockDim.x) Ws[t] = Wk[t];
    __syncthreads();
    const int lane = threadIdx.x & 63;
    const int n = blockIdx.x * WPB + (threadIdx.x >> 6);
    if (n >= N) return;
    const int s = rowptr[n], e = rowptr[n + 1];
    const float u = gather_sum(csr, s, e, Sprev + lane, lane);
    const size_t o = (size_t)n * F + lane;
    const float d2 = dinv2[n];
    const float snew = -2.0f * d2 * u - Sown[o];
    Sown[o] = snew;
    const float t = (d2 > 0.0f) ? snew * rdinv[n] : zcoef * x[o];
    float s0 = 0.f, s1 = 0.f, s2 = 0.f, s3 = 0.f;
#pragma unroll
    for (int j = 0; j < F; j += 4) {
        s0 += __shfl(t, j + 0) * Ws[(j + 0) * F + lane];
        s1 += __shfl(t, j + 1) * Ws[(j + 1) * F + lane];
        s2 += __shfl(t, j + 2) * Ws[(j + 2) * F + lane];
        s3 += __shfl(t, j + 3) * Ws[(j + 3) * F + lane];
    }
    float r = out[o] + (s0 + s1) + (s2 + s3);
    if (final_relu) r = fmaxf(r, 0.f);
    out[o] = r;
}

extern "C" void kernel_launch(void* const* d_in, const int* in_sizes, int n_in,
                              void* d_out, int out_size, void* d_ws, size_t ws_size,
                              hipStream_t stream) {
    const float* x = (const float*)d_in[0];
    const int* ei = (const int*)d_in[1];
    const float* W = (const float*)d_in[2];
    const float* b = (const float*)d_in[3];

    const int N = in_sizes[0] / F;
    const int E = in_sizes[1] / 2;
    const int* row = ei;      // sources j
    const int* col = ei + E;  // targets i

    // workspace layout
    float* deg    = (float*)d_ws;              // N   (deg, then reused scratch)
    int*   cnt    = (int*)(deg + N);           // N   (memset together with deg)
    float* dinv   = (float*)(cnt + N);         // N
    float* dinv2  = dinv + N;                  // N
    float* rdinv  = dinv2 + N;                 // N
    int*   rowptr = (int*)(rdinv + N);         // N+1
    int*   cursor = rowptr + N + 1;            // N
    int*   csr    = cursor + N;                // E
    float* SA     = (float*)(csr + E);         // N*F
    float* SB     = SA + (size_t)N * F;        // N*F
    float* out    = (float*)d_out;             // N*F

    const int B = 256;
    constexpr int WPB = 4;
    const int pgrid = (N + WPB - 1) / WPB;
    const int NF = N * F;

    // build dinv variants + CSR (counting sort by destination)
    hipMemsetAsync(deg, 0, (size_t)2 * N * sizeof(float), stream);  // deg + cnt
    deg_cnt_kernel<<<(E + B - 1) / B, B, 0, stream>>>(row, col, deg, cnt, E);
    dinv_kernel<<<(N + B - 1) / B, B, 0, stream>>>(deg, dinv, dinv2, rdinv, N);
    scan_kernel<<<1, 1024, 0, stream>>>(cnt, rowptr, cursor, N);
    fill_kernel<<<(E + B - 1) / B, B, 0, stream>>>(row, col, cursor, csr, E);

    // S0 = dinv (.) x  -> SA
    sx_kernel<<<(NF + B - 1) / B, B, 0, stream>>>(dinv, x, SA, NF);

    // k=0,1: out = b + x@W0 + Tx1@W1 ; S1 -> SB
    prop_first_kernel<WPB><<<pgrid, WPB * 64, 0, stream>>>(rowptr, csr, dinv, x, SA, SB, W, b, out, N);
    // k=2: gather SB, own SA   (Tx_k pattern for deg-0 rows: k=2 -> -x)
    prop_step_kernel<WPB><<<pgrid, WPB * 64, 0, stream>>>(rowptr, csr, dinv2, rdinv, x, SB, SA,
                                                          W + 2 * F * F, out, N, -1.0f, 0);
    // k=3: gather SA, own SB  (deg-0: 0)
    prop_step_kernel<WPB><<<pgrid, WPB * 64, 0, stream>>>(rowptr, csr, dinv2, rdinv, x, SA, SB,
                                                          W + 3 * F * F, out, N, 0.0f, 0);
    // k=4: gather SB, own SA  (deg-0: +x)
    prop_step_kernel<WPB><<<pgrid, WPB * 64, 0, stream>>>(rowptr, csr, dinv2, rdinv, x, SB, SA,
                                                          W + 4 * F * F, out, N, 1.0f, 0);
    // k=5: gather SA, own SB  (deg-0: 0) + relu
    prop_step_kernel<WPB><<<pgrid, WPB * 64, 0, stream>>>(rowptr, csr, dinv2, rdinv, x, SA, SB,
                                                          W + 5 * F * F, out, N, 0.0f, 1);
}

// Round 4
// 1458.233 us; speedup vs baseline: 4.9546x; 1.0573x over previous
//
#include <hip/hip_runtime.h>

// ChebConv K=6, sym norm, lambda_max=2 => L_hat = -D^{-1/2} A D^{-1/2}
// N=100000, E=1600000, F=64.
// R4: float4 gather — one wave-wide load covers 4 source rows (1 KB), 4
// independent loads in flight per 16 edges. Recurrence in pre-scaled space
// S_k = dinv (.) Tx_k (in-place ping-pong), GEMM/bias/relu fused.

constexpr int F = 64;

__global__ void deg_cnt_kernel(const int* __restrict__ row, const int* __restrict__ col,
                               float* __restrict__ deg, int* __restrict__ cnt, int E) {
    int e = blockIdx.x * blockDim.x + threadIdx.x;
    if (e < E) {
        atomicAdd(&deg[row[e]], 1.0f);
        atomicAdd(&cnt[col[e]], 1);
    }
}

__global__ void dinv_kernel(const float* __restrict__ deg, float* __restrict__ dinv,
                            float* __restrict__ dinv2, float* __restrict__ rdinv, int N) {
    int i = blockIdx.x * blockDim.x + threadIdx.x;
    if (i < N) {
        float d = deg[i];
        bool ok = d > 0.0f;
        dinv[i]  = ok ? rsqrtf(d) : 0.0f;
        dinv2[i] = ok ? 1.0f / d : 0.0f;
        rdinv[i] = ok ? sqrtf(d) : 0.0f;
    }
}

// single-block exclusive scan of cnt[0..N) -> rowptr[0..N], cursor copy
__global__ void scan_kernel(const int* __restrict__ cnt, int* __restrict__ rowptr,
                            int* __restrict__ cursor, int N) {
    __shared__ int partial[1024];
    const int tid = threadIdx.x;
    const int chunk = (N + 1023) / 1024;
    const int begin = tid * chunk;
    const int end = (begin + chunk < N) ? begin + chunk : N;
    int sum = 0;
    for (int i = begin; i < end; ++i) sum += cnt[i];
    partial[tid] = sum;
    __syncthreads();
    for (int off = 1; off < 1024; off <<= 1) {
        int v = (tid >= off) ? partial[tid - off] : 0;
        __syncthreads();
        partial[tid] += v;
        __syncthreads();
    }
    int run = (tid == 0) ? 0 : partial[tid - 1];
    for (int i = begin; i < end; ++i) {
        rowptr[i] = run;
        cursor[i] = run;
        run += cnt[i];
    }
    if (end == N) rowptr[N] = run;
}

__global__ void fill_kernel(const int* __restrict__ row, const int* __restrict__ col,
                            int* __restrict__ cursor, int* __restrict__ csr_src, int E) {
    int e = blockIdx.x * blockDim.x + threadIdx.x;
    if (e < E) {
        int pos = atomicAdd(&cursor[col[e]], 1);
        csr_src[pos] = row[e];
    }
}

// S0 = dinv (.) x
__global__ void sx_kernel(const float* __restrict__ dinv, const float* __restrict__ x,
                          float* __restrict__ S0, int NF) {
    int i = blockIdx.x * blockDim.x + threadIdx.x;
    if (i < NF) S0[i] = dinv[i >> 6] * x[i];
}

// Gather-sum over in-edges of node n: returns sum_{src} S[src, lane].
// One wave-wide float4 load covers 4 rows; 4 loads (16 edges) in flight.
__device__ __forceinline__ float gather_sum_f4(const int* __restrict__ csr, int s, int e,
                                               const float* __restrict__ S, int lane) {
    const int q = lane >> 4;          // subrow within a load group
    const int fo = (lane & 15) * 4;   // feature offset of this lane's float4
    float4 A0 = {0, 0, 0, 0}, A1 = {0, 0, 0, 0}, A2 = {0, 0, 0, 0}, A3 = {0, 0, 0, 0};
    for (int base = s; base < e; base += 64) {
        int li = base + lane;
        int idx = csr[li < e ? li : e - 1];
        int m = e - base;
        if (m > 64) m = 64;
        for (int g0 = 0; g0 < m; g0 += 16) {
            const int e0 = g0 + q, e1 = g0 + 4 + q, e2 = g0 + 8 + q, e3 = g0 + 12 + q;
            const int r0 = __shfl(idx, e0), r1 = __shfl(idx, e1);
            const int r2 = __shfl(idx, e2), r3 = __shfl(idx, e3);
            const float4 v0 = *(const float4*)(S + (size_t)r0 * F + fo);
            const float4 v1 = *(const float4*)(S + (size_t)r1 * F + fo);
            const float4 v2 = *(const float4*)(S + (size_t)r2 * F + fo);
            const float4 v3 = *(const float4*)(S + (size_t)r3 * F + fo);
            if (g0 + 16 <= m) {  // full batch (wave-uniform branch)
                A0.x += v0.x; A0.y += v0.y; A0.z += v0.z; A0.w += v0.w;
                A1.x += v1.x; A1.y += v1.y; A1.z += v1.z; A1.w += v1.w;
                A2.x += v2.x; A2.y += v2.y; A2.z += v2.z; A2.w += v2.w;
                A3.x += v3.x; A3.y += v3.y; A3.z += v3.z; A3.w += v3.w;
            } else {
                const float s0 = e0 < m ? 1.f : 0.f, s1 = e1 < m ? 1.f : 0.f;
                const float s2 = e2 < m ? 1.f : 0.f, s3 = e3 < m ? 1.f : 0.f;
                A0.x += s0 * v0.x; A0.y += s0 * v0.y; A0.z += s0 * v0.z; A0.w += s0 * v0.w;
                A1.x += s1 * v1.x; A1.y += s1 * v1.y; A1.z += s1 * v1.z; A1.w += s1 * v1.w;
                A2.x += s2 * v2.x; A2.y += s2 * v2.y; A2.z += s2 * v2.z; A2.w += s2 * v2.w;
                A3.x += s3 * v3.x; A3.y += s3 * v3.y; A3.z += s3 * v3.z; A3.w += s3 * v3.w;
            }
        }
    }
    float4 t;
    t.x = (A0.x + A1.x) + (A2.x + A3.x);
    t.y = (A0.y + A1.y) + (A2.y + A3.y);
    t.z = (A0.z + A1.z) + (A2.z + A3.z);
    t.w = (A0.w + A1.w) + (A2.w + A3.w);
    // reduce across the 4 subrow groups (lanes l, l^16, l^32, l^48)
    t.x += __shfl_xor(t.x, 16); t.y += __shfl_xor(t.y, 16);
    t.z += __shfl_xor(t.z, 16); t.w += __shfl_xor(t.w, 16);
    t.x += __shfl_xor(t.x, 32); t.y += __shfl_xor(t.y, 32);
    t.z += __shfl_xor(t.z, 32); t.w += __shfl_xor(t.w, 32);
    // remap: lane wants feature `lane` = 4*(lane>>2) + (lane&3)
    const int sl = lane >> 2;
    const float vx = __shfl(t.x, sl), vy = __shfl(t.y, sl);
    const float vz = __shfl(t.z, sl), vw = __shfl(t.w, sl);
    const int c = lane & 3;
    return c == 0 ? vx : (c == 1 ? vy : (c == 2 ? vz : vw));
}

// k0+k1 fused: S1 = -dinv^2 * gather(S0); out = b + x@W0 + Tx1@W1, Tx1 = S1*rdinv
template <int WPB>
__global__ void prop_first_kernel(const int* __restrict__ rowptr, const int* __restrict__ csr,
                                  const float* __restrict__ dinv, const float* __restrict__ x,
                                  const float* __restrict__ S0, float* __restrict__ S1,
                                  const float* __restrict__ W01, const float* __restrict__ b,
                                  float* __restrict__ out, int N) {
    __shared__ float Ws[2 * F * F];
    for (int t = threadIdx.x; t < 2 * F * F; t += blockDim.x) Ws[t] = W01[t];
    __syncthreads();
    const int lane = threadIdx.x & 63;
    const int n = blockIdx.x * WPB + (threadIdx.x >> 6);
    if (n >= N) return;
    const int s = rowptr[n], e = rowptr[n + 1];
    const float u = gather_sum_f4(csr, s, e, S0, lane);
    const float dv = dinv[n];
    const float t1 = -dv * u;  // Tx1 row element
    const size_t o = (size_t)n * F + lane;
    S1[o] = dv * t1;           // = -dinv^2 * u
    const float x0 = x[o];
    float s0 = b[lane], s1 = 0.f, s2 = 0.f, s3 = 0.f;
#pragma unroll
    for (int j = 0; j < F; j += 4) {
        s0 += __shfl(x0, j + 0) * Ws[(j + 0) * F + lane];
        s1 += __shfl(x0, j + 1) * Ws[(j + 1) * F + lane];
        s2 += __shfl(x0, j + 2) * Ws[(j + 2) * F + lane];
        s3 += __shfl(x0, j + 3) * Ws[(j + 3) * F + lane];
    }
#pragma unroll
    for (int j = 0; j < F; j += 4) {
        s0 += __shfl(t1, j + 0) * Ws[F * F + (j + 0) * F + lane];
        s1 += __shfl(t1, j + 1) * Ws[F * F + (j + 1) * F + lane];
        s2 += __shfl(t1, j + 2) * Ws[F * F + (j + 2) * F + lane];
        s3 += __shfl(t1, j + 3) * Ws[F * F + (j + 3) * F + lane];
    }
    out[o] = (s0 + s1) + (s2 + s3);
}

// k>=2: snew = -2*dinv^2 * gather(Sprev) - Sown[o]; Sown[o] = snew (in place);
// t = snew*rdinv (analytic pattern for deg-0 rows); out += t@Wk; optional relu
template <int WPB>
__global__ void prop_step_kernel(const int* __restrict__ rowptr, const int* __restrict__ csr,
                                 const float* __restrict__ dinv2, const float* __restrict__ rdinv,
                                 const float* __restrict__ x, const float* __restrict__ Sprev,
                                 float* __restrict__ Sown, const float* __restrict__ Wk,
                                 float* __restrict__ out, int N, float zcoef, int final_relu) {
    __shared__ float Ws[F * F];
    for (int t = threadIdx.x; t < F * F; t += blockDim.x) Ws[t] = Wk[t];
    __syncthreads();
    const int lane = threadIdx.x & 63;
    const int n = blockIdx.x * WPB + (threadIdx.x >> 6);
    if (n >= N) return;
    const int s = rowptr[n], e = rowptr[n + 1];
    const float u = gather_sum_f4(csr, s, e, Sprev, lane);
    const size_t o = (size_t)n * F + lane;
    const float d2 = dinv2[n];
    const float snew = -2.0f * d2 * u - Sown[o];
    Sown[o] = snew;
    const float t = (d2 > 0.0f) ? snew * rdinv[n] : zcoef * x[o];
    float s0 = 0.f, s1 = 0.f, s2 = 0.f, s3 = 0.f;
#pragma unroll
    for (int j = 0; j < F; j += 4) {
        s0 += __shfl(t, j + 0) * Ws[(j + 0) * F + lane];
        s1 += __shfl(t, j + 1) * Ws[(j + 1) * F + lane];
        s2 += __shfl(t, j + 2) * Ws[(j + 2) * F + lane];
        s3 += __shfl(t, j + 3) * Ws[(j + 3) * F + lane];
    }
    float r = out[o] + (s0 + s1) + (s2 + s3);
    if (final_relu) r = fmaxf(r, 0.f);
    out[o] = r;
}

extern "C" void kernel_launch(void* const* d_in, const int* in_sizes, int n_in,
                              void* d_out, int out_size, void* d_ws, size_t ws_size,
                              hipStream_t stream) {
    const float* x = (const float*)d_in[0];
    const int* ei = (const int*)d_in[1];
    const float* W = (const float*)d_in[2];
    const float* b = (const float*)d_in[3];

    const int N = in_sizes[0] / F;
    const int E = in_sizes[1] / 2;
    const int* row = ei;      // sources j
    const int* col = ei + E;  // targets i

    // workspace layout
    float* deg    = (float*)d_ws;              // N
    int*   cnt    = (int*)(deg + N);           // N (memset together with deg)
    float* dinv   = (float*)(cnt + N);         // N
    float* dinv2  = dinv + N;                  // N
    float* rdinv  = dinv2 + N;                 // N
    int*   rowptr = (int*)(rdinv + N);         // N+1
    int*   cursor = rowptr + N + 1;            // N
    int*   csr    = cursor + N;                // E
    float* SA     = (float*)(csr + E);         // N*F
    float* SB     = SA + (size_t)N * F;        // N*F
    float* out    = (float*)d_out;             // N*F

    const int B = 256;
    constexpr int WPB = 4;
    const int pgrid = (N + WPB - 1) / WPB;
    const int NF = N * F;

    hipMemsetAsync(deg, 0, (size_t)2 * N * sizeof(float), stream);  // deg + cnt
    deg_cnt_kernel<<<(E + B - 1) / B, B, 0, stream>>>(row, col, deg, cnt, E);
    dinv_kernel<<<(N + B - 1) / B, B, 0, stream>>>(deg, dinv, dinv2, rdinv, N);
    scan_kernel<<<1, 1024, 0, stream>>>(cnt, rowptr, cursor, N);
    fill_kernel<<<(E + B - 1) / B, B, 0, stream>>>(row, col, cursor, csr, E);

    sx_kernel<<<(NF + B - 1) / B, B, 0, stream>>>(dinv, x, SA, NF);

    // k=0,1: out = b + x@W0 + Tx1@W1 ; S1 -> SB
    prop_first_kernel<WPB><<<pgrid, WPB * 64, 0, stream>>>(rowptr, csr, dinv, x, SA, SB, W, b, out, N);
    // k=2: gather SB, own SA (deg-0 rows: Tx2 = -x)
    prop_step_kernel<WPB><<<pgrid, WPB * 64, 0, stream>>>(rowptr, csr, dinv2, rdinv, x, SB, SA,
                                                          W + 2 * F * F, out, N, -1.0f, 0);
    // k=3: gather SA, own SB (deg-0: 0)
    prop_step_kernel<WPB><<<pgrid, WPB * 64, 0, stream>>>(rowptr, csr, dinv2, rdinv, x, SA, SB,
                                                          W + 3 * F * F, out, N, 0.0f, 0);
    // k=4: gather SB, own SA (deg-0: +x)
    prop_step_kernel<WPB><<<pgrid, WPB * 64, 0, stream>>>(rowptr, csr, dinv2, rdinv, x, SB, SA,
                                                          W + 4 * F * F, out, N, 1.0f, 0);
    // k=5: gather SA, own SB (deg-0: 0) + relu
    prop_step_kernel<WPB><<<pgrid, WPB * 64, 0, stream>>>(rowptr, csr, dinv2, rdinv, x, SA, SB,
                                                          W + 5 * F * F, out, N, 0.0f, 1);
}

// Round 5
// 1131.092 us; speedup vs baseline: 6.3875x; 1.2892x over previous
//
#include <hip/hip_runtime.h>

// ChebConv K=6, sym norm, lambda_max=2 => L_hat = -D^{-1/2} A D^{-1/2}
// N=100000, E=1600000, F=64.
// R5: W column held in registers (64 VGPR/lane), epilogue GEMM via per-wave
// LDS t-row broadcast (ds_read_b128) instead of 64 shfl/bpermutes; 8 nodes
// per wave amortize W load. Recurrence in pre-scaled space S_k = dinv (.) Tx_k.

constexpr int F = 64;
constexpr int WPB = 4;   // waves per block
constexpr int NPW = 8;   // nodes per wave

__global__ void deg_cnt_kernel(const int* __restrict__ row, const int* __restrict__ col,
                               float* __restrict__ deg, int* __restrict__ cnt, int E) {
    int e = blockIdx.x * blockDim.x + threadIdx.x;
    if (e < E) {
        atomicAdd(&deg[row[e]], 1.0f);
        atomicAdd(&cnt[col[e]], 1);
    }
}

__global__ void dinv_kernel(const float* __restrict__ deg, float* __restrict__ dinv,
                            float* __restrict__ dinv2, float* __restrict__ rdinv, int N) {
    int i = blockIdx.x * blockDim.x + threadIdx.x;
    if (i < N) {
        float d = deg[i];
        bool ok = d > 0.0f;
        dinv[i]  = ok ? rsqrtf(d) : 0.0f;
        dinv2[i] = ok ? 1.0f / d : 0.0f;
        rdinv[i] = ok ? sqrtf(d) : 0.0f;
    }
}

// single-block exclusive scan of cnt[0..N) -> rowptr[0..N], cursor copy
__global__ void scan_kernel(const int* __restrict__ cnt, int* __restrict__ rowptr,
                            int* __restrict__ cursor, int N) {
    __shared__ int partial[1024];
    const int tid = threadIdx.x;
    const int chunk = (N + 1023) / 1024;
    const int begin = tid * chunk;
    const int end = (begin + chunk < N) ? begin + chunk : N;
    int sum = 0;
    for (int i = begin; i < end; ++i) sum += cnt[i];
    partial[tid] = sum;
    __syncthreads();
    for (int off = 1; off < 1024; off <<= 1) {
        int v = (tid >= off) ? partial[tid - off] : 0;
        __syncthreads();
        partial[tid] += v;
        __syncthreads();
    }
    int run = (tid == 0) ? 0 : partial[tid - 1];
    for (int i = begin; i < end; ++i) {
        rowptr[i] = run;
        cursor[i] = run;
        run += cnt[i];
    }
    if (end == N) rowptr[N] = run;
}

__global__ void fill_kernel(const int* __restrict__ row, const int* __restrict__ col,
                            int* __restrict__ cursor, int* __restrict__ csr_src, int E) {
    int e = blockIdx.x * blockDim.x + threadIdx.x;
    if (e < E) {
        int pos = atomicAdd(&cursor[col[e]], 1);
        csr_src[pos] = row[e];
    }
}

// Gather-sum over in-edges of node n: returns sum_{src} S[src, lane] (feature = lane).
// One wave-wide float4 load covers 4 rows; 4 loads (16 edges) in flight.
__device__ __forceinline__ float gather_sum_f4(const int* __restrict__ csr, int s, int e,
                                               const float* __restrict__ S, int lane) {
    const int q = lane >> 4;          // subrow within a load group
    const int fo = (lane & 15) * 4;   // feature offset of this lane's float4
    float4 A0 = {0, 0, 0, 0}, A1 = {0, 0, 0, 0}, A2 = {0, 0, 0, 0}, A3 = {0, 0, 0, 0};
    for (int base = s; base < e; base += 64) {
        int li = base + lane;
        int idx = csr[li < e ? li : e - 1];
        int m = e - base;
        if (m > 64) m = 64;
        for (int g0 = 0; g0 < m; g0 += 16) {
            const int e0 = g0 + q, e1 = g0 + 4 + q, e2 = g0 + 8 + q, e3 = g0 + 12 + q;
            const int r0 = __shfl(idx, e0), r1 = __shfl(idx, e1);
            const int r2 = __shfl(idx, e2), r3 = __shfl(idx, e3);
            const float4 v0 = *(const float4*)(S + (size_t)r0 * F + fo);
            const float4 v1 = *(const float4*)(S + (size_t)r1 * F + fo);
            const float4 v2 = *(const float4*)(S + (size_t)r2 * F + fo);
            const float4 v3 = *(const float4*)(S + (size_t)r3 * F + fo);
            if (g0 + 16 <= m) {  // full batch (wave-uniform branch)
                A0.x += v0.x; A0.y += v0.y; A0.z += v0.z; A0.w += v0.w;
                A1.x += v1.x; A1.y += v1.y; A1.z += v1.z; A1.w += v1.w;
                A2.x += v2.x; A2.y += v2.y; A2.z += v2.z; A2.w += v2.w;
                A3.x += v3.x; A3.y += v3.y; A3.z += v3.z; A3.w += v3.w;
            } else {
                const float s0 = e0 < m ? 1.f : 0.f, s1 = e1 < m ? 1.f : 0.f;
                const float s2 = e2 < m ? 1.f : 0.f, s3 = e3 < m ? 1.f : 0.f;
                A0.x += s0 * v0.x; A0.y += s0 * v0.y; A0.z += s0 * v0.z; A0.w += s0 * v0.w;
                A1.x += s1 * v1.x; A1.y += s1 * v1.y; A1.z += s1 * v1.z; A1.w += s1 * v1.w;
                A2.x += s2 * v2.x; A2.y += s2 * v2.y; A2.z += s2 * v2.z; A2.w += s2 * v2.w;
                A3.x += s3 * v3.x; A3.y += s3 * v3.y; A3.z += s3 * v3.z; A3.w += s3 * v3.w;
            }
        }
    }
    float4 t;
    t.x = (A0.x + A1.x) + (A2.x + A3.x);
    t.y = (A0.y + A1.y) + (A2.y + A3.y);
    t.z = (A0.z + A1.z) + (A2.z + A3.z);
    t.w = (A0.w + A1.w) + (A2.w + A3.w);
    // reduce across the 4 subrow groups (lanes l, l^16, l^32, l^48)
    t.x += __shfl_xor(t.x, 16); t.y += __shfl_xor(t.y, 16);
    t.z += __shfl_xor(t.z, 16); t.w += __shfl_xor(t.w, 16);
    t.x += __shfl_xor(t.x, 32); t.y += __shfl_xor(t.y, 32);
    t.z += __shfl_xor(t.z, 32); t.w += __shfl_xor(t.w, 32);
    // remap: lane wants feature `lane` = 4*(lane>>2) + (lane&3)
    const int sl = lane >> 2;
    const float vx = __shfl(t.x, sl), vy = __shfl(t.y, sl);
    const float vz = __shfl(t.z, sl), vw = __shfl(t.w, sl);
    const int c = lane & 3;
    return c == 0 ? vx : (c == 1 ? vy : (c == 2 ? vz : vw));
}

// GEMM epilogue: s = sum_i tb_row[i] * Wcol[i]  (tb_row broadcast via LDS b128 reads)
__device__ __forceinline__ float row_gemm(const float* __restrict__ tb_row,
                                          const float Wcol[F]) {
    float s0 = 0.f, s1 = 0.f, s2 = 0.f, s3 = 0.f;
#pragma unroll
    for (int j = 0; j < F; j += 16) {
        const float4 t0 = *(const float4*)(tb_row + j + 0);
        const float4 t1 = *(const float4*)(tb_row + j + 4);
        const float4 t2 = *(const float4*)(tb_row + j + 8);
        const float4 t3 = *(const float4*)(tb_row + j + 12);
        s0 += t0.x * Wcol[j + 0] + t0.y * Wcol[j + 1] + t0.z * Wcol[j + 2] + t0.w * Wcol[j + 3];
        s1 += t1.x * Wcol[j + 4] + t1.y * Wcol[j + 5] + t1.z * Wcol[j + 6] + t1.w * Wcol[j + 7];
        s2 += t2.x * Wcol[j + 8] + t2.y * Wcol[j + 9] + t2.z * Wcol[j + 10] + t2.w * Wcol[j + 11];
        s3 += t3.x * Wcol[j + 12] + t3.y * Wcol[j + 13] + t3.z * Wcol[j + 14] + t3.w * Wcol[j + 15];
    }
    return (s0 + s1) + (s2 + s3);
}

// init: S0 = dinv (.) x ; out = b + x@W0
__global__ __launch_bounds__(WPB * 64, 4)
void init_kernel(const float* __restrict__ dinv, const float* __restrict__ x,
                 float* __restrict__ S0, const float* __restrict__ W0,
                 const float* __restrict__ b, float* __restrict__ out, int N) {
    __shared__ float tb[WPB][F];
    const int lane = threadIdx.x & 63;
    const int wave = threadIdx.x >> 6;
    float Wcol[F];
#pragma unroll
    for (int i = 0; i < F; ++i) Wcol[i] = W0[i * F + lane];
    const float bl = b[lane];
    const int wbase = blockIdx.x * (WPB * NPW) + wave * NPW;
    for (int it = 0; it < NPW; ++it) {
        const int n = wbase + it;
        if (n >= N) break;
        const size_t o = (size_t)n * F + lane;
        const float xv = x[o];
        S0[o] = dinv[n] * xv;
        tb[wave][lane] = xv;
        const float s = row_gemm(tb[wave], Wcol);
        out[o] = bl + s;
    }
}

// k=1: S1 = -dinv^2 * gather(S0); out += Tx1@W1, Tx1 = -dinv * gather(S0)
__global__ __launch_bounds__(WPB * 64, 4)
void prop_first_kernel(const int* __restrict__ rowptr, const int* __restrict__ csr,
                       const float* __restrict__ dinv, const float* __restrict__ S0,
                       float* __restrict__ S1, const float* __restrict__ W1,
                       float* __restrict__ out, int N) {
    __shared__ float tb[WPB][F];
    const int lane = threadIdx.x & 63;
    const int wave = threadIdx.x >> 6;
    float Wcol[F];
#pragma unroll
    for (int i = 0; i < F; ++i) Wcol[i] = W1[i * F + lane];
    const int wbase = blockIdx.x * (WPB * NPW) + wave * NPW;
    for (int it = 0; it < NPW; ++it) {
        const int n = wbase + it;
        if (n >= N) break;
        const int s = rowptr[n], e = rowptr[n + 1];
        const float u = gather_sum_f4(csr, s, e, S0, lane);
        const float dv = dinv[n];
        const float t1 = -dv * u;
        const size_t o = (size_t)n * F + lane;
        S1[o] = dv * t1;
        tb[wave][lane] = t1;
        const float g = row_gemm(tb[wave], Wcol);
        out[o] += g;
    }
}

// k>=2: snew = -2*dinv^2*gather(Sprev) - Sown; Sown = snew (in place);
// t = snew*rdinv (analytic for deg-0); out += t@Wk; optional relu
__global__ __launch_bounds__(WPB * 64, 4)
void prop_step_kernel(const int* __restrict__ rowptr, const int* __restrict__ csr,
                      const float* __restrict__ dinv2, const float* __restrict__ rdinv,
                      const float* __restrict__ x, const float* __restrict__ Sprev,
                      float* __restrict__ Sown, const float* __restrict__ Wk,
                      float* __restrict__ out, int N, float zcoef, int final_relu) {
    __shared__ float tb[WPB][F];
    const int lane = threadIdx.x & 63;
    const int wave = threadIdx.x >> 6;
    float Wcol[F];
#pragma unroll
    for (int i = 0; i < F; ++i) Wcol[i] = Wk[i * F + lane];
    const int wbase = blockIdx.x * (WPB * NPW) + wave * NPW;
    for (int it = 0; it < NPW; ++it) {
        const int n = wbase + it;
        if (n >= N) break;
        const int s = rowptr[n], e = rowptr[n + 1];
        const float u = gather_sum_f4(csr, s, e, Sprev, lane);
        const size_t o = (size_t)n * F + lane;
        const float d2 = dinv2[n];
        const float snew = -2.0f * d2 * u - Sown[o];
        Sown[o] = snew;
        const float t = (d2 > 0.0f) ? snew * rdinv[n] : zcoef * x[o];
        tb[wave][lane] = t;
        const float g = row_gemm(tb[wave], Wcol);
        float r = out[o] + g;
        if (final_relu) r = fmaxf(r, 0.f);
        out[o] = r;
    }
}

extern "C" void kernel_launch(void* const* d_in, const int* in_sizes, int n_in,
                              void* d_out, int out_size, void* d_ws, size_t ws_size,
                              hipStream_t stream) {
    const float* x = (const float*)d_in[0];
    const int* ei = (const int*)d_in[1];
    const float* W = (const float*)d_in[2];
    const float* b = (const float*)d_in[3];

    const int N = in_sizes[0] / F;
    const int E = in_sizes[1] / 2;
    const int* row = ei;      // sources j
    const int* col = ei + E;  // targets i

    // workspace layout
    float* deg    = (float*)d_ws;              // N
    int*   cnt    = (int*)(deg + N);           // N (memset together with deg)
    float* dinv   = (float*)(cnt + N);         // N
    float* dinv2  = dinv + N;                  // N
    float* rdinv  = dinv2 + N;                 // N
    int*   rowptr = (int*)(rdinv + N);         // N+1
    int*   cursor = rowptr + N + 1;            // N
    int*   csr    = cursor + N;                // E
    float* SA     = (float*)(csr + E);         // N*F
    float* SB     = SA + (size_t)N * F;        // N*F
    float* out    = (float*)d_out;             // N*F

    const int B = 256;
    const int pgrid = (N + WPB * NPW - 1) / (WPB * NPW);

    hipMemsetAsync(deg, 0, (size_t)2 * N * sizeof(float), stream);  // deg + cnt
    deg_cnt_kernel<<<(E + B - 1) / B, B, 0, stream>>>(row, col, deg, cnt, E);
    dinv_kernel<<<(N + B - 1) / B, B, 0, stream>>>(deg, dinv, dinv2, rdinv, N);
    scan_kernel<<<1, 1024, 0, stream>>>(cnt, rowptr, cursor, N);
    fill_kernel<<<(E + B - 1) / B, B, 0, stream>>>(row, col, cursor, csr, E);

    // S0 -> SA ; out = b + x@W0
    init_kernel<<<pgrid, WPB * 64, 0, stream>>>(dinv, x, SA, W, b, out, N);
    // k=1: S1 -> SB ; out += Tx1@W1
    prop_first_kernel<<<pgrid, WPB * 64, 0, stream>>>(rowptr, csr, dinv, SA, SB,
                                                      W + 1 * F * F, out, N);
    // k=2: gather SB, own SA (deg-0 rows: Tx2 = -x)
    prop_step_kernel<<<pgrid, WPB * 64, 0, stream>>>(rowptr, csr, dinv2, rdinv, x, SB, SA,
                                                     W + 2 * F * F, out, N, -1.0f, 0);
    // k=3: gather SA, own SB (deg-0: 0)
    prop_step_kernel<<<pgrid, WPB * 64, 0, stream>>>(rowptr, csr, dinv2, rdinv, x, SA, SB,
                                                     W + 3 * F * F, out, N, 0.0f, 0);
    // k=4: gather SB, own SA (deg-0: +x)
    prop_step_kernel<<<pgrid, WPB * 64, 0, stream>>>(rowptr, csr, dinv2, rdinv, x, SB, SA,
                                                     W + 4 * F * F, out, N, 1.0f, 0);
    // k=5: gather SA, own SB (deg-0: 0) + relu
    prop_step_kernel<<<pgrid, WPB * 64, 0, stream>>>(rowptr, csr, dinv2, rdinv, x, SA, SB,
                                                     W + 5 * F * F, out, N, 0.0f, 1);
}

// Round 6
// 899.288 us; speedup vs baseline: 8.0340x; 1.2578x over previous
//
#include <hip/hip_runtime.h>

// ChebConv K=6, sym norm, lambda_max=2 => L_hat = -D^{-1/2} A D^{-1/2}
// N=100000, E=1600000, F=64.
// R6: replace 229us single-block scan with 3-phase multi-block scan
// (coalesced int4). Props unchanged from R5: W column in registers, LDS
// t-row broadcast epilogue, 8 nodes/wave, pre-scaled recurrence space.

constexpr int F = 64;
constexpr int WPB = 4;        // waves per block (prop kernels)
constexpr int NPW = 8;        // nodes per wave
constexpr int SCAN_ELEMS = 1024;  // elements per scan block (256 thr x int4)

__global__ void deg_cnt_kernel(const int* __restrict__ row, const int* __restrict__ col,
                               float* __restrict__ deg, int* __restrict__ cnt, int E) {
    int e = blockIdx.x * blockDim.x + threadIdx.x;
    if (e < E) {
        atomicAdd(&deg[row[e]], 1.0f);
        atomicAdd(&cnt[col[e]], 1);
    }
}

__global__ void dinv_kernel(const float* __restrict__ deg, float* __restrict__ dinv,
                            float* __restrict__ dinv2, float* __restrict__ rdinv, int N) {
    int i = blockIdx.x * blockDim.x + threadIdx.x;
    if (i < N) {
        float d = deg[i];
        bool ok = d > 0.0f;
        dinv[i]  = ok ? rsqrtf(d) : 0.0f;
        dinv2[i] = ok ? 1.0f / d : 0.0f;
        rdinv[i] = ok ? sqrtf(d) : 0.0f;
    }
}

__device__ __forceinline__ int4 load_cnt4(const int* __restrict__ cnt, int i, int N) {
    int4 v = make_int4(0, 0, 0, 0);
    if (i + 3 < N) {
        v = *(const int4*)(cnt + i);
    } else {
        if (i + 0 < N) v.x = cnt[i + 0];
        if (i + 1 < N) v.y = cnt[i + 1];
        if (i + 2 < N) v.z = cnt[i + 2];
        if (i + 3 < N) v.w = cnt[i + 3];
    }
    return v;
}

// phase 1: per-block sums (256 threads x 4 elems)
__global__ void scan1_kernel(const int* __restrict__ cnt, int* __restrict__ bsum, int N) {
    const int tid = threadIdx.x;
    const int i = blockIdx.x * SCAN_ELEMS + tid * 4;
    int4 v = load_cnt4(cnt, i, N);
    int s = v.x + v.y + v.z + v.w;
#pragma unroll
    for (int off = 1; off < 64; off <<= 1) s += __shfl_xor(s, off);
    __shared__ int ws[4];
    if ((tid & 63) == 0) ws[tid >> 6] = s;
    __syncthreads();
    if (tid == 0) bsum[blockIdx.x] = ws[0] + ws[1] + ws[2] + ws[3];
}

// phase 2: exclusive scan of block sums (nb <= 256), writes rowptr[N] = total
__global__ void scan2_kernel(const int* __restrict__ bsum, int* __restrict__ boff,
                             int* __restrict__ rowptr_last, int nb) {
    const int tid = threadIdx.x;  // 256
    const int lane = tid & 63, w = tid >> 6;
    int v = (tid < nb) ? bsum[tid] : 0;
    int inc = v;
#pragma unroll
    for (int off = 1; off < 64; off <<= 1) {
        int t = __shfl_up(inc, off);
        if (lane >= off) inc += t;
    }
    __shared__ int wsum[4];
    if (lane == 63) wsum[w] = inc;
    __syncthreads();
    int wo = 0;
    for (int k = 0; k < w; ++k) wo += wsum[k];
    const int excl = wo + inc - v;
    if (tid < nb) boff[tid] = excl;
    if (tid == nb - 1) *rowptr_last = excl + v;  // == E
}

// phase 3: per-block exclusive scan + block offset -> rowptr & cursor
__global__ void scan3_kernel(const int* __restrict__ cnt, const int* __restrict__ boff,
                             int* __restrict__ rowptr, int* __restrict__ cursor, int N) {
    const int tid = threadIdx.x;
    const int lane = tid & 63, w = tid >> 6;
    const int i = blockIdx.x * SCAN_ELEMS + tid * 4;
    int4 v = load_cnt4(cnt, i, N);
    const int s = v.x + v.y + v.z + v.w;
    int inc = s;
#pragma unroll
    for (int off = 1; off < 64; off <<= 1) {
        int t = __shfl_up(inc, off);
        if (lane >= off) inc += t;
    }
    __shared__ int wsum[4];
    if (lane == 63) wsum[w] = inc;
    __syncthreads();
    int wo = 0;
    for (int k = 0; k < w; ++k) wo += wsum[k];
    const int r0 = boff[blockIdx.x] + wo + inc - s;
    const int r1 = r0 + v.x, r2 = r1 + v.y, r3 = r2 + v.z;
    if (i + 3 < N) {
        *(int4*)(rowptr + i) = make_int4(r0, r1, r2, r3);
        *(int4*)(cursor + i) = make_int4(r0, r1, r2, r3);
    } else {
        if (i + 0 < N) { rowptr[i + 0] = r0; cursor[i + 0] = r0; }
        if (i + 1 < N) { rowptr[i + 1] = r1; cursor[i + 1] = r1; }
        if (i + 2 < N) { rowptr[i + 2] = r2; cursor[i + 2] = r2; }
        if (i + 3 < N) { rowptr[i + 3] = r3; cursor[i + 3] = r3; }
    }
}

__global__ void fill_kernel(const int* __restrict__ row, const int* __restrict__ col,
                            int* __restrict__ cursor, int* __restrict__ csr_src, int E) {
    int e = blockIdx.x * blockDim.x + threadIdx.x;
    if (e < E) {
        int pos = atomicAdd(&cursor[col[e]], 1);
        csr_src[pos] = row[e];
    }
}

// Gather-sum over in-edges of node n: returns sum_{src} S[src, lane] (feature = lane).
__device__ __forceinline__ float gather_sum_f4(const int* __restrict__ csr, int s, int e,
                                               const float* __restrict__ S, int lane) {
    const int q = lane >> 4;
    const int fo = (lane & 15) * 4;
    float4 A0 = {0, 0, 0, 0}, A1 = {0, 0, 0, 0}, A2 = {0, 0, 0, 0}, A3 = {0, 0, 0, 0};
    for (int base = s; base < e; base += 64) {
        int li = base + lane;
        int idx = csr[li < e ? li : e - 1];
        int m = e - base;
        if (m > 64) m = 64;
        for (int g0 = 0; g0 < m; g0 += 16) {
            const int e0 = g0 + q, e1 = g0 + 4 + q, e2 = g0 + 8 + q, e3 = g0 + 12 + q;
            const int r0 = __shfl(idx, e0), r1 = __shfl(idx, e1);
            const int r2 = __shfl(idx, e2), r3 = __shfl(idx, e3);
            const float4 v0 = *(const float4*)(S + (size_t)r0 * F + fo);
            const float4 v1 = *(const float4*)(S + (size_t)r1 * F + fo);
            const float4 v2 = *(const float4*)(S + (size_t)r2 * F + fo);
            const float4 v3 = *(const float4*)(S + (size_t)r3 * F + fo);
            if (g0 + 16 <= m) {
                A0.x += v0.x; A0.y += v0.y; A0.z += v0.z; A0.w += v0.w;
                A1.x += v1.x; A1.y += v1.y; A1.z += v1.z; A1.w += v1.w;
                A2.x += v2.x; A2.y += v2.y; A2.z += v2.z; A2.w += v2.w;
                A3.x += v3.x; A3.y += v3.y; A3.z += v3.z; A3.w += v3.w;
            } else {
                const float s0 = e0 < m ? 1.f : 0.f, s1 = e1 < m ? 1.f : 0.f;
                const float s2 = e2 < m ? 1.f : 0.f, s3 = e3 < m ? 1.f : 0.f;
                A0.x += s0 * v0.x; A0.y += s0 * v0.y; A0.z += s0 * v0.z; A0.w += s0 * v0.w;
                A1.x += s1 * v1.x; A1.y += s1 * v1.y; A1.z += s1 * v1.z; A1.w += s1 * v1.w;
                A2.x += s2 * v2.x; A2.y += s2 * v2.y; A2.z += s2 * v2.z; A2.w += s2 * v2.w;
                A3.x += s3 * v3.x; A3.y += s3 * v3.y; A3.z += s3 * v3.z; A3.w += s3 * v3.w;
            }
        }
    }
    float4 t;
    t.x = (A0.x + A1.x) + (A2.x + A3.x);
    t.y = (A0.y + A1.y) + (A2.y + A3.y);
    t.z = (A0.z + A1.z) + (A2.z + A3.z);
    t.w = (A0.w + A1.w) + (A2.w + A3.w);
    t.x += __shfl_xor(t.x, 16); t.y += __shfl_xor(t.y, 16);
    t.z += __shfl_xor(t.z, 16); t.w += __shfl_xor(t.w, 16);
    t.x += __shfl_xor(t.x, 32); t.y += __shfl_xor(t.y, 32);
    t.z += __shfl_xor(t.z, 32); t.w += __shfl_xor(t.w, 32);
    const int sl = lane >> 2;
    const float vx = __shfl(t.x, sl), vy = __shfl(t.y, sl);
    const float vz = __shfl(t.z, sl), vw = __shfl(t.w, sl);
    const int c = lane & 3;
    return c == 0 ? vx : (c == 1 ? vy : (c == 2 ? vz : vw));
}

// GEMM epilogue: s = sum_i tb_row[i] * Wcol[i]  (tb_row broadcast via LDS b128 reads)
__device__ __forceinline__ float row_gemm(const float* __restrict__ tb_row,
                                          const float Wcol[F]) {
    float s0 = 0.f, s1 = 0.f, s2 = 0.f, s3 = 0.f;
#pragma unroll
    for (int j = 0; j < F; j += 16) {
        const float4 t0 = *(const float4*)(tb_row + j + 0);
        const float4 t1 = *(const float4*)(tb_row + j + 4);
        const float4 t2 = *(const float4*)(tb_row + j + 8);
        const float4 t3 = *(const float4*)(tb_row + j + 12);
        s0 += t0.x * Wcol[j + 0] + t0.y * Wcol[j + 1] + t0.z * Wcol[j + 2] + t0.w * Wcol[j + 3];
        s1 += t1.x * Wcol[j + 4] + t1.y * Wcol[j + 5] + t1.z * Wcol[j + 6] + t1.w * Wcol[j + 7];
        s2 += t2.x * Wcol[j + 8] + t2.y * Wcol[j + 9] + t2.z * Wcol[j + 10] + t2.w * Wcol[j + 11];
        s3 += t3.x * Wcol[j + 12] + t3.y * Wcol[j + 13] + t3.z * Wcol[j + 14] + t3.w * Wcol[j + 15];
    }
    return (s0 + s1) + (s2 + s3);
}

// init: S0 = dinv (.) x ; out = b + x@W0
__global__ __launch_bounds__(WPB * 64, 4)
void init_kernel(const float* __restrict__ dinv, const float* __restrict__ x,
                 float* __restrict__ S0, const float* __restrict__ W0,
                 const float* __restrict__ b, float* __restrict__ out, int N) {
    __shared__ float tb[WPB][F];
    const int lane = threadIdx.x & 63;
    const int wave = threadIdx.x >> 6;
    float Wcol[F];
#pragma unroll
    for (int i = 0; i < F; ++i) Wcol[i] = W0[i * F + lane];
    const float bl = b[lane];
    const int wbase = blockIdx.x * (WPB * NPW) + wave * NPW;
    for (int it = 0; it < NPW; ++it) {
        const int n = wbase + it;
        if (n >= N) break;
        const size_t o = (size_t)n * F + lane;
        const float xv = x[o];
        S0[o] = dinv[n] * xv;
        tb[wave][lane] = xv;
        const float s = row_gemm(tb[wave], Wcol);
        out[o] = bl + s;
    }
}

// k=1: S1 = -dinv^2 * gather(S0); out += Tx1@W1, Tx1 = -dinv * gather(S0)
__global__ __launch_bounds__(WPB * 64, 4)
void prop_first_kernel(const int* __restrict__ rowptr, const int* __restrict__ csr,
                       const float* __restrict__ dinv, const float* __restrict__ S0,
                       float* __restrict__ S1, const float* __restrict__ W1,
                       float* __restrict__ out, int N) {
    __shared__ float tb[WPB][F];
    const int lane = threadIdx.x & 63;
    const int wave = threadIdx.x >> 6;
    float Wcol[F];
#pragma unroll
    for (int i = 0; i < F; ++i) Wcol[i] = W1[i * F + lane];
    const int wbase = blockIdx.x * (WPB * NPW) + wave * NPW;
    for (int it = 0; it < NPW; ++it) {
        const int n = wbase + it;
        if (n >= N) break;
        const int s = rowptr[n], e = rowptr[n + 1];
        const float u = gather_sum_f4(csr, s, e, S0, lane);
        const float dv = dinv[n];
        const float t1 = -dv * u;
        const size_t o = (size_t)n * F + lane;
        S1[o] = dv * t1;
        tb[wave][lane] = t1;
        const float g = row_gemm(tb[wave], Wcol);
        out[o] += g;
    }
}

// k>=2: snew = -2*dinv^2*gather(Sprev) - Sown; Sown = snew (in place);
// t = snew*rdinv (analytic for deg-0); out += t@Wk; optional relu
__global__ __launch_bounds__(WPB * 64, 4)
void prop_step_kernel(const int* __restrict__ rowptr, const int* __restrict__ csr,
                      const float* __restrict__ dinv2, const float* __restrict__ rdinv,
                      const float* __restrict__ x, const float* __restrict__ Sprev,
                      float* __restrict__ Sown, const float* __restrict__ Wk,
                      float* __restrict__ out, int N, float zcoef, int final_relu) {
    __shared__ float tb[WPB][F];
    const int lane = threadIdx.x & 63;
    const int wave = threadIdx.x >> 6;
    float Wcol[F];
#pragma unroll
    for (int i = 0; i < F; ++i) Wcol[i] = Wk[i * F + lane];
    const int wbase = blockIdx.x * (WPB * NPW) + wave * NPW;
    for (int it = 0; it < NPW; ++it) {
        const int n = wbase + it;
        if (n >= N) break;
        const int s = rowptr[n], e = rowptr[n + 1];
        const float u = gather_sum_f4(csr, s, e, Sprev, lane);
        const size_t o = (size_t)n * F + lane;
        const float d2 = dinv2[n];
        const float snew = -2.0f * d2 * u - Sown[o];
        Sown[o] = snew;
        const float t = (d2 > 0.0f) ? snew * rdinv[n] : zcoef * x[o];
        tb[wave][lane] = t;
        const float g = row_gemm(tb[wave], Wcol);
        float r = out[o] + g;
        if (final_relu) r = fmaxf(r, 0.f);
        out[o] = r;
    }
}

extern "C" void kernel_launch(void* const* d_in, const int* in_sizes, int n_in,
                              void* d_out, int out_size, void* d_ws, size_t ws_size,
                              hipStream_t stream) {
    const float* x = (const float*)d_in[0];
    const int* ei = (const int*)d_in[1];
    const float* W = (const float*)d_in[2];
    const float* b = (const float*)d_in[3];

    const int N = in_sizes[0] / F;
    const int E = in_sizes[1] / 2;
    const int* row = ei;      // sources j
    const int* col = ei + E;  // targets i

    // workspace layout
    float* deg    = (float*)d_ws;              // N
    int*   cnt    = (int*)(deg + N);           // N (memset together with deg)
    float* dinv   = (float*)(cnt + N);         // N
    float* dinv2  = dinv + N;                  // N
    float* rdinv  = dinv2 + N;                 // N
    int*   rowptr = (int*)(rdinv + N);         // N+1
    int*   cursor = rowptr + N + 1;            // N
    int*   bsum   = cursor + N;                // 256
    int*   boff   = bsum + 256;                // 256
    int*   csr    = boff + 256;                // E
    float* SA     = (float*)(csr + E);         // N*F
    float* SB     = SA + (size_t)N * F;        // N*F
    float* out    = (float*)d_out;             // N*F

    const int B = 256;
    const int pgrid = (N + WPB * NPW - 1) / (WPB * NPW);
    const int nsb = (N + SCAN_ELEMS - 1) / SCAN_ELEMS;  // 98 (<= 256 required)

    hipMemsetAsync(deg, 0, (size_t)2 * N * sizeof(float), stream);  // deg + cnt
    deg_cnt_kernel<<<(E + B - 1) / B, B, 0, stream>>>(row, col, deg, cnt, E);
    dinv_kernel<<<(N + B - 1) / B, B, 0, stream>>>(deg, dinv, dinv2, rdinv, N);
    scan1_kernel<<<nsb, B, 0, stream>>>(cnt, bsum, N);
    scan2_kernel<<<1, B, 0, stream>>>(bsum, boff, rowptr + N, nsb);
    scan3_kernel<<<nsb, B, 0, stream>>>(cnt, boff, rowptr, cursor, N);
    fill_kernel<<<(E + B - 1) / B, B, 0, stream>>>(row, col, cursor, csr, E);

    // S0 -> SA ; out = b + x@W0
    init_kernel<<<pgrid, WPB * 64, 0, stream>>>(dinv, x, SA, W, b, out, N);
    // k=1: S1 -> SB ; out += Tx1@W1
    prop_first_kernel<<<pgrid, WPB * 64, 0, stream>>>(rowptr, csr, dinv, SA, SB,
                                                      W + 1 * F * F, out, N);
    // k=2: gather SB, own SA (deg-0 rows: Tx2 = -x)
    prop_step_kernel<<<pgrid, WPB * 64, 0, stream>>>(rowptr, csr, dinv2, rdinv, x, SB, SA,
                                                     W + 2 * F * F, out, N, -1.0f, 0);
    // k=3: gather SA, own SB (deg-0: 0)
    prop_step_kernel<<<pgrid, WPB * 64, 0, stream>>>(rowptr, csr, dinv2, rdinv, x, SA, SB,
                                                     W + 3 * F * F, out, N, 0.0f, 0);
    // k=4: gather SB, own SA (deg-0: +x)
    prop_step_kernel<<<pgrid, WPB * 64, 0, stream>>>(rowptr, csr, dinv2, rdinv, x, SB, SA,
                                                     W + 4 * F * F, out, N, 1.0f, 0);
    // k=5: gather SA, own SB (deg-0: 0) + relu
    prop_step_kernel<<<pgrid, WPB * 64, 0, stream>>>(rowptr, csr, dinv2, rdinv, x, SA, SB,
                                                     W + 5 * F * F, out, N, 0.0f, 1);
}

// Round 7
// 806.608 us; speedup vs baseline: 8.9571x; 1.1149x over previous
//
#include <hip/hip_runtime.h>

// ChebConv K=6, sym norm, lambda_max=2 => L_hat = -D^{-1/2} A D^{-1/2}
// N=100000, E=1600000, F=64.
// R7: (1) S recurrence state stored as bf16 (arithmetic fp32 in-kernel) ->
// random gather rows 256B -> 128B; (2) deg/cnt histograms with 4 shadow
// copies (block-striped) to cut atomic line contention; int4 edge loads.

constexpr int F = 64;
constexpr int WPB = 4;        // waves per block (prop kernels)
constexpr int NPW = 8;        // nodes per wave
constexpr int SCAN_ELEMS = 1024;  // elements per scan block (256 thr x int4)
constexpr int NSHADOW = 4;

__device__ __forceinline__ unsigned short f_to_bf(float f) {
    unsigned u = __float_as_uint(f);
    u += 0x7FFFu + ((u >> 16) & 1u);  // RNE
    return (unsigned short)(u >> 16);
}
__device__ __forceinline__ float bf_to_f(unsigned short s) {
    return __uint_as_float(((unsigned)s) << 16);
}
__device__ __forceinline__ float4 bf4_to_f4(ushort4 u) {
    float4 f;
    f.x = bf_to_f(u.x); f.y = bf_to_f(u.y); f.z = bf_to_f(u.z); f.w = bf_to_f(u.w);
    return f;
}

// 4-shadow histograms: deg (out-degree of row) and cnt (in-degree of col)
__global__ void deg_cnt_kernel(const int* __restrict__ row, const int* __restrict__ col,
                               int* __restrict__ deg4, int* __restrict__ cnt4, int N, int E) {
    const int t = blockIdx.x * blockDim.x + threadIdx.x;
    const int e = t * 4;
    if (e >= E) return;
    const int sh = (blockIdx.x & (NSHADOW - 1)) * N;
    if (e + 3 < E) {
        const int4 r = *(const int4*)(row + e);
        const int4 c = *(const int4*)(col + e);
        atomicAdd(&deg4[sh + r.x], 1); atomicAdd(&cnt4[sh + c.x], 1);
        atomicAdd(&deg4[sh + r.y], 1); atomicAdd(&cnt4[sh + c.y], 1);
        atomicAdd(&deg4[sh + r.z], 1); atomicAdd(&cnt4[sh + c.z], 1);
        atomicAdd(&deg4[sh + r.w], 1); atomicAdd(&cnt4[sh + c.w], 1);
    } else {
        for (int k = e; k < E; ++k) {
            atomicAdd(&deg4[sh + row[k]], 1);
            atomicAdd(&cnt4[sh + col[k]], 1);
        }
    }
}

// reduce shadows; deg -> dinv, dinv2, rdinv; cnt -> cnt
__global__ void reduce_dinv_kernel(const int* __restrict__ deg4, const int* __restrict__ cnt4,
                                   float* __restrict__ dinv, float* __restrict__ dinv2,
                                   float* __restrict__ rdinv, int* __restrict__ cnt, int N) {
    int i = blockIdx.x * blockDim.x + threadIdx.x;
    if (i >= N) return;
    int dI = deg4[i] + deg4[N + i] + deg4[2 * N + i] + deg4[3 * N + i];
    cnt[i] = cnt4[i] + cnt4[N + i] + cnt4[2 * N + i] + cnt4[3 * N + i];
    float d = (float)dI;
    bool ok = dI > 0;
    dinv[i]  = ok ? rsqrtf(d) : 0.0f;
    dinv2[i] = ok ? 1.0f / d : 0.0f;
    rdinv[i] = ok ? sqrtf(d) : 0.0f;
}

__device__ __forceinline__ int4 load_cnt4(const int* __restrict__ cnt, int i, int N) {
    int4 v = make_int4(0, 0, 0, 0);
    if (i + 3 < N) {
        v = *(const int4*)(cnt + i);
    } else {
        if (i + 0 < N) v.x = cnt[i + 0];
        if (i + 1 < N) v.y = cnt[i + 1];
        if (i + 2 < N) v.z = cnt[i + 2];
        if (i + 3 < N) v.w = cnt[i + 3];
    }
    return v;
}

// phase 1: per-block sums (256 threads x 4 elems)
__global__ void scan1_kernel(const int* __restrict__ cnt, int* __restrict__ bsum, int N) {
    const int tid = threadIdx.x;
    const int i = blockIdx.x * SCAN_ELEMS + tid * 4;
    int4 v = load_cnt4(cnt, i, N);
    int s = v.x + v.y + v.z + v.w;
#pragma unroll
    for (int off = 1; off < 64; off <<= 1) s += __shfl_xor(s, off);
    __shared__ int ws[4];
    if ((tid & 63) == 0) ws[tid >> 6] = s;
    __syncthreads();
    if (tid == 0) bsum[blockIdx.x] = ws[0] + ws[1] + ws[2] + ws[3];
}

// phase 2: exclusive scan of block sums (nb <= 256), writes rowptr[N] = total
__global__ void scan2_kernel(const int* __restrict__ bsum, int* __restrict__ boff,
                             int* __restrict__ rowptr_last, int nb) {
    const int tid = threadIdx.x;  // 256
    const int lane = tid & 63, w = tid >> 6;
    int v = (tid < nb) ? bsum[tid] : 0;
    int inc = v;
#pragma unroll
    for (int off = 1; off < 64; off <<= 1) {
        int t = __shfl_up(inc, off);
        if (lane >= off) inc += t;
    }
    __shared__ int wsum[4];
    if (lane == 63) wsum[w] = inc;
    __syncthreads();
    int wo = 0;
    for (int k = 0; k < w; ++k) wo += wsum[k];
    const int excl = wo + inc - v;
    if (tid < nb) boff[tid] = excl;
    if (tid == nb - 1) *rowptr_last = excl + v;  // == E
}

// phase 3: per-block exclusive scan + block offset -> rowptr & cursor
__global__ void scan3_kernel(const int* __restrict__ cnt, const int* __restrict__ boff,
                             int* __restrict__ rowptr, int* __restrict__ cursor, int N) {
    const int tid = threadIdx.x;
    const int lane = tid & 63, w = tid >> 6;
    const int i = blockIdx.x * SCAN_ELEMS + tid * 4;
    int4 v = load_cnt4(cnt, i, N);
    const int s = v.x + v.y + v.z + v.w;
    int inc = s;
#pragma unroll
    for (int off = 1; off < 64; off <<= 1) {
        int t = __shfl_up(inc, off);
        if (lane >= off) inc += t;
    }
    __shared__ int wsum[4];
    if (lane == 63) wsum[w] = inc;
    __syncthreads();
    int wo = 0;
    for (int k = 0; k < w; ++k) wo += wsum[k];
    const int r0 = boff[blockIdx.x] + wo + inc - s;
    const int r1 = r0 + v.x, r2 = r1 + v.y, r3 = r2 + v.z;
    if (i + 3 < N) {
        *(int4*)(rowptr + i) = make_int4(r0, r1, r2, r3);
        *(int4*)(cursor + i) = make_int4(r0, r1, r2, r3);
    } else {
        if (i + 0 < N) { rowptr[i + 0] = r0; cursor[i + 0] = r0; }
        if (i + 1 < N) { rowptr[i + 1] = r1; cursor[i + 1] = r1; }
        if (i + 2 < N) { rowptr[i + 2] = r2; cursor[i + 2] = r2; }
        if (i + 3 < N) { rowptr[i + 3] = r3; cursor[i + 3] = r3; }
    }
}

__global__ void fill_kernel(const int* __restrict__ row, const int* __restrict__ col,
                            int* __restrict__ cursor, int* __restrict__ csr_src, int E) {
    int e = blockIdx.x * blockDim.x + threadIdx.x;
    if (e < E) {
        int pos = atomicAdd(&cursor[col[e]], 1);
        csr_src[pos] = row[e];
    }
}

// Gather-sum over in-edges: u[lane] = sum_{src} S[src, lane], S in bf16.
// One wave-wide ushort4 load covers 4 rows (128B each); 4 loads in flight.
__device__ __forceinline__ float gather_sum_bf(const int* __restrict__ csr, int s, int e,
                                               const unsigned short* __restrict__ S, int lane) {
    const int q = lane >> 4;
    const int fo = (lane & 15) * 4;
    float4 A0 = {0, 0, 0, 0}, A1 = {0, 0, 0, 0}, A2 = {0, 0, 0, 0}, A3 = {0, 0, 0, 0};
    for (int base = s; base < e; base += 64) {
        int li = base + lane;
        int idx = csr[li < e ? li : e - 1];
        int m = e - base;
        if (m > 64) m = 64;
        for (int g0 = 0; g0 < m; g0 += 16) {
            const int e0 = g0 + q, e1 = g0 + 4 + q, e2 = g0 + 8 + q, e3 = g0 + 12 + q;
            const int r0 = __shfl(idx, e0), r1 = __shfl(idx, e1);
            const int r2 = __shfl(idx, e2), r3 = __shfl(idx, e3);
            const float4 v0 = bf4_to_f4(*(const ushort4*)(S + (size_t)r0 * F + fo));
            const float4 v1 = bf4_to_f4(*(const ushort4*)(S + (size_t)r1 * F + fo));
            const float4 v2 = bf4_to_f4(*(const ushort4*)(S + (size_t)r2 * F + fo));
            const float4 v3 = bf4_to_f4(*(const ushort4*)(S + (size_t)r3 * F + fo));
            if (g0 + 16 <= m) {  // full batch (wave-uniform branch)
                A0.x += v0.x; A0.y += v0.y; A0.z += v0.z; A0.w += v0.w;
                A1.x += v1.x; A1.y += v1.y; A1.z += v1.z; A1.w += v1.w;
                A2.x += v2.x; A2.y += v2.y; A2.z += v2.z; A2.w += v2.w;
                A3.x += v3.x; A3.y += v3.y; A3.z += v3.z; A3.w += v3.w;
            } else {
                const float s0 = e0 < m ? 1.f : 0.f, s1 = e1 < m ? 1.f : 0.f;
                const float s2 = e2 < m ? 1.f : 0.f, s3 = e3 < m ? 1.f : 0.f;
                A0.x += s0 * v0.x; A0.y += s0 * v0.y; A0.z += s0 * v0.z; A0.w += s0 * v0.w;
                A1.x += s1 * v1.x; A1.y += s1 * v1.y; A1.z += s1 * v1.z; A1.w += s1 * v1.w;
                A2.x += s2 * v2.x; A2.y += s2 * v2.y; A2.z += s2 * v2.z; A2.w += s2 * v2.w;
                A3.x += s3 * v3.x; A3.y += s3 * v3.y; A3.z += s3 * v3.z; A3.w += s3 * v3.w;
            }
        }
    }
    float4 t;
    t.x = (A0.x + A1.x) + (A2.x + A3.x);
    t.y = (A0.y + A1.y) + (A2.y + A3.y);
    t.z = (A0.z + A1.z) + (A2.z + A3.z);
    t.w = (A0.w + A1.w) + (A2.w + A3.w);
    t.x += __shfl_xor(t.x, 16); t.y += __shfl_xor(t.y, 16);
    t.z += __shfl_xor(t.z, 16); t.w += __shfl_xor(t.w, 16);
    t.x += __shfl_xor(t.x, 32); t.y += __shfl_xor(t.y, 32);
    t.z += __shfl_xor(t.z, 32); t.w += __shfl_xor(t.w, 32);
    const int sl = lane >> 2;
    const float vx = __shfl(t.x, sl), vy = __shfl(t.y, sl);
    const float vz = __shfl(t.z, sl), vw = __shfl(t.w, sl);
    const int c = lane & 3;
    return c == 0 ? vx : (c == 1 ? vy : (c == 2 ? vz : vw));
}

// GEMM epilogue: s = sum_i tb_row[i] * Wcol[i]  (tb_row broadcast via LDS b128 reads)
__device__ __forceinline__ float row_gemm(const float* __restrict__ tb_row,
                                          const float Wcol[F]) {
    float s0 = 0.f, s1 = 0.f, s2 = 0.f, s3 = 0.f;
#pragma unroll
    for (int j = 0; j < F; j += 16) {
        const float4 t0 = *(const float4*)(tb_row + j + 0);
        const float4 t1 = *(const float4*)(tb_row + j + 4);
        const float4 t2 = *(const float4*)(tb_row + j + 8);
        const float4 t3 = *(const float4*)(tb_row + j + 12);
        s0 += t0.x * Wcol[j + 0] + t0.y * Wcol[j + 1] + t0.z * Wcol[j + 2] + t0.w * Wcol[j + 3];
        s1 += t1.x * Wcol[j + 4] + t1.y * Wcol[j + 5] + t1.z * Wcol[j + 6] + t1.w * Wcol[j + 7];
        s2 += t2.x * Wcol[j + 8] + t2.y * Wcol[j + 9] + t2.z * Wcol[j + 10] + t2.w * Wcol[j + 11];
        s3 += t3.x * Wcol[j + 12] + t3.y * Wcol[j + 13] + t3.z * Wcol[j + 14] + t3.w * Wcol[j + 15];
    }
    return (s0 + s1) + (s2 + s3);
}

// init: S0b = bf16(dinv (.) x) ; out = b + x@W0
__global__ __launch_bounds__(WPB * 64, 4)
void init_kernel(const float* __restrict__ dinv, const float* __restrict__ x,
                 unsigned short* __restrict__ S0b, const float* __restrict__ W0,
                 const float* __restrict__ b, float* __restrict__ out, int N) {
    __shared__ float tb[WPB][F];
    const int lane = threadIdx.x & 63;
    const int wave = threadIdx.x >> 6;
    float Wcol[F];
#pragma unroll
    for (int i = 0; i < F; ++i) Wcol[i] = W0[i * F + lane];
    const float bl = b[lane];
    const int wbase = blockIdx.x * (WPB * NPW) + wave * NPW;
    for (int it = 0; it < NPW; ++it) {
        const int n = wbase + it;
        if (n >= N) break;
        const size_t o = (size_t)n * F + lane;
        const float xv = x[o];
        S0b[o] = f_to_bf(dinv[n] * xv);
        tb[wave][lane] = xv;
        const float s = row_gemm(tb[wave], Wcol);
        out[o] = bl + s;
    }
}

// k=1: S1 = -dinv^2 * gather(S0); out += Tx1@W1, Tx1 = -dinv * gather(S0)
__global__ __launch_bounds__(WPB * 64, 4)
void prop_first_kernel(const int* __restrict__ rowptr, const int* __restrict__ csr,
                       const float* __restrict__ dinv, const unsigned short* __restrict__ S0b,
                       unsigned short* __restrict__ S1b, const float* __restrict__ W1,
                       float* __restrict__ out, int N) {
    __shared__ float tb[WPB][F];
    const int lane = threadIdx.x & 63;
    const int wave = threadIdx.x >> 6;
    float Wcol[F];
#pragma unroll
    for (int i = 0; i < F; ++i) Wcol[i] = W1[i * F + lane];
    const int wbase = blockIdx.x * (WPB * NPW) + wave * NPW;
    for (int it = 0; it < NPW; ++it) {
        const int n = wbase + it;
        if (n >= N) break;
        const int s = rowptr[n], e = rowptr[n + 1];
        const float u = gather_sum_bf(csr, s, e, S0b, lane);
        const float dv = dinv[n];
        const float t1 = -dv * u;
        const size_t o = (size_t)n * F + lane;
        S1b[o] = f_to_bf(dv * t1);
        tb[wave][lane] = t1;
        const float g = row_gemm(tb[wave], Wcol);
        out[o] += g;
    }
}

// k>=2: snew = -2*dinv^2*gather(Sprev) - Sown; Sown = snew (in place, bf16);
// t = snew*rdinv (analytic for deg-0); out += t@Wk; optional relu
__global__ __launch_bounds__(WPB * 64, 4)
void prop_step_kernel(const int* __restrict__ rowptr, const int* __restrict__ csr,
                      const float* __restrict__ dinv2, const float* __restrict__ rdinv,
                      const float* __restrict__ x, const unsigned short* __restrict__ Sprevb,
                      unsigned short* __restrict__ Sownb, const float* __restrict__ Wk,
                      float* __restrict__ out, int N, float zcoef, int final_relu) {
    __shared__ float tb[WPB][F];
    const int lane = threadIdx.x & 63;
    const int wave = threadIdx.x >> 6;
    float Wcol[F];
#pragma unroll
    for (int i = 0; i < F; ++i) Wcol[i] = Wk[i * F + lane];
    const int wbase = blockIdx.x * (WPB * NPW) + wave * NPW;
    for (int it = 0; it < NPW; ++it) {
        const int n = wbase + it;
        if (n >= N) break;
        const int s = rowptr[n], e = rowptr[n + 1];
        const float u = gather_sum_bf(csr, s, e, Sprevb, lane);
        const size_t o = (size_t)n * F + lane;
        const float d2 = dinv2[n];
        const float own = bf_to_f(Sownb[o]);
        const float snew = -2.0f * d2 * u - own;
        Sownb[o] = f_to_bf(snew);
        const float t = (d2 > 0.0f) ? snew * rdinv[n] : zcoef * x[o];
        tb[wave][lane] = t;
        const float g = row_gemm(tb[wave], Wcol);
        float r = out[o] + g;
        if (final_relu) r = fmaxf(r, 0.f);
        out[o] = r;
    }
}

extern "C" void kernel_launch(void* const* d_in, const int* in_sizes, int n_in,
                              void* d_out, int out_size, void* d_ws, size_t ws_size,
                              hipStream_t stream) {
    const float* x = (const float*)d_in[0];
    const int* ei = (const int*)d_in[1];
    const float* W = (const float*)d_in[2];
    const float* b = (const float*)d_in[3];

    const int N = in_sizes[0] / F;
    const int E = in_sizes[1] / 2;
    const int* row = ei;      // sources j
    const int* col = ei + E;  // targets i

    // workspace layout
    int*   deg4   = (int*)d_ws;                // 4N (memset with cnt4)
    int*   cnt4   = deg4 + NSHADOW * (size_t)N;        // 4N
    float* dinv   = (float*)(cnt4 + NSHADOW * (size_t)N);  // N
    float* dinv2  = dinv + N;                  // N
    float* rdinv  = dinv2 + N;                 // N
    int*   cnt    = (int*)(rdinv + N);         // N
    int*   rowptr = cnt + N;                   // N+1
    int*   cursor = rowptr + N + 1;            // N
    int*   bsum   = cursor + N;                // 256
    int*   boff   = bsum + 256;                // 256
    int*   csr    = boff + 256;                // E
    unsigned short* SAb = (unsigned short*)(csr + E);   // N*F bf16
    unsigned short* SBb = SAb + (size_t)N * F;          // N*F bf16
    float* out    = (float*)d_out;             // N*F

    const int B = 256;
    const int pgrid = (N + WPB * NPW - 1) / (WPB * NPW);
    const int nsb = (N + SCAN_ELEMS - 1) / SCAN_ELEMS;  // 98 (<= 256 required)

    hipMemsetAsync(deg4, 0, (size_t)2 * NSHADOW * N * sizeof(int), stream);
    deg_cnt_kernel<<<(E / 4 + B - 1) / B, B, 0, stream>>>(row, col, deg4, cnt4, N, E);
    reduce_dinv_kernel<<<(N + B - 1) / B, B, 0, stream>>>(deg4, cnt4, dinv, dinv2, rdinv, cnt, N);
    scan1_kernel<<<nsb, B, 0, stream>>>(cnt, bsum, N);
    scan2_kernel<<<1, B, 0, stream>>>(bsum, boff, rowptr + N, nsb);
    scan3_kernel<<<nsb, B, 0, stream>>>(cnt, boff, rowptr, cursor, N);
    fill_kernel<<<(E + B - 1) / B, B, 0, stream>>>(row, col, cursor, csr, E);

    // S0 -> SAb ; out = b + x@W0
    init_kernel<<<pgrid, WPB * 64, 0, stream>>>(dinv, x, SAb, W, b, out, N);
    // k=1: S1 -> SBb ; out += Tx1@W1
    prop_first_kernel<<<pgrid, WPB * 64, 0, stream>>>(rowptr, csr, dinv, SAb, SBb,
                                                      W + 1 * F * F, out, N);
    // k=2: gather SBb, own SAb (deg-0 rows: Tx2 = -x)
    prop_step_kernel<<<pgrid, WPB * 64, 0, stream>>>(rowptr, csr, dinv2, rdinv, x, SBb, SAb,
                                                     W + 2 * F * F, out, N, -1.0f, 0);
    // k=3: gather SAb, own SBb (deg-0: 0)
    prop_step_kernel<<<pgrid, WPB * 64, 0, stream>>>(rowptr, csr, dinv2, rdinv, x, SAb, SBb,
                                                     W + 3 * F * F, out, N, 0.0f, 0);
    // k=4: gather SBb, own SAb (deg-0: +x)
    prop_step_kernel<<<pgrid, WPB * 64, 0, stream>>>(rowptr, csr, dinv2, rdinv, x, SBb, SAb,
                                                     W + 4 * F * F, out, N, 1.0f, 0);
    // k=5: gather SAb, own SBb (deg-0: 0) + relu
    prop_step_kernel<<<pgrid, WPB * 64, 0, stream>>>(rowptr, csr, dinv2, rdinv, x, SAb, SBb,
                                                     W + 5 * F * F, out, N, 0.0f, 1);
}

// Round 8
// 708.882 us; speedup vs baseline: 10.1920x; 1.1379x over previous
//
#include <hip/hip_runtime.h>

// ChebConv K=6, sym norm, lambda_max=2 => L_hat = -D^{-1/2} A D^{-1/2}
// N=100000, E=1600000, F=64.
// R8: (1) atomic-free fill: deg_cnt's cnt-atomic RETURN value = edge rank in
// its dst segment -> csr[rowptr[col]+rank] = row, no cursor atomics.
// (2) lean gather props (no W epilogue, occupancy 6 waves/EU) writing an
// S_k bf16 stack + ONE final GEMM out = relu(b + sum_k t_k @ W_k).
// Falls back to R7-style fused props if ws_size is too small (call-invariant).

constexpr int F = 64;
constexpr int WPB = 4;        // waves per block (prop/gemm kernels)
constexpr int NPW = 8;        // nodes per wave
constexpr int SCAN_ELEMS = 1024;

__device__ __forceinline__ unsigned short f_to_bf(float f) {
    unsigned u = __float_as_uint(f);
    u += 0x7FFFu + ((u >> 16) & 1u);  // RNE
    return (unsigned short)(u >> 16);
}
__device__ __forceinline__ float bf_to_f(unsigned short s) {
    return __uint_as_float(((unsigned)s) << 16);
}
__device__ __forceinline__ float4 bf4_to_f4(ushort4 u) {
    float4 f;
    f.x = bf_to_f(u.x); f.y = bf_to_f(u.y); f.z = bf_to_f(u.z); f.w = bf_to_f(u.w);
    return f;
}

// histograms: deg (out-degree of row); cnt (in-degree of col) whose atomic
// return value is the edge's rank within its destination segment.
__global__ void deg_cnt_kernel(const int* __restrict__ row, const int* __restrict__ col,
                               int* __restrict__ deg, int* __restrict__ cnt,
                               int* __restrict__ rank, int E) {
    const int t = blockIdx.x * blockDim.x + threadIdx.x;
    const int e = t * 4;
    if (e >= E) return;
    if (e + 3 < E) {
        const int4 r = *(const int4*)(row + e);
        const int4 c = *(const int4*)(col + e);
        atomicAdd(&deg[r.x], 1);
        atomicAdd(&deg[r.y], 1);
        atomicAdd(&deg[r.z], 1);
        atomicAdd(&deg[r.w], 1);
        int4 k;
        k.x = atomicAdd(&cnt[c.x], 1);
        k.y = atomicAdd(&cnt[c.y], 1);
        k.z = atomicAdd(&cnt[c.z], 1);
        k.w = atomicAdd(&cnt[c.w], 1);
        *(int4*)(rank + e) = k;
    } else {
        for (int k = e; k < E; ++k) {
            atomicAdd(&deg[row[k]], 1);
            rank[k] = atomicAdd(&cnt[col[k]], 1);
        }
    }
}

__global__ void dinv_kernel(const int* __restrict__ deg, float* __restrict__ dinv,
                            float* __restrict__ dinv2, float* __restrict__ rdinv, int N) {
    int i = blockIdx.x * blockDim.x + threadIdx.x;
    if (i >= N) return;
    int dI = deg[i];
    float d = (float)dI;
    bool ok = dI > 0;
    dinv[i]  = ok ? rsqrtf(d) : 0.0f;
    dinv2[i] = ok ? 1.0f / d : 0.0f;
    rdinv[i] = ok ? sqrtf(d) : 0.0f;
}

__device__ __forceinline__ int4 load_cnt4(const int* __restrict__ cnt, int i, int N) {
    int4 v = make_int4(0, 0, 0, 0);
    if (i + 3 < N) {
        v = *(const int4*)(cnt + i);
    } else {
        if (i + 0 < N) v.x = cnt[i + 0];
        if (i + 1 < N) v.y = cnt[i + 1];
        if (i + 2 < N) v.z = cnt[i + 2];
        if (i + 3 < N) v.w = cnt[i + 3];
    }
    return v;
}

__global__ void scan1_kernel(const int* __restrict__ cnt, int* __restrict__ bsum, int N) {
    const int tid = threadIdx.x;
    const int i = blockIdx.x * SCAN_ELEMS + tid * 4;
    int4 v = load_cnt4(cnt, i, N);
    int s = v.x + v.y + v.z + v.w;
#pragma unroll
    for (int off = 1; off < 64; off <<= 1) s += __shfl_xor(s, off);
    __shared__ int ws[4];
    if ((tid & 63) == 0) ws[tid >> 6] = s;
    __syncthreads();
    if (tid == 0) bsum[blockIdx.x] = ws[0] + ws[1] + ws[2] + ws[3];
}

__global__ void scan2_kernel(const int* __restrict__ bsum, int* __restrict__ boff,
                             int* __restrict__ rowptr_last, int nb) {
    const int tid = threadIdx.x;  // 256
    const int lane = tid & 63, w = tid >> 6;
    int v = (tid < nb) ? bsum[tid] : 0;
    int inc = v;
#pragma unroll
    for (int off = 1; off < 64; off <<= 1) {
        int t = __shfl_up(inc, off);
        if (lane >= off) inc += t;
    }
    __shared__ int wsum[4];
    if (lane == 63) wsum[w] = inc;
    __syncthreads();
    int wo = 0;
    for (int k = 0; k < w; ++k) wo += wsum[k];
    const int excl = wo + inc - v;
    if (tid < nb) boff[tid] = excl;
    if (tid == nb - 1) *rowptr_last = excl + v;  // == E
}

__global__ void scan3_kernel(const int* __restrict__ cnt, const int* __restrict__ boff,
                             int* __restrict__ rowptr, int N) {
    const int tid = threadIdx.x;
    const int lane = tid & 63, w = tid >> 6;
    const int i = blockIdx.x * SCAN_ELEMS + tid * 4;
    int4 v = load_cnt4(cnt, i, N);
    const int s = v.x + v.y + v.z + v.w;
    int inc = s;
#pragma unroll
    for (int off = 1; off < 64; off <<= 1) {
        int t = __shfl_up(inc, off);
        if (lane >= off) inc += t;
    }
    __shared__ int wsum[4];
    if (lane == 63) wsum[w] = inc;
    __syncthreads();
    int wo = 0;
    for (int k = 0; k < w; ++k) wo += wsum[k];
    const int r0 = boff[blockIdx.x] + wo + inc - s;
    const int r1 = r0 + v.x, r2 = r1 + v.y, r3 = r2 + v.z;
    if (i + 3 < N) {
        *(int4*)(rowptr + i) = make_int4(r0, r1, r2, r3);
    } else {
        if (i + 0 < N) rowptr[i + 0] = r0;
        if (i + 1 < N) rowptr[i + 1] = r1;
        if (i + 2 < N) rowptr[i + 2] = r2;
        if (i + 3 < N) rowptr[i + 3] = r3;
    }
}

// atomic-free counting-sort fill
__global__ void fill_kernel(const int* __restrict__ row, const int* __restrict__ col,
                            const int* __restrict__ rank, const int* __restrict__ rowptr,
                            int* __restrict__ csr, int E) {
    const int t = blockIdx.x * blockDim.x + threadIdx.x;
    const int e = t * 4;
    if (e >= E) return;
    if (e + 3 < E) {
        const int4 r = *(const int4*)(row + e);
        const int4 c = *(const int4*)(col + e);
        const int4 k = *(const int4*)(rank + e);
        csr[rowptr[c.x] + k.x] = r.x;
        csr[rowptr[c.y] + k.y] = r.y;
        csr[rowptr[c.z] + k.z] = r.z;
        csr[rowptr[c.w] + k.w] = r.w;
    } else {
        for (int k = e; k < E; ++k) csr[rowptr[col[k]] + rank[k]] = row[k];
    }
}

// S0 = bf16(dinv (.) x), vectorized
__global__ void init_s0_kernel(const float* __restrict__ dinv, const float* __restrict__ x,
                               unsigned short* __restrict__ S0b, int NF) {
    int i = blockIdx.x * blockDim.x + threadIdx.x;
    int j = i * 4;
    if (j >= NF) return;
    const float dv = dinv[j >> 6];
    const float4 v = *(const float4*)(x + j);
    ushort4 u;
    u.x = f_to_bf(dv * v.x); u.y = f_to_bf(dv * v.y);
    u.z = f_to_bf(dv * v.z); u.w = f_to_bf(dv * v.w);
    *(ushort4*)(S0b + j) = u;
}

// Gather-sum over in-edges: u[lane] = sum_{src} S[src, lane], S in bf16.
__device__ __forceinline__ float gather_sum_bf(const int* __restrict__ csr, int s, int e,
                                               const unsigned short* __restrict__ S, int lane) {
    const int q = lane >> 4;
    const int fo = (lane & 15) * 4;
    float4 A0 = {0, 0, 0, 0}, A1 = {0, 0, 0, 0}, A2 = {0, 0, 0, 0}, A3 = {0, 0, 0, 0};
    for (int base = s; base < e; base += 64) {
        int li = base + lane;
        int idx = csr[li < e ? li : e - 1];
        int m = e - base;
        if (m > 64) m = 64;
        for (int g0 = 0; g0 < m; g0 += 16) {
            const int e0 = g0 + q, e1 = g0 + 4 + q, e2 = g0 + 8 + q, e3 = g0 + 12 + q;
            const int r0 = __shfl(idx, e0), r1 = __shfl(idx, e1);
            const int r2 = __shfl(idx, e2), r3 = __shfl(idx, e3);
            const float4 v0 = bf4_to_f4(*(const ushort4*)(S + (size_t)r0 * F + fo));
            const float4 v1 = bf4_to_f4(*(const ushort4*)(S + (size_t)r1 * F + fo));
            const float4 v2 = bf4_to_f4(*(const ushort4*)(S + (size_t)r2 * F + fo));
            const float4 v3 = bf4_to_f4(*(const ushort4*)(S + (size_t)r3 * F + fo));
            if (g0 + 16 <= m) {
                A0.x += v0.x; A0.y += v0.y; A0.z += v0.z; A0.w += v0.w;
                A1.x += v1.x; A1.y += v1.y; A1.z += v1.z; A1.w += v1.w;
                A2.x += v2.x; A2.y += v2.y; A2.z += v2.z; A2.w += v2.w;
                A3.x += v3.x; A3.y += v3.y; A3.z += v3.z; A3.w += v3.w;
            } else {
                const float s0 = e0 < m ? 1.f : 0.f, s1 = e1 < m ? 1.f : 0.f;
                const float s2 = e2 < m ? 1.f : 0.f, s3 = e3 < m ? 1.f : 0.f;
                A0.x += s0 * v0.x; A0.y += s0 * v0.y; A0.z += s0 * v0.z; A0.w += s0 * v0.w;
                A1.x += s1 * v1.x; A1.y += s1 * v1.y; A1.z += s1 * v1.z; A1.w += s1 * v1.w;
                A2.x += s2 * v2.x; A2.y += s2 * v2.y; A2.z += s2 * v2.z; A2.w += s2 * v2.w;
                A3.x += s3 * v3.x; A3.y += s3 * v3.y; A3.z += s3 * v3.z; A3.w += s3 * v3.w;
            }
        }
    }
    float4 t;
    t.x = (A0.x + A1.x) + (A2.x + A3.x);
    t.y = (A0.y + A1.y) + (A2.y + A3.y);
    t.z = (A0.z + A1.z) + (A2.z + A3.z);
    t.w = (A0.w + A1.w) + (A2.w + A3.w);
    t.x += __shfl_xor(t.x, 16); t.y += __shfl_xor(t.y, 16);
    t.z += __shfl_xor(t.z, 16); t.w += __shfl_xor(t.w, 16);
    t.x += __shfl_xor(t.x, 32); t.y += __shfl_xor(t.y, 32);
    t.z += __shfl_xor(t.z, 32); t.w += __shfl_xor(t.w, 32);
    const int sl = lane >> 2;
    const float vx = __shfl(t.x, sl), vy = __shfl(t.y, sl);
    const float vz = __shfl(t.z, sl), vw = __shfl(t.w, sl);
    const int c = lane & 3;
    return c == 0 ? vx : (c == 1 ? vy : (c == 2 ? vz : vw));
}

// ---- Path A: lean props + final GEMM ----

// k=1: S1 = bf16(-dinv^2 * gather(S0))
__global__ __launch_bounds__(WPB * 64, 6)
void prop1_lean(const int* __restrict__ rowptr, const int* __restrict__ csr,
                const float* __restrict__ dinv2, const unsigned short* __restrict__ S0b,
                unsigned short* __restrict__ S1b, int N) {
    const int lane = threadIdx.x & 63;
    const int wbase = blockIdx.x * (WPB * NPW) + (threadIdx.x >> 6) * NPW;
    for (int it = 0; it < NPW; ++it) {
        const int n = wbase + it;
        if (n >= N) break;
        const float u = gather_sum_bf(csr, rowptr[n], rowptr[n + 1], S0b, lane);
        S1b[(size_t)n * F + lane] = f_to_bf(-dinv2[n] * u);
    }
}

// k>=2: Sk = bf16(-2*dinv^2 * gather(S_{k-1}) - S_{k-2})
__global__ __launch_bounds__(WPB * 64, 6)
void prop_lean(const int* __restrict__ rowptr, const int* __restrict__ csr,
               const float* __restrict__ dinv2, const unsigned short* __restrict__ Sprev,
               const unsigned short* __restrict__ Sm2, unsigned short* __restrict__ Sk, int N) {
    const int lane = threadIdx.x & 63;
    const int wbase = blockIdx.x * (WPB * NPW) + (threadIdx.x >> 6) * NPW;
    for (int it = 0; it < NPW; ++it) {
        const int n = wbase + it;
        if (n >= N) break;
        const float u = gather_sum_bf(csr, rowptr[n], rowptr[n + 1], Sprev, lane);
        const size_t o = (size_t)n * F + lane;
        Sk[o] = f_to_bf(-2.0f * dinv2[n] * u - bf_to_f(Sm2[o]));
    }
}

__device__ __forceinline__ float row_gemm(const float* __restrict__ tb_row,
                                          const float Wcol[F]) {
    float s0 = 0.f, s1 = 0.f, s2 = 0.f, s3 = 0.f;
#pragma unroll
    for (int j = 0; j < F; j += 16) {
        const float4 t0 = *(const float4*)(tb_row + j + 0);
        const float4 t1 = *(const float4*)(tb_row + j + 4);
        const float4 t2 = *(const float4*)(tb_row + j + 8);
        const float4 t3 = *(const float4*)(tb_row + j + 12);
        s0 += t0.x * Wcol[j + 0] + t0.y * Wcol[j + 1] + t0.z * Wcol[j + 2] + t0.w * Wcol[j + 3];
        s1 += t1.x * Wcol[j + 4] + t1.y * Wcol[j + 5] + t1.z * Wcol[j + 6] + t1.w * Wcol[j + 7];
        s2 += t2.x * Wcol[j + 8] + t2.y * Wcol[j + 9] + t2.z * Wcol[j + 10] + t2.w * Wcol[j + 11];
        s3 += t3.x * Wcol[j + 12] + t3.y * Wcol[j + 13] + t3.z * Wcol[j + 14] + t3.w * Wcol[j + 15];
    }
    return (s0 + s1) + (s2 + s3);
}

// out = relu(b + x@W0 + sum_{k=1..5} t_k@Wk), t_k = S_k*rdinv (deg-0: pattern*x)
__global__ __launch_bounds__(WPB * 64, 4)
void final_gemm_kernel(const float* __restrict__ x, const unsigned short* __restrict__ Sstack,
                       const float* __restrict__ rdinv, const float* __restrict__ dinv2,
                       const float* __restrict__ W, const float* __restrict__ b,
                       float* __restrict__ out, int N, int NF) {
    __shared__ float tb[WPB][F];
    const int lane = threadIdx.x & 63;
    const int wave = threadIdx.x >> 6;
    const int wbase = blockIdx.x * (WPB * NPW) + wave * NPW;
    float acc[NPW];
#pragma unroll
    for (int it = 0; it < NPW; ++it) acc[it] = 0.f;
    const float pat[6] = {0.f, 0.f, -1.f, 0.f, 1.f, 0.f};  // deg-0 Tx_k = pat*x
    for (int k = 0; k < 6; ++k) {
        float Wcol[F];
#pragma unroll
        for (int i = 0; i < F; ++i) Wcol[i] = W[k * F * F + i * F + lane];
#pragma unroll
        for (int it = 0; it < NPW; ++it) {
            const int n = wbase + it;
            if (n >= N) continue;
            const size_t o = (size_t)n * F + lane;
            float t;
            if (k == 0) {
                t = x[o];
            } else {
                const bool ok = dinv2[n] > 0.0f;
                t = ok ? bf_to_f(Sstack[(size_t)(k)*NF + o]) * rdinv[n] : pat[k] * x[o];
            }
            tb[wave][lane] = t;
            acc[it] += row_gemm(tb[wave], Wcol);
        }
    }
    const float bl = b[lane];
#pragma unroll
    for (int it = 0; it < NPW; ++it) {
        const int n = wbase + it;
        if (n >= N) continue;
        out[(size_t)n * F + lane] = fmaxf(acc[it] + bl, 0.f);
    }
}

// ---- Path B (small ws fallback): R7-style fused props ----

__global__ __launch_bounds__(WPB * 64, 4)
void init_kernel(const float* __restrict__ dinv, const float* __restrict__ x,
                 unsigned short* __restrict__ S0b, const float* __restrict__ W0,
                 const float* __restrict__ b, float* __restrict__ out, int N) {
    __shared__ float tb[WPB][F];
    const int lane = threadIdx.x & 63;
    const int wave = threadIdx.x >> 6;
    float Wcol[F];
#pragma unroll
    for (int i = 0; i < F; ++i) Wcol[i] = W0[i * F + lane];
    const float bl = b[lane];
    const int wbase = blockIdx.x * (WPB * NPW) + wave * NPW;
    for (int it = 0; it < NPW; ++it) {
        const int n = wbase + it;
        if (n >= N) break;
        const size_t o = (size_t)n * F + lane;
        const float xv = x[o];
        S0b[o] = f_to_bf(dinv[n] * xv);
        tb[wave][lane] = xv;
        out[o] = bl + row_gemm(tb[wave], Wcol);
    }
}

__global__ __launch_bounds__(WPB * 64, 4)
void prop_first_kernel(const int* __restrict__ rowptr, const int* __restrict__ csr,
                       const float* __restrict__ dinv, const unsigned short* __restrict__ S0b,
                       unsigned short* __restrict__ S1b, const float* __restrict__ W1,
                       float* __restrict__ out, int N) {
    __shared__ float tb[WPB][F];
    const int lane = threadIdx.x & 63;
    const int wave = threadIdx.x >> 6;
    float Wcol[F];
#pragma unroll
    for (int i = 0; i < F; ++i) Wcol[i] = W1[i * F + lane];
    const int wbase = blockIdx.x * (WPB * NPW) + wave * NPW;
    for (int it = 0; it < NPW; ++it) {
        const int n = wbase + it;
        if (n >= N) break;
        const float u = gather_sum_bf(csr, rowptr[n], rowptr[n + 1], S0b, lane);
        const float dv = dinv[n];
        const float t1 = -dv * u;
        const size_t o = (size_t)n * F + lane;
        S1b[o] = f_to_bf(dv * t1);
        tb[wave][lane] = t1;
        out[o] += row_gemm(tb[wave], Wcol);
    }
}

__global__ __launch_bounds__(WPB * 64, 4)
void prop_step_kernel(const int* __restrict__ rowptr, const int* __restrict__ csr,
                      const float* __restrict__ dinv2, const float* __restrict__ rdinv,
                      const float* __restrict__ x, const unsigned short* __restrict__ Sprevb,
                      unsigned short* __restrict__ Sownb, const float* __restrict__ Wk,
                      float* __restrict__ out, int N, float zcoef, int final_relu) {
    __shared__ float tb[WPB][F];
    const int lane = threadIdx.x & 63;
    const int wave = threadIdx.x >> 6;
    float Wcol[F];
#pragma unroll
    for (int i = 0; i < F; ++i) Wcol[i] = Wk[i * F + lane];
    const int wbase = blockIdx.x * (WPB * NPW) + wave * NPW;
    for (int it = 0; it < NPW; ++it) {
        const int n = wbase + it;
        if (n >= N) break;
        const float u = gather_sum_bf(csr, rowptr[n], rowptr[n + 1], Sprevb, lane);
        const size_t o = (size_t)n * F + lane;
        const float d2 = dinv2[n];
        const float snew = -2.0f * d2 * u - bf_to_f(Sownb[o]);
        Sownb[o] = f_to_bf(snew);
        const float t = (d2 > 0.0f) ? snew * rdinv[n] : zcoef * x[o];
        tb[wave][lane] = t;
        float r = out[o] + row_gemm(tb[wave], Wcol);
        if (final_relu) r = fmaxf(r, 0.f);
        out[o] = r;
    }
}

extern "C" void kernel_launch(void* const* d_in, const int* in_sizes, int n_in,
                              void* d_out, int out_size, void* d_ws, size_t ws_size,
                              hipStream_t stream) {
    const float* x = (const float*)d_in[0];
    const int* ei = (const int*)d_in[1];
    const float* W = (const float*)d_in[2];
    const float* b = (const float*)d_in[3];

    const int N = in_sizes[0] / F;
    const int E = in_sizes[1] / 2;
    const int NF = N * F;
    const int* row = ei;      // sources j
    const int* col = ei + E;  // targets i

    // workspace allocator (64B-aligned chunks)
    char* p = (char*)d_ws;
    auto alloc = [&](size_t bytes) {
        char* r = p;
        p += (bytes + 63) & ~(size_t)63;
        return r;
    };
    int*   deg    = (int*)alloc((size_t)2 * N * sizeof(int));  // deg + cnt contiguous
    int*   cnt    = deg + N;
    float* dinv   = (float*)alloc((size_t)N * sizeof(float));
    float* dinv2  = (float*)alloc((size_t)N * sizeof(float));
    float* rdinv  = (float*)alloc((size_t)N * sizeof(float));
    int*   rowptr = (int*)alloc((size_t)(N + 1) * sizeof(int));
    int*   bsum   = (int*)alloc(256 * sizeof(int));
    int*   boff   = (int*)alloc(256 * sizeof(int));
    int*   csr    = (int*)alloc((size_t)E * sizeof(int));
    const size_t common_used = (size_t)(p - (char*)d_ws);
    const size_t stackA = (size_t)6 * NF * sizeof(unsigned short);
    const bool pathA = ws_size >= common_used + stackA + ((size_t)E + 64) * sizeof(int) / 1;  // rank aliased, margin
    float* out = (float*)d_out;

    const int B = 256;
    const int pgrid = (N + WPB * NPW - 1) / (WPB * NPW);
    const int nsb = (N + SCAN_ELEMS - 1) / SCAN_ELEMS;
    const int egrid4 = (E / 4 + B - 1) / B;

    if (pathA) {
        unsigned short* Sstack = (unsigned short*)alloc(stackA);  // S0..S5
        unsigned short* S0b = Sstack;
        // rank aliased into S5 (written only by the last prop, long after fill)
        int* rank = (int*)(Sstack + (size_t)5 * NF);

        hipMemsetAsync(deg, 0, (size_t)2 * N * sizeof(int), stream);
        deg_cnt_kernel<<<egrid4, B, 0, stream>>>(row, col, deg, cnt, rank, E);
        dinv_kernel<<<(N + B - 1) / B, B, 0, stream>>>(deg, dinv, dinv2, rdinv, N);
        scan1_kernel<<<nsb, B, 0, stream>>>(cnt, bsum, N);
        scan2_kernel<<<1, B, 0, stream>>>(bsum, boff, rowptr + N, nsb);
        scan3_kernel<<<nsb, B, 0, stream>>>(cnt, boff, rowptr, N);
        fill_kernel<<<egrid4, B, 0, stream>>>(row, col, rank, rowptr, csr, E);

        init_s0_kernel<<<(NF / 4 + B - 1) / B, B, 0, stream>>>(dinv, x, S0b, NF);
        prop1_lean<<<pgrid, WPB * 64, 0, stream>>>(rowptr, csr, dinv2, S0b,
                                                   Sstack + (size_t)1 * NF, N);
        for (int k = 2; k < 6; ++k) {
            prop_lean<<<pgrid, WPB * 64, 0, stream>>>(
                rowptr, csr, dinv2, Sstack + (size_t)(k - 1) * NF,
                Sstack + (size_t)(k - 2) * NF, Sstack + (size_t)k * NF, N);
        }
        final_gemm_kernel<<<pgrid, WPB * 64, 0, stream>>>(x, Sstack, rdinv, dinv2, W, b,
                                                          out, N, NF);
    } else {
        unsigned short* SAb = (unsigned short*)alloc((size_t)NF * sizeof(unsigned short));
        unsigned short* SBb = (unsigned short*)alloc((size_t)NF * sizeof(unsigned short));
        int* rank = (int*)SAb;  // dead before init_kernel writes SAb

        hipMemsetAsync(deg, 0, (size_t)2 * N * sizeof(int), stream);
        deg_cnt_kernel<<<egrid4, B, 0, stream>>>(row, col, deg, cnt, rank, E);
        dinv_kernel<<<(N + B - 1) / B, B, 0, stream>>>(deg, dinv, dinv2, rdinv, N);
        scan1_kernel<<<nsb, B, 0, stream>>>(cnt, bsum, N);
        scan2_kernel<<<1, B, 0, stream>>>(bsum, boff, rowptr + N, nsb);
        scan3_kernel<<<nsb, B, 0, stream>>>(cnt, boff, rowptr, N);
        fill_kernel<<<egrid4, B, 0, stream>>>(row, col, rank, rowptr, csr, E);

        init_kernel<<<pgrid, WPB * 64, 0, stream>>>(dinv, x, SAb, W, b, out, N);
        prop_first_kernel<<<pgrid, WPB * 64, 0, stream>>>(rowptr, csr, dinv, SAb, SBb,
                                                          W + 1 * F * F, out, N);
        prop_step_kernel<<<pgrid, WPB * 64, 0, stream>>>(rowptr, csr, dinv2, rdinv, x, SBb, SAb,
                                                         W + 2 * F * F, out, N, -1.0f, 0);
        prop_step_kernel<<<pgrid, WPB * 64, 0, stream>>>(rowptr, csr, dinv2, rdinv, x, SAb, SBb,
                                                         W + 3 * F * F, out, N, 0.0f, 0);
        prop_step_kernel<<<pgrid, WPB * 64, 0, stream>>>(rowptr, csr, dinv2, rdinv, x, SBb, SAb,
                                                         W + 4 * F * F, out, N, 1.0f, 0);
        prop_step_kernel<<<pgrid, WPB * 64, 0, stream>>>(rowptr, csr, dinv2, rdinv, x, SAb, SBb,
                                                         W + 5 * F * F, out, N, 0.0f, 1);
    }
}

// Round 9
// 587.958 us; speedup vs baseline: 12.2881x; 1.2057x over previous
//
#include <hip/hip_runtime.h>

// ChebConv K=6, sym norm, lambda_max=2 => L_hat = -D^{-1/2} A D^{-1/2}
// N=100000, E=1600000, F=64.
// R9: final output stage rewritten as bf16 MFMA GEMM (16x16x32):
//   A = [x | S1..S5] (Nx384, S raw bf16 - no rescale rounding),
//   B = bf16(W) pre-swizzled into fragment order (49KB, L2-broadcast),
//   two accumulators: C0 = x@W0, C1 = sum_k Sk@Wk;
//   out = relu(C0 + rdinv*C1 + b) (+ exec-masked deg-0 fixup x@(W4-W2)).
// Build pipeline (rank-based atomic-free fill) and lean props unchanged.

constexpr int F = 64;
constexpr int WPB = 4;        // waves per block (prop kernels)
constexpr int NPW = 8;        // nodes per wave
constexpr int SCAN_ELEMS = 1024;

typedef __attribute__((ext_vector_type(8))) short short8;
typedef __attribute__((ext_vector_type(4))) float floatx4;

__device__ __forceinline__ unsigned short f_to_bf(float f) {
    unsigned u = __float_as_uint(f);
    u += 0x7FFFu + ((u >> 16) & 1u);  // RNE
    return (unsigned short)(u >> 16);
}
__device__ __forceinline__ float bf_to_f(unsigned short s) {
    return __uint_as_float(((unsigned)s) << 16);
}
__device__ __forceinline__ float4 bf4_to_f4(ushort4 u) {
    float4 f;
    f.x = bf_to_f(u.x); f.y = bf_to_f(u.y); f.z = bf_to_f(u.z); f.w = bf_to_f(u.w);
    return f;
}

// histograms: deg (out-degree of row); cnt (in-degree of col) whose atomic
// return value is the edge's rank within its destination segment.
__global__ void deg_cnt_kernel(const int* __restrict__ row, const int* __restrict__ col,
                               int* __restrict__ deg, int* __restrict__ cnt,
                               int* __restrict__ rank, int E) {
    const int t = blockIdx.x * blockDim.x + threadIdx.x;
    const int e = t * 4;
    if (e >= E) return;
    if (e + 3 < E) {
        const int4 r = *(const int4*)(row + e);
        const int4 c = *(const int4*)(col + e);
        atomicAdd(&deg[r.x], 1);
        atomicAdd(&deg[r.y], 1);
        atomicAdd(&deg[r.z], 1);
        atomicAdd(&deg[r.w], 1);
        int4 k;
        k.x = atomicAdd(&cnt[c.x], 1);
        k.y = atomicAdd(&cnt[c.y], 1);
        k.z = atomicAdd(&cnt[c.z], 1);
        k.w = atomicAdd(&cnt[c.w], 1);
        *(int4*)(rank + e) = k;
    } else {
        for (int k = e; k < E; ++k) {
            atomicAdd(&deg[row[k]], 1);
            rank[k] = atomicAdd(&cnt[col[k]], 1);
        }
    }
}

__global__ void dinv_kernel(const int* __restrict__ deg, float* __restrict__ dinv,
                            float* __restrict__ dinv2, float* __restrict__ rdinv, int N) {
    int i = blockIdx.x * blockDim.x + threadIdx.x;
    if (i >= N) return;
    int dI = deg[i];
    float d = (float)dI;
    bool ok = dI > 0;
    dinv[i]  = ok ? rsqrtf(d) : 0.0f;
    dinv2[i] = ok ? 1.0f / d : 0.0f;
    rdinv[i] = ok ? sqrtf(d) : 0.0f;
}

__device__ __forceinline__ int4 load_cnt4(const int* __restrict__ cnt, int i, int N) {
    int4 v = make_int4(0, 0, 0, 0);
    if (i + 3 < N) {
        v = *(const int4*)(cnt + i);
    } else {
        if (i + 0 < N) v.x = cnt[i + 0];
        if (i + 1 < N) v.y = cnt[i + 1];
        if (i + 2 < N) v.z = cnt[i + 2];
        if (i + 3 < N) v.w = cnt[i + 3];
    }
    return v;
}

__global__ void scan1_kernel(const int* __restrict__ cnt, int* __restrict__ bsum, int N) {
    const int tid = threadIdx.x;
    const int i = blockIdx.x * SCAN_ELEMS + tid * 4;
    int4 v = load_cnt4(cnt, i, N);
    int s = v.x + v.y + v.z + v.w;
#pragma unroll
    for (int off = 1; off < 64; off <<= 1) s += __shfl_xor(s, off);
    __shared__ int ws[4];
    if ((tid & 63) == 0) ws[tid >> 6] = s;
    __syncthreads();
    if (tid == 0) bsum[blockIdx.x] = ws[0] + ws[1] + ws[2] + ws[3];
}

__global__ void scan2_kernel(const int* __restrict__ bsum, int* __restrict__ boff,
                             int* __restrict__ rowptr_last, int nb) {
    const int tid = threadIdx.x;  // 256
    const int lane = tid & 63, w = tid >> 6;
    int v = (tid < nb) ? bsum[tid] : 0;
    int inc = v;
#pragma unroll
    for (int off = 1; off < 64; off <<= 1) {
        int t = __shfl_up(inc, off);
        if (lane >= off) inc += t;
    }
    __shared__ int wsum[4];
    if (lane == 63) wsum[w] = inc;
    __syncthreads();
    int wo = 0;
    for (int k = 0; k < w; ++k) wo += wsum[k];
    const int excl = wo + inc - v;
    if (tid < nb) boff[tid] = excl;
    if (tid == nb - 1) *rowptr_last = excl + v;  // == E
}

__global__ void scan3_kernel(const int* __restrict__ cnt, const int* __restrict__ boff,
                             int* __restrict__ rowptr, int N) {
    const int tid = threadIdx.x;
    const int lane = tid & 63, w = tid >> 6;
    const int i = blockIdx.x * SCAN_ELEMS + tid * 4;
    int4 v = load_cnt4(cnt, i, N);
    const int s = v.x + v.y + v.z + v.w;
    int inc = s;
#pragma unroll
    for (int off = 1; off < 64; off <<= 1) {
        int t = __shfl_up(inc, off);
        if (lane >= off) inc += t;
    }
    __shared__ int wsum[4];
    if (lane == 63) wsum[w] = inc;
    __syncthreads();
    int wo = 0;
    for (int k = 0; k < w; ++k) wo += wsum[k];
    const int r0 = boff[blockIdx.x] + wo + inc - s;
    const int r1 = r0 + v.x, r2 = r1 + v.y, r3 = r2 + v.z;
    if (i + 3 < N) {
        *(int4*)(rowptr + i) = make_int4(r0, r1, r2, r3);
    } else {
        if (i + 0 < N) rowptr[i + 0] = r0;
        if (i + 1 < N) rowptr[i + 1] = r1;
        if (i + 2 < N) rowptr[i + 2] = r2;
        if (i + 3 < N) rowptr[i + 3] = r3;
    }
}

// atomic-free counting-sort fill
__global__ void fill_kernel(const int* __restrict__ row, const int* __restrict__ col,
                            const int* __restrict__ rank, const int* __restrict__ rowptr,
                            int* __restrict__ csr, int E) {
    const int t = blockIdx.x * blockDim.x + threadIdx.x;
    const int e = t * 4;
    if (e >= E) return;
    if (e + 3 < E) {
        const int4 r = *(const int4*)(row + e);
        const int4 c = *(const int4*)(col + e);
        const int4 k = *(const int4*)(rank + e);
        csr[rowptr[c.x] + k.x] = r.x;
        csr[rowptr[c.y] + k.y] = r.y;
        csr[rowptr[c.z] + k.z] = r.z;
        csr[rowptr[c.w] + k.w] = r.w;
    } else {
        for (int k = e; k < E; ++k) csr[rowptr[col[k]] + rank[k]] = row[k];
    }
}

// S0 = bf16(dinv (.) x), vectorized
__global__ void init_s0_kernel(const float* __restrict__ dinv, const float* __restrict__ x,
                               unsigned short* __restrict__ S0b, int NF) {
    int i = blockIdx.x * blockDim.x + threadIdx.x;
    int j = i * 4;
    if (j >= NF) return;
    const float dv = dinv[j >> 6];
    const float4 v = *(const float4*)(x + j);
    ushort4 u;
    u.x = f_to_bf(dv * v.x); u.y = f_to_bf(dv * v.y);
    u.z = f_to_bf(dv * v.z); u.w = f_to_bf(dv * v.w);
    *(ushort4*)(S0b + j) = u;
}

// Gather-sum over in-edges: u[lane] = sum_{src} S[src, lane], S in bf16.
__device__ __forceinline__ float gather_sum_bf(const int* __restrict__ csr, int s, int e,
                                               const unsigned short* __restrict__ S, int lane) {
    const int q = lane >> 4;
    const int fo = (lane & 15) * 4;
    float4 A0 = {0, 0, 0, 0}, A1 = {0, 0, 0, 0}, A2 = {0, 0, 0, 0}, A3 = {0, 0, 0, 0};
    for (int base = s; base < e; base += 64) {
        int li = base + lane;
        int idx = csr[li < e ? li : e - 1];
        int m = e - base;
        if (m > 64) m = 64;
        for (int g0 = 0; g0 < m; g0 += 16) {
            const int e0 = g0 + q, e1 = g0 + 4 + q, e2 = g0 + 8 + q, e3 = g0 + 12 + q;
            const int r0 = __shfl(idx, e0), r1 = __shfl(idx, e1);
            const int r2 = __shfl(idx, e2), r3 = __shfl(idx, e3);
            const float4 v0 = bf4_to_f4(*(const ushort4*)(S + (size_t)r0 * F + fo));
            const float4 v1 = bf4_to_f4(*(const ushort4*)(S + (size_t)r1 * F + fo));
            const float4 v2 = bf4_to_f4(*(const ushort4*)(S + (size_t)r2 * F + fo));
            const float4 v3 = bf4_to_f4(*(const ushort4*)(S + (size_t)r3 * F + fo));
            if (g0 + 16 <= m) {
                A0.x += v0.x; A0.y += v0.y; A0.z += v0.z; A0.w += v0.w;
                A1.x += v1.x; A1.y += v1.y; A1.z += v1.z; A1.w += v1.w;
                A2.x += v2.x; A2.y += v2.y; A2.z += v2.z; A2.w += v2.w;
                A3.x += v3.x; A3.y += v3.y; A3.z += v3.z; A3.w += v3.w;
            } else {
                const float s0 = e0 < m ? 1.f : 0.f, s1 = e1 < m ? 1.f : 0.f;
                const float s2 = e2 < m ? 1.f : 0.f, s3 = e3 < m ? 1.f : 0.f;
                A0.x += s0 * v0.x; A0.y += s0 * v0.y; A0.z += s0 * v0.z; A0.w += s0 * v0.w;
                A1.x += s1 * v1.x; A1.y += s1 * v1.y; A1.z += s1 * v1.z; A1.w += s1 * v1.w;
                A2.x += s2 * v2.x; A2.y += s2 * v2.y; A2.z += s2 * v2.z; A2.w += s2 * v2.w;
                A3.x += s3 * v3.x; A3.y += s3 * v3.y; A3.z += s3 * v3.z; A3.w += s3 * v3.w;
            }
        }
    }
    float4 t;
    t.x = (A0.x + A1.x) + (A2.x + A3.x);
    t.y = (A0.y + A1.y) + (A2.y + A3.y);
    t.z = (A0.z + A1.z) + (A2.z + A3.z);
    t.w = (A0.w + A1.w) + (A2.w + A3.w);
    t.x += __shfl_xor(t.x, 16); t.y += __shfl_xor(t.y, 16);
    t.z += __shfl_xor(t.z, 16); t.w += __shfl_xor(t.w, 16);
    t.x += __shfl_xor(t.x, 32); t.y += __shfl_xor(t.y, 32);
    t.z += __shfl_xor(t.z, 32); t.w += __shfl_xor(t.w, 32);
    const int sl = lane >> 2;
    const float vx = __shfl(t.x, sl), vy = __shfl(t.y, sl);
    const float vz = __shfl(t.z, sl), vw = __shfl(t.w, sl);
    const int c = lane & 3;
    return c == 0 ? vx : (c == 1 ? vy : (c == 2 ? vz : vw));
}

// k=1: S1 = bf16(-dinv^2 * gather(S0))
__global__ __launch_bounds__(WPB * 64, 6)
void prop1_lean(const int* __restrict__ rowptr, const int* __restrict__ csr,
                const float* __restrict__ dinv2, const unsigned short* __restrict__ S0b,
                unsigned short* __restrict__ S1b, int N) {
    const int lane = threadIdx.x & 63;
    const int wbase = blockIdx.x * (WPB * NPW) + (threadIdx.x >> 6) * NPW;
    for (int it = 0; it < NPW; ++it) {
        const int n = wbase + it;
        if (n >= N) break;
        const float u = gather_sum_bf(csr, rowptr[n], rowptr[n + 1], S0b, lane);
        S1b[(size_t)n * F + lane] = f_to_bf(-dinv2[n] * u);
    }
}

// k>=2: Sk = bf16(-2*dinv^2 * gather(S_{k-1}) - S_{k-2})
__global__ __launch_bounds__(WPB * 64, 6)
void prop_lean(const int* __restrict__ rowptr, const int* __restrict__ csr,
               const float* __restrict__ dinv2, const unsigned short* __restrict__ Sprev,
               const unsigned short* __restrict__ Sm2, unsigned short* __restrict__ Sk, int N) {
    const int lane = threadIdx.x & 63;
    const int wbase = blockIdx.x * (WPB * NPW) + (threadIdx.x >> 6) * NPW;
    for (int it = 0; it < NPW; ++it) {
        const int n = wbase + it;
        if (n >= N) break;
        const float u = gather_sum_bf(csr, rowptr[n], rowptr[n + 1], Sprev, lane);
        const size_t o = (size_t)n * F + lane;
        Sk[o] = f_to_bf(-2.0f * dinv2[n] * u - bf_to_f(Sm2[o]));
    }
}

// Pre-swizzle bf16(W) into MFMA B-fragment order:
// Wfrag[((ft*12 + s)*64 + lane)*8 + j] = bf16(W[kk][f][ft*16 + (lane&15)])
// with kg = s*32 + (lane>>4)*8 + j, kk = kg>>6, f = kg&63.
__global__ void wfrag_kernel(const float* __restrict__ W, unsigned short* __restrict__ Wfrag) {
    const int idx = blockIdx.x * blockDim.x + threadIdx.x;  // 3072 entries
    if (idx >= 4 * 12 * 64) return;
    const int lane = idx & 63;
    const int s = (idx >> 6) % 12;
    const int ft = idx / (64 * 12);
    const int n = ft * 16 + (lane & 15);
    const int quad = lane >> 4;
    unsigned short v[8];
#pragma unroll
    for (int j = 0; j < 8; ++j) {
        const int kg = s * 32 + quad * 8 + j;
        const int kk = kg >> 6, f = kg & 63;
        v[j] = f_to_bf(W[kk * F * F + f * F + n]);
    }
    ushort4 lo = {v[0], v[1], v[2], v[3]};
    ushort4 hi = {v[4], v[5], v[6], v[7]};
    *(ushort4*)(Wfrag + (size_t)idx * 8) = lo;
    *(ushort4*)(Wfrag + (size_t)idx * 8 + 4) = hi;
}

// out = relu(b + x@W0 + rdinv (.) sum_{k=1..5} Sk@Wk)  [+ deg-0 fixup x@(W4-W2)]
// Block = 16 nodes; wave w handles feature tile [16w, 16w+16). 12 MFMA/wave.
__global__ __launch_bounds__(256, 4)
void mfma_out_kernel(const float* __restrict__ x, const unsigned short* __restrict__ Sstack,
                     const unsigned short* __restrict__ Wfrag, const float* __restrict__ rdinv,
                     const float* __restrict__ dinv2, const float* __restrict__ W,
                     const float* __restrict__ b, float* __restrict__ out, int N, int NF) {
    const int lane = threadIdx.x & 63;
    const int wave = threadIdx.x >> 6;      // feature tile
    const int quad = lane >> 4;
    const int tm = blockIdx.x * 16;
    const int ma = tm + (lane & 15);        // A-row this lane feeds
    const int mac = ma < N ? ma : N - 1;    // clamped (stores masked below)

    floatx4 C0 = {0.f, 0.f, 0.f, 0.f};
    floatx4 C1 = {0.f, 0.f, 0.f, 0.f};
    const unsigned short* wf = Wfrag + ((size_t)(wave * 12) * 64 + lane) * 8;

    // K-steps 0..1: A = bf16(x row)
    {
        const float* xr = x + (size_t)mac * F + quad * 8;
#pragma unroll
        for (int s = 0; s < 2; ++s) {
            const float4 a0 = *(const float4*)(xr + s * 32);
            const float4 a1 = *(const float4*)(xr + s * 32 + 4);
            short8 A;
            A[0] = (short)f_to_bf(a0.x); A[1] = (short)f_to_bf(a0.y);
            A[2] = (short)f_to_bf(a0.z); A[3] = (short)f_to_bf(a0.w);
            A[4] = (short)f_to_bf(a1.x); A[5] = (short)f_to_bf(a1.y);
            A[6] = (short)f_to_bf(a1.z); A[7] = (short)f_to_bf(a1.w);
            const short8 B = *(const short8*)(wf + (size_t)s * 64 * 8);
            C0 = __builtin_amdgcn_mfma_f32_16x16x32_bf16(A, B, C0, 0, 0, 0);
        }
    }
    // K-steps 2..11: A = raw bf16 S_kk rows (kk = s/2)
#pragma unroll
    for (int s = 2; s < 12; ++s) {
        const int kk = s >> 1, f0 = (s & 1) * 32;
        const short8 A = *(const short8*)(Sstack + (size_t)kk * NF + (size_t)mac * F + f0 + quad * 8);
        const short8 B = *(const short8*)(wf + (size_t)s * 64 * 8);
        C1 = __builtin_amdgcn_mfma_f32_16x16x32_bf16(A, B, C1, 0, 0, 0);
    }

    // epilogue: lane holds D[rows tm+quad*4+r][col n]
    const int n = wave * 16 + (lane & 15);
    const float bl = b[n];
#pragma unroll
    for (int r = 0; r < 4; ++r) {
        const int m = tm + quad * 4 + r;
        if (m >= N) continue;
        float v = C0[r] + rdinv[m] * C1[r];
        if (dinv2[m] == 0.0f) {  // rare deg-0 rows: Tx pattern {x,0,-x,0,x,0}
            const float* xr = x + (size_t)m * F;
            float fx = 0.f;
            for (int f = 0; f < F; ++f)
                fx += xr[f] * (W[4 * F * F + f * F + n] - W[2 * F * F + f * F + n]);
            v += fx;
        }
        out[(size_t)m * F + n] = fmaxf(v + bl, 0.f);
    }
}

extern "C" void kernel_launch(void* const* d_in, const int* in_sizes, int n_in,
                              void* d_out, int out_size, void* d_ws, size_t ws_size,
                              hipStream_t stream) {
    const float* x = (const float*)d_in[0];
    const int* ei = (const int*)d_in[1];
    const float* W = (const float*)d_in[2];
    const float* b = (const float*)d_in[3];

    const int N = in_sizes[0] / F;
    const int E = in_sizes[1] / 2;
    const int NF = N * F;
    const int* row = ei;      // sources j
    const int* col = ei + E;  // targets i

    // workspace allocator (64B-aligned chunks)
    char* p = (char*)d_ws;
    auto alloc = [&](size_t bytes) {
        char* r = p;
        p += (bytes + 63) & ~(size_t)63;
        return r;
    };
    int*   deg    = (int*)alloc((size_t)2 * N * sizeof(int));  // deg + cnt contiguous
    int*   cnt    = deg + N;
    float* dinv   = (float*)alloc((size_t)N * sizeof(float));
    float* dinv2  = (float*)alloc((size_t)N * sizeof(float));
    float* rdinv  = (float*)alloc((size_t)N * sizeof(float));
    int*   rowptr = (int*)alloc((size_t)(N + 1) * sizeof(int));
    int*   bsum   = (int*)alloc(256 * sizeof(int));
    int*   boff   = (int*)alloc(256 * sizeof(int));
    int*   csr    = (int*)alloc((size_t)E * sizeof(int));
    unsigned short* Sstack = (unsigned short*)alloc((size_t)6 * NF * sizeof(unsigned short));
    unsigned short* Wfrag  = (unsigned short*)alloc((size_t)4 * 12 * 64 * 8 * sizeof(unsigned short));
    // rank aliased into S5 (S5 written only by the last prop, long after fill)
    int* rank = (int*)(Sstack + (size_t)5 * NF);
    float* out = (float*)d_out;

    const int B = 256;
    const int pgrid = (N + WPB * NPW - 1) / (WPB * NPW);
    const int nsb = (N + SCAN_ELEMS - 1) / SCAN_ELEMS;
    const int egrid4 = (E / 4 + B - 1) / B;

    hipMemsetAsync(deg, 0, (size_t)2 * N * sizeof(int), stream);
    deg_cnt_kernel<<<egrid4, B, 0, stream>>>(row, col, deg, cnt, rank, E);
    dinv_kernel<<<(N + B - 1) / B, B, 0, stream>>>(deg, dinv, dinv2, rdinv, N);
    scan1_kernel<<<nsb, B, 0, stream>>>(cnt, bsum, N);
    scan2_kernel<<<1, B, 0, stream>>>(bsum, boff, rowptr + N, nsb);
    scan3_kernel<<<nsb, B, 0, stream>>>(cnt, boff, rowptr, N);
    fill_kernel<<<egrid4, B, 0, stream>>>(row, col, rank, rowptr, csr, E);
    wfrag_kernel<<<(4 * 12 * 64 + B - 1) / B, B, 0, stream>>>(W, Wfrag);

    init_s0_kernel<<<(NF / 4 + B - 1) / B, B, 0, stream>>>(dinv, x, Sstack, NF);
    prop1_lean<<<pgrid, WPB * 64, 0, stream>>>(rowptr, csr, dinv2, Sstack,
                                               Sstack + (size_t)1 * NF, N);
    for (int k = 2; k < 6; ++k) {
        prop_lean<<<pgrid, WPB * 64, 0, stream>>>(
            rowptr, csr, dinv2, Sstack + (size_t)(k - 1) * NF,
            Sstack + (size_t)(k - 2) * NF, Sstack + (size_t)k * NF, N);
    }
    mfma_out_kernel<<<(N + 15) / 16, 256, 0, stream>>>(x, Sstack, Wfrag, rdinv, dinv2,
                                                       W, b, out, N, NF);
}

// Round 10
// 548.291 us; speedup vs baseline: 13.1771x; 1.0723x over previous
//
#include <hip/hip_runtime.h>

// ChebConv K=6, sym norm, lambda_max=2 => L_hat = -D^{-1/2} A D^{-1/2}
// N=100000, E=1600000, F=64.
// R10: radix-partitioned CSR build (LDS histograms/cursors; only the
// out-degree histogram keeps global atomics). Props: 16 gather rows in
// flight per wave (full-block fast path). MFMA output stage unchanged.

constexpr int F = 64;
constexpr int WPB = 4;        // waves per block (prop kernels)
constexpr int NPW = 8;        // nodes per wave
constexpr int SCAN_ELEMS = 1024;
constexpr int BSH = 9;        // bucket shift: 512 nodes per bucket
constexpr int EPB = 2048;     // edges per partition block

typedef __attribute__((ext_vector_type(8))) short short8;
typedef __attribute__((ext_vector_type(4))) float floatx4;

__device__ __forceinline__ unsigned short f_to_bf(float f) {
    unsigned u = __float_as_uint(f);
    u += 0x7FFFu + ((u >> 16) & 1u);  // RNE
    return (unsigned short)(u >> 16);
}
__device__ __forceinline__ float bf_to_f(unsigned short s) {
    return __uint_as_float(((unsigned)s) << 16);
}
__device__ __forceinline__ float4 bf4_to_f4(ushort4 u) {
    float4 f;
    f.x = bf_to_f(u.x); f.y = bf_to_f(u.y); f.z = bf_to_f(u.z); f.w = bf_to_f(u.w);
    return f;
}

// out-degree histogram (the one remaining global-atomic pass)
__global__ void deg_kernel(const int* __restrict__ row, int* __restrict__ deg, int E) {
    const int t = blockIdx.x * blockDim.x + threadIdx.x;
    const int e = t * 4;
    if (e >= E) return;
    if (e + 3 < E) {
        const int4 r = *(const int4*)(row + e);
        atomicAdd(&deg[r.x], 1);
        atomicAdd(&deg[r.y], 1);
        atomicAdd(&deg[r.z], 1);
        atomicAdd(&deg[r.w], 1);
    } else {
        for (int k = e; k < E; ++k) atomicAdd(&deg[row[k]], 1);
    }
}

__global__ void dinv_kernel(const int* __restrict__ deg, float* __restrict__ dinv,
                            float* __restrict__ dinv2, float* __restrict__ rdinv, int N) {
    int i = blockIdx.x * blockDim.x + threadIdx.x;
    if (i >= N) return;
    int dI = deg[i];
    float d = (float)dI;
    bool ok = dI > 0;
    dinv[i]  = ok ? rsqrtf(d) : 0.0f;
    dinv2[i] = ok ? 1.0f / d : 0.0f;
    rdinv[i] = ok ? sqrtf(d) : 0.0f;
}

// ---- radix partition by dst bucket (dst>>BSH) ----

// per-block bucket histogram -> gcount[bucket*G + blk]
__global__ void histH_kernel(const int* __restrict__ col, int* __restrict__ gcount,
                             int P, int G, int E) {
    __shared__ int hist[256];
    const int tid = threadIdx.x, blk = blockIdx.x;
    if (tid < P) hist[tid] = 0;
    __syncthreads();
    const int start = blk * EPB + tid * 8;
    if (start + 7 < E) {
        const int4 c0 = *(const int4*)(col + start);
        const int4 c1 = *(const int4*)(col + start + 4);
        atomicAdd(&hist[c0.x >> BSH], 1); atomicAdd(&hist[c0.y >> BSH], 1);
        atomicAdd(&hist[c0.z >> BSH], 1); atomicAdd(&hist[c0.w >> BSH], 1);
        atomicAdd(&hist[c1.x >> BSH], 1); atomicAdd(&hist[c1.y >> BSH], 1);
        atomicAdd(&hist[c1.z >> BSH], 1); atomicAdd(&hist[c1.w >> BSH], 1);
    } else {
        for (int k = start; k < E && k < start + 8; ++k) atomicAdd(&hist[col[k] >> BSH], 1);
    }
    __syncthreads();
    if (tid < P) gcount[(size_t)tid * G + blk] = hist[tid];
}

__device__ __forceinline__ int4 load_cnt4(const int* __restrict__ cnt, int i, int N) {
    int4 v = make_int4(0, 0, 0, 0);
    if (i + 3 < N) {
        v = *(const int4*)(cnt + i);
    } else {
        if (i + 0 < N) v.x = cnt[i + 0];
        if (i + 1 < N) v.y = cnt[i + 1];
        if (i + 2 < N) v.z = cnt[i + 2];
        if (i + 3 < N) v.w = cnt[i + 3];
    }
    return v;
}

__global__ void scan1_kernel(const int* __restrict__ cnt, int* __restrict__ bsum, int N) {
    const int tid = threadIdx.x;
    const int i = blockIdx.x * SCAN_ELEMS + tid * 4;
    int4 v = load_cnt4(cnt, i, N);
    int s = v.x + v.y + v.z + v.w;
#pragma unroll
    for (int off = 1; off < 64; off <<= 1) s += __shfl_xor(s, off);
    __shared__ int ws[4];
    if ((tid & 63) == 0) ws[tid >> 6] = s;
    __syncthreads();
    if (tid == 0) bsum[blockIdx.x] = ws[0] + ws[1] + ws[2] + ws[3];
}

// exclusive scan of block sums (nb <= 256); writes *total_out = grand total (== E)
__global__ void scan2_kernel(const int* __restrict__ bsum, int* __restrict__ boff,
                             int* __restrict__ total_out, int nb) {
    const int tid = threadIdx.x;  // 256
    const int lane = tid & 63, w = tid >> 6;
    int v = (tid < nb) ? bsum[tid] : 0;
    int inc = v;
#pragma unroll
    for (int off = 1; off < 64; off <<= 1) {
        int t = __shfl_up(inc, off);
        if (lane >= off) inc += t;
    }
    __shared__ int wsum[4];
    if (lane == 63) wsum[w] = inc;
    __syncthreads();
    int wo = 0;
    for (int k = 0; k < w; ++k) wo += wsum[k];
    const int excl = wo + inc - v;
    if (tid < nb) boff[tid] = excl;
    if (tid == nb - 1) *total_out = excl + v;
}

__global__ void scan3_kernel(const int* __restrict__ cnt, const int* __restrict__ boff,
                             int* __restrict__ dst, int N) {
    const int tid = threadIdx.x;
    const int lane = tid & 63, w = tid >> 6;
    const int i = blockIdx.x * SCAN_ELEMS + tid * 4;
    int4 v = load_cnt4(cnt, i, N);
    const int s = v.x + v.y + v.z + v.w;
    int inc = s;
#pragma unroll
    for (int off = 1; off < 64; off <<= 1) {
        int t = __shfl_up(inc, off);
        if (lane >= off) inc += t;
    }
    __shared__ int wsum[4];
    if (lane == 63) wsum[w] = inc;
    __syncthreads();
    int wo = 0;
    for (int k = 0; k < w; ++k) wo += wsum[k];
    const int r0 = boff[blockIdx.x] + wo + inc - s;
    const int r1 = r0 + v.x, r2 = r1 + v.y, r3 = r2 + v.z;
    if (i + 3 < N) {
        *(int4*)(dst + i) = make_int4(r0, r1, r2, r3);
    } else {
        if (i + 0 < N) dst[i + 0] = r0;
        if (i + 1 < N) dst[i + 1] = r1;
        if (i + 2 < N) dst[i + 2] = r2;
        if (i + 3 < N) dst[i + 3] = r3;
    }
}

// scatter edges into bucket-partitioned (dst,src) pairs via LDS cursors
__global__ void partX_kernel(const int* __restrict__ row, const int* __restrict__ col,
                             const int* __restrict__ goff, int2* __restrict__ part,
                             int P, int G, int E) {
    __shared__ int cursor[256];
    const int tid = threadIdx.x, blk = blockIdx.x;
    if (tid < P) cursor[tid] = goff[(size_t)tid * G + blk];
    __syncthreads();
    const int start = blk * EPB + tid * 8;
    for (int k = start; k < E && k < start + 8; ++k) {
        const int c = col[k], r = row[k];
        const int pos = atomicAdd(&cursor[c >> BSH], 1);
        part[pos] = make_int2(c, r);
    }
}

// one block per bucket: exact per-node counts/ranks in LDS -> rowptr + final csr
__global__ void bucketC_kernel(const int2* __restrict__ part, const int* __restrict__ goff,
                               int* __restrict__ rowptr, int* __restrict__ csr,
                               int P, int G, int N, int E) {
    __shared__ int cnt[512];
    __shared__ int excl[512];
    __shared__ int wsum[4];
    const int tid = threadIdx.x;  // 256
    const int b = blockIdx.x;
    const int base_node = b << BSH;
    const int nn = min(512, N - base_node);
    const int estart = goff[(size_t)b * G];
    const int eend = (b + 1 < P) ? goff[(size_t)(b + 1) * G] : E;

    cnt[tid] = 0; cnt[tid + 256] = 0;
    __syncthreads();
    for (int i = estart + tid; i < eend; i += 256)
        atomicAdd(&cnt[part[i].x - base_node], 1);
    __syncthreads();
    // block exclusive scan of cnt[0..511] -> excl
    {
        const int lane = tid & 63, w = tid >> 6;
        const int a0 = cnt[2 * tid], a1 = cnt[2 * tid + 1];
        const int ps = a0 + a1;
        int inc = ps;
#pragma unroll
        for (int off = 1; off < 64; off <<= 1) {
            int t = __shfl_up(inc, off);
            if (lane >= off) inc += t;
        }
        if (lane == 63) wsum[w] = inc;
        __syncthreads();
        int wo = 0;
        for (int k = 0; k < w; ++k) wo += wsum[k];
        const int ep = wo + inc - ps;
        excl[2 * tid] = ep;
        excl[2 * tid + 1] = ep + a0;
    }
    __syncthreads();
    // rowptr (global CSR offsets: bucket ranges are contiguous node ranges)
    if (tid < nn) rowptr[base_node + tid] = estart + excl[tid];
    for (int ln = 256 + tid; ln < nn; ln += 256) rowptr[base_node + ln] = estart + excl[ln];
    if (b == P - 1 && tid == 0) rowptr[N] = E;
    // reset counters, then rank + scatter into final csr
    cnt[tid] = 0; cnt[tid + 256] = 0;
    __syncthreads();
    for (int i = estart + tid; i < eend; i += 256) {
        const int2 e = part[i];
        const int ln = e.x - base_node;
        const int pos = atomicAdd(&cnt[ln], 1);
        csr[estart + excl[ln] + pos] = e.y;
    }
}

// S0 = bf16(dinv (.) x), vectorized
__global__ void init_s0_kernel(const float* __restrict__ dinv, const float* __restrict__ x,
                               unsigned short* __restrict__ S0b, int NF) {
    int i = blockIdx.x * blockDim.x + threadIdx.x;
    int j = i * 4;
    if (j >= NF) return;
    const float dv = dinv[j >> 6];
    const float4 v = *(const float4*)(x + j);
    ushort4 u;
    u.x = f_to_bf(dv * v.x); u.y = f_to_bf(dv * v.y);
    u.z = f_to_bf(dv * v.z); u.w = f_to_bf(dv * v.w);
    *(ushort4*)(S0b + j) = u;
}

// Gather-sum over in-edges: u[lane] = sum_{src} S[src, lane], S in bf16.
// Full-64-edge fast path keeps 16 independent 128B row loads in flight.
__device__ __forceinline__ float gather_sum_bf(const int* __restrict__ csr, int s, int e,
                                               const unsigned short* __restrict__ S, int lane) {
    const int q = lane >> 4;
    const int fo = (lane & 15) * 4;
    float4 A0 = {0, 0, 0, 0}, A1 = {0, 0, 0, 0}, A2 = {0, 0, 0, 0}, A3 = {0, 0, 0, 0};
    int base = s;
    for (; base + 64 <= e; base += 64) {
        const int idx = csr[base + lane];
        int r[16];
#pragma unroll
        for (int g = 0; g < 16; ++g) r[g] = __shfl(idx, g * 4 + q);
        ushort4 uv[16];
#pragma unroll
        for (int g = 0; g < 16; ++g) uv[g] = *(const ushort4*)(S + (size_t)r[g] * F + fo);
#pragma unroll
        for (int g = 0; g < 16; ++g) {
            const float4 v = bf4_to_f4(uv[g]);
            if ((g & 3) == 0) { A0.x += v.x; A0.y += v.y; A0.z += v.z; A0.w += v.w; }
            else if ((g & 3) == 1) { A1.x += v.x; A1.y += v.y; A1.z += v.z; A1.w += v.w; }
            else if ((g & 3) == 2) { A2.x += v.x; A2.y += v.y; A2.z += v.z; A2.w += v.w; }
            else { A3.x += v.x; A3.y += v.y; A3.z += v.z; A3.w += v.w; }
        }
    }
    if (base < e) {  // remainder < 64 edges
        const int li = base + lane;
        const int idx = csr[li < e ? li : e - 1];
        const int m = e - base;
        for (int g0 = 0; g0 < m; g0 += 16) {
            const int e0 = g0 + q, e1 = g0 + 4 + q, e2 = g0 + 8 + q, e3 = g0 + 12 + q;
            const int r0 = __shfl(idx, e0), r1 = __shfl(idx, e1);
            const int r2 = __shfl(idx, e2), r3 = __shfl(idx, e3);
            const float4 v0 = bf4_to_f4(*(const ushort4*)(S + (size_t)r0 * F + fo));
            const float4 v1 = bf4_to_f4(*(const ushort4*)(S + (size_t)r1 * F + fo));
            const float4 v2 = bf4_to_f4(*(const ushort4*)(S + (size_t)r2 * F + fo));
            const float4 v3 = bf4_to_f4(*(const ushort4*)(S + (size_t)r3 * F + fo));
            const float s0 = e0 < m ? 1.f : 0.f, s1 = e1 < m ? 1.f : 0.f;
            const float s2 = e2 < m ? 1.f : 0.f, s3 = e3 < m ? 1.f : 0.f;
            A0.x += s0 * v0.x; A0.y += s0 * v0.y; A0.z += s0 * v0.z; A0.w += s0 * v0.w;
            A1.x += s1 * v1.x; A1.y += s1 * v1.y; A1.z += s1 * v1.z; A1.w += s1 * v1.w;
            A2.x += s2 * v2.x; A2.y += s2 * v2.y; A2.z += s2 * v2.z; A2.w += s2 * v2.w;
            A3.x += s3 * v3.x; A3.y += s3 * v3.y; A3.z += s3 * v3.z; A3.w += s3 * v3.w;
        }
    }
    float4 t;
    t.x = (A0.x + A1.x) + (A2.x + A3.x);
    t.y = (A0.y + A1.y) + (A2.y + A3.y);
    t.z = (A0.z + A1.z) + (A2.z + A3.z);
    t.w = (A0.w + A1.w) + (A2.w + A3.w);
    t.x += __shfl_xor(t.x, 16); t.y += __shfl_xor(t.y, 16);
    t.z += __shfl_xor(t.z, 16); t.w += __shfl_xor(t.w, 16);
    t.x += __shfl_xor(t.x, 32); t.y += __shfl_xor(t.y, 32);
    t.z += __shfl_xor(t.z, 32); t.w += __shfl_xor(t.w, 32);
    const int sl = lane >> 2;
    const float vx = __shfl(t.x, sl), vy = __shfl(t.y, sl);
    const float vz = __shfl(t.z, sl), vw = __shfl(t.w, sl);
    const int c = lane & 3;
    return c == 0 ? vx : (c == 1 ? vy : (c == 2 ? vz : vw));
}

// k=1: S1 = bf16(-dinv^2 * gather(S0))
__global__ __launch_bounds__(WPB * 64, 4)
void prop1_lean(const int* __restrict__ rowptr, const int* __restrict__ csr,
                const float* __restrict__ dinv2, const unsigned short* __restrict__ S0b,
                unsigned short* __restrict__ S1b, int N) {
    const int lane = threadIdx.x & 63;
    const int wbase = blockIdx.x * (WPB * NPW) + (threadIdx.x >> 6) * NPW;
    for (int it = 0; it < NPW; ++it) {
        const int n = wbase + it;
        if (n >= N) break;
        const float u = gather_sum_bf(csr, rowptr[n], rowptr[n + 1], S0b, lane);
        S1b[(size_t)n * F + lane] = f_to_bf(-dinv2[n] * u);
    }
}

// k>=2: Sk = bf16(-2*dinv^2 * gather(S_{k-1}) - S_{k-2})
__global__ __launch_bounds__(WPB * 64, 4)
void prop_lean(const int* __restrict__ rowptr, const int* __restrict__ csr,
               const float* __restrict__ dinv2, const unsigned short* __restrict__ Sprev,
               const unsigned short* __restrict__ Sm2, unsigned short* __restrict__ Sk, int N) {
    const int lane = threadIdx.x & 63;
    const int wbase = blockIdx.x * (WPB * NPW) + (threadIdx.x >> 6) * NPW;
    for (int it = 0; it < NPW; ++it) {
        const int n = wbase + it;
        if (n >= N) break;
        const float u = gather_sum_bf(csr, rowptr[n], rowptr[n + 1], Sprev, lane);
        const size_t o = (size_t)n * F + lane;
        Sk[o] = f_to_bf(-2.0f * dinv2[n] * u - bf_to_f(Sm2[o]));
    }
}

// Pre-swizzle bf16(W) into MFMA B-fragment order.
__global__ void wfrag_kernel(const float* __restrict__ W, unsigned short* __restrict__ Wfrag) {
    const int idx = blockIdx.x * blockDim.x + threadIdx.x;  // 3072 entries
    if (idx >= 4 * 12 * 64) return;
    const int lane = idx & 63;
    const int s = (idx >> 6) % 12;
    const int ft = idx / (64 * 12);
    const int n = ft * 16 + (lane & 15);
    const int quad = lane >> 4;
    unsigned short v[8];
#pragma unroll
    for (int j = 0; j < 8; ++j) {
        const int kg = s * 32 + quad * 8 + j;
        const int kk = kg >> 6, f = kg & 63;
        v[j] = f_to_bf(W[kk * F * F + f * F + n]);
    }
    ushort4 lo = {v[0], v[1], v[2], v[3]};
    ushort4 hi = {v[4], v[5], v[6], v[7]};
    *(ushort4*)(Wfrag + (size_t)idx * 8) = lo;
    *(ushort4*)(Wfrag + (size_t)idx * 8 + 4) = hi;
}

// out = relu(b + x@W0 + rdinv (.) sum_{k=1..5} Sk@Wk)  [+ deg-0 fixup x@(W4-W2)]
__global__ __launch_bounds__(256, 4)
void mfma_out_kernel(const float* __restrict__ x, const unsigned short* __restrict__ Sstack,
                     const unsigned short* __restrict__ Wfrag, const float* __restrict__ rdinv,
                     const float* __restrict__ dinv2, const float* __restrict__ W,
                     const float* __restrict__ b, float* __restrict__ out, int N, int NF) {
    const int lane = threadIdx.x & 63;
    const int wave = threadIdx.x >> 6;      // feature tile
    const int quad = lane >> 4;
    const int tm = blockIdx.x * 16;
    const int ma = tm + (lane & 15);
    const int mac = ma < N ? ma : N - 1;

    floatx4 C0 = {0.f, 0.f, 0.f, 0.f};
    floatx4 C1 = {0.f, 0.f, 0.f, 0.f};
    const unsigned short* wf = Wfrag + ((size_t)(wave * 12) * 64 + lane) * 8;

    {
        const float* xr = x + (size_t)mac * F + quad * 8;
#pragma unroll
        for (int s = 0; s < 2; ++s) {
            const float4 a0 = *(const float4*)(xr + s * 32);
            const float4 a1 = *(const float4*)(xr + s * 32 + 4);
            short8 A;
            A[0] = (short)f_to_bf(a0.x); A[1] = (short)f_to_bf(a0.y);
            A[2] = (short)f_to_bf(a0.z); A[3] = (short)f_to_bf(a0.w);
            A[4] = (short)f_to_bf(a1.x); A[5] = (short)f_to_bf(a1.y);
            A[6] = (short)f_to_bf(a1.z); A[7] = (short)f_to_bf(a1.w);
            const short8 B = *(const short8*)(wf + (size_t)s * 64 * 8);
            C0 = __builtin_amdgcn_mfma_f32_16x16x32_bf16(A, B, C0, 0, 0, 0);
        }
    }
#pragma unroll
    for (int s = 2; s < 12; ++s) {
        const int kk = s >> 1, f0 = (s & 1) * 32;
        const short8 A = *(const short8*)(Sstack + (size_t)kk * NF + (size_t)mac * F + f0 + quad * 8);
        const short8 B = *(const short8*)(wf + (size_t)s * 64 * 8);
        C1 = __builtin_amdgcn_mfma_f32_16x16x32_bf16(A, B, C1, 0, 0, 0);
    }

    const int n = wave * 16 + (lane & 15);
    const float bl = b[n];
#pragma unroll
    for (int r = 0; r < 4; ++r) {
        const int m = tm + quad * 4 + r;
        if (m >= N) continue;
        float v = C0[r] + rdinv[m] * C1[r];
        if (dinv2[m] == 0.0f) {  // rare deg-0 rows: Tx pattern {x,0,-x,0,x,0}
            const float* xr = x + (size_t)m * F;
            float fx = 0.f;
            for (int f = 0; f < F; ++f)
                fx += xr[f] * (W[4 * F * F + f * F + n] - W[2 * F * F + f * F + n]);
            v += fx;
        }
        out[(size_t)m * F + n] = fmaxf(v + bl, 0.f);
    }
}

extern "C" void kernel_launch(void* const* d_in, const int* in_sizes, int n_in,
                              void* d_out, int out_size, void* d_ws, size_t ws_size,
                              hipStream_t stream) {
    const float* x = (const float*)d_in[0];
    const int* ei = (const int*)d_in[1];
    const float* W = (const float*)d_in[2];
    const float* b = (const float*)d_in[3];

    const int N = in_sizes[0] / F;
    const int E = in_sizes[1] / 2;
    const int NF = N * F;
    const int* row = ei;      // sources j
    const int* col = ei + E;  // targets i

    const int P = (N + 511) >> BSH;           // buckets (<=256 for N<=131072)
    const int G = (E + EPB - 1) / EPB;        // partition blocks
    const int M = P * G;                      // scan length

    // workspace allocator (64B-aligned chunks)
    char* p = (char*)d_ws;
    auto alloc = [&](size_t bytes) {
        char* r = p;
        p += (bytes + 63) & ~(size_t)63;
        return r;
    };
    int*   deg    = (int*)alloc((size_t)N * sizeof(int));
    float* dinv   = (float*)alloc((size_t)N * sizeof(float));
    float* dinv2  = (float*)alloc((size_t)N * sizeof(float));
    float* rdinv  = (float*)alloc((size_t)N * sizeof(float));
    int*   rowptr = (int*)alloc((size_t)(N + 1) * sizeof(int));
    int*   bsum   = (int*)alloc(256 * sizeof(int));
    int*   boff   = (int*)alloc(256 * sizeof(int));
    int*   gcount = (int*)alloc((size_t)M * sizeof(int));
    int*   goff   = (int*)alloc((size_t)M * sizeof(int));
    int*   csr    = (int*)alloc((size_t)E * sizeof(int));
    unsigned short* Sstack = (unsigned short*)alloc((size_t)6 * NF * sizeof(unsigned short));
    unsigned short* Wfrag  = (unsigned short*)alloc((size_t)4 * 12 * 64 * 8 * sizeof(unsigned short));
    // part (2E int2 = 12.8MB) aliases S0 (dead before init_s0 writes S0)
    int2* part = (int2*)Sstack;
    float* out = (float*)d_out;

    const int B = 256;
    const int pgrid = (N + WPB * NPW - 1) / (WPB * NPW);
    const int nsbM = (M + SCAN_ELEMS - 1) / SCAN_ELEMS;  // <=256 required
    const int egrid4 = (E / 4 + B - 1) / B;

    hipMemsetAsync(deg, 0, (size_t)N * sizeof(int), stream);
    deg_kernel<<<egrid4, B, 0, stream>>>(row, deg, E);
    dinv_kernel<<<(N + B - 1) / B, B, 0, stream>>>(deg, dinv, dinv2, rdinv, N);

    histH_kernel<<<G, B, 0, stream>>>(col, gcount, P, G, E);
    scan1_kernel<<<nsbM, B, 0, stream>>>(gcount, bsum, M);
    scan2_kernel<<<1, B, 0, stream>>>(bsum, boff, rowptr + N, nsbM);  // total == E
    scan3_kernel<<<nsbM, B, 0, stream>>>(gcount, boff, goff, M);
    partX_kernel<<<G, B, 0, stream>>>(row, col, goff, part, P, G, E);
    bucketC_kernel<<<P, B, 0, stream>>>(part, goff, rowptr, csr, P, G, N, E);

    wfrag_kernel<<<(4 * 12 * 64 + B - 1) / B, B, 0, stream>>>(W, Wfrag);
    init_s0_kernel<<<(NF / 4 + B - 1) / B, B, 0, stream>>>(dinv, x, Sstack, NF);
    prop1_lean<<<pgrid, WPB * 64, 0, stream>>>(rowptr, csr, dinv2, Sstack,
                                               Sstack + (size_t)1 * NF, N);
    for (int k = 2; k < 6; ++k) {
        prop_lean<<<pgrid, WPB * 64, 0, stream>>>(
            rowptr, csr, dinv2, Sstack + (size_t)(k - 1) * NF,
            Sstack + (size_t)(k - 2) * NF, Sstack + (size_t)k * NF, N);
    }
    mfma_out_kernel<<<(N + 15) / 16, 256, 0, stream>>>(x, Sstack, Wfrag, rdinv, dinv2,
                                                       W, b, out, N, NF);
}

// Round 11
// 397.798 us; speedup vs baseline: 18.1622x; 1.3783x over previous
//
#include <hip/hip_runtime.h>

// ChebConv K=6, sym norm, lambda_max=2 => L_hat = -D^{-1/2} A D^{-1/2}
// N=100000, E=1600000, F=64.
// R11: (1) group-per-node gather props: 16-lane group owns a node, lane owns
// a 4-feature slice -> no cross-lane reduce, 16 useful rows in flight at
// degree~16. (2) zero global atomics: degree computed via a second radix
// partition (by src bucket) with LDS counting; hist+partition fused for
// dst & src. MFMA output stage unchanged.

constexpr int F = 64;
constexpr int SCAN_ELEMS = 1024;
constexpr int BSH = 9;        // bucket shift: 512 nodes per bucket
constexpr int EPB = 2048;     // edges per partition block
constexpr int PNPW = 8;       // nodes per wave (prop kernels)

typedef __attribute__((ext_vector_type(8))) short short8;
typedef __attribute__((ext_vector_type(4))) float floatx4;

__device__ __forceinline__ unsigned short f_to_bf(float f) {
    unsigned u = __float_as_uint(f);
    u += 0x7FFFu + ((u >> 16) & 1u);  // RNE
    return (unsigned short)(u >> 16);
}
__device__ __forceinline__ float bf_to_f(unsigned short s) {
    return __uint_as_float(((unsigned)s) << 16);
}
__device__ __forceinline__ float4 bf4_to_f4(ushort4 u) {
    float4 f;
    f.x = bf_to_f(u.x); f.y = bf_to_f(u.y); f.z = bf_to_f(u.z); f.w = bf_to_f(u.w);
    return f;
}

// ---- fused dst/src bucket histograms ----
__global__ void hist2_kernel(const int* __restrict__ row, const int* __restrict__ col,
                             int* __restrict__ gcH, int* __restrict__ gcS,
                             int P, int G, int E) {
    __shared__ int hH[256], hS[256];
    const int tid = threadIdx.x, blk = blockIdx.x;
    hH[tid] = 0; hS[tid] = 0;
    __syncthreads();
    const int start = blk * EPB + tid * 8;
    if (start + 7 < E) {
        const int4 c0 = *(const int4*)(col + start);
        const int4 c1 = *(const int4*)(col + start + 4);
        const int4 r0 = *(const int4*)(row + start);
        const int4 r1 = *(const int4*)(row + start + 4);
        atomicAdd(&hH[c0.x >> BSH], 1); atomicAdd(&hH[c0.y >> BSH], 1);
        atomicAdd(&hH[c0.z >> BSH], 1); atomicAdd(&hH[c0.w >> BSH], 1);
        atomicAdd(&hH[c1.x >> BSH], 1); atomicAdd(&hH[c1.y >> BSH], 1);
        atomicAdd(&hH[c1.z >> BSH], 1); atomicAdd(&hH[c1.w >> BSH], 1);
        atomicAdd(&hS[r0.x >> BSH], 1); atomicAdd(&hS[r0.y >> BSH], 1);
        atomicAdd(&hS[r0.z >> BSH], 1); atomicAdd(&hS[r0.w >> BSH], 1);
        atomicAdd(&hS[r1.x >> BSH], 1); atomicAdd(&hS[r1.y >> BSH], 1);
        atomicAdd(&hS[r1.z >> BSH], 1); atomicAdd(&hS[r1.w >> BSH], 1);
    } else {
        for (int k = start; k < E && k < start + 8; ++k) {
            atomicAdd(&hH[col[k] >> BSH], 1);
            atomicAdd(&hS[row[k] >> BSH], 1);
        }
    }
    __syncthreads();
    if (tid < P) {
        gcH[(size_t)tid * G + blk] = hH[tid];
        gcS[(size_t)tid * G + blk] = hS[tid];
    }
}

__device__ __forceinline__ int4 load_cnt4(const int* __restrict__ cnt, int i, int N) {
    int4 v = make_int4(0, 0, 0, 0);
    if (i + 3 < N) {
        v = *(const int4*)(cnt + i);
    } else {
        if (i + 0 < N) v.x = cnt[i + 0];
        if (i + 1 < N) v.y = cnt[i + 1];
        if (i + 2 < N) v.z = cnt[i + 2];
        if (i + 3 < N) v.w = cnt[i + 3];
    }
    return v;
}

__global__ void scan1_kernel(const int* __restrict__ cnt, int* __restrict__ bsum, int N) {
    const int tid = threadIdx.x;
    const int i = blockIdx.x * SCAN_ELEMS + tid * 4;
    int4 v = load_cnt4(cnt, i, N);
    int s = v.x + v.y + v.z + v.w;
#pragma unroll
    for (int off = 1; off < 64; off <<= 1) s += __shfl_xor(s, off);
    __shared__ int ws[4];
    if ((tid & 63) == 0) ws[tid >> 6] = s;
    __syncthreads();
    if (tid == 0) bsum[blockIdx.x] = ws[0] + ws[1] + ws[2] + ws[3];
}

__global__ void scan2_kernel(const int* __restrict__ bsum, int* __restrict__ boff,
                             int* __restrict__ total_out, int nb) {
    const int tid = threadIdx.x;  // 256
    const int lane = tid & 63, w = tid >> 6;
    int v = (tid < nb) ? bsum[tid] : 0;
    int inc = v;
#pragma unroll
    for (int off = 1; off < 64; off <<= 1) {
        int t = __shfl_up(inc, off);
        if (lane >= off) inc += t;
    }
    __shared__ int wsum[4];
    if (lane == 63) wsum[w] = inc;
    __syncthreads();
    int wo = 0;
    for (int k = 0; k < w; ++k) wo += wsum[k];
    const int excl = wo + inc - v;
    if (tid < nb) boff[tid] = excl;
    if (tid == nb - 1) *total_out = excl + v;
}

__global__ void scan3_kernel(const int* __restrict__ cnt, const int* __restrict__ boff,
                             int* __restrict__ dst, int N) {
    const int tid = threadIdx.x;
    const int lane = tid & 63, w = tid >> 6;
    const int i = blockIdx.x * SCAN_ELEMS + tid * 4;
    int4 v = load_cnt4(cnt, i, N);
    const int s = v.x + v.y + v.z + v.w;
    int inc = s;
#pragma unroll
    for (int off = 1; off < 64; off <<= 1) {
        int t = __shfl_up(inc, off);
        if (lane >= off) inc += t;
    }
    __shared__ int wsum[4];
    if (lane == 63) wsum[w] = inc;
    __syncthreads();
    int wo = 0;
    for (int k = 0; k < w; ++k) wo += wsum[k];
    const int r0 = boff[blockIdx.x] + wo + inc - s;
    const int r1 = r0 + v.x, r2 = r1 + v.y, r3 = r2 + v.z;
    if (i + 3 < N) {
        *(int4*)(dst + i) = make_int4(r0, r1, r2, r3);
    } else {
        if (i + 0 < N) dst[i + 0] = r0;
        if (i + 1 < N) dst[i + 1] = r1;
        if (i + 2 < N) dst[i + 2] = r2;
        if (i + 3 < N) dst[i + 3] = r3;
    }
}

// fused scatter into dst-partitioned (dst,src) pairs AND src-partitioned src list
__global__ void part2_kernel(const int* __restrict__ row, const int* __restrict__ col,
                             const int* __restrict__ goH, const int* __restrict__ goS,
                             int2* __restrict__ partH, int* __restrict__ partS,
                             int P, int G, int E) {
    __shared__ int cH[256], cS[256];
    const int tid = threadIdx.x, blk = blockIdx.x;
    if (tid < P) {
        cH[tid] = goH[(size_t)tid * G + blk];
        cS[tid] = goS[(size_t)tid * G + blk];
    }
    __syncthreads();
    const int start = blk * EPB + tid * 8;
    for (int k = start; k < E && k < start + 8; ++k) {
        const int c = col[k], r = row[k];
        const int posH = atomicAdd(&cH[c >> BSH], 1);
        partH[posH] = make_int2(c, r);
        const int posS = atomicAdd(&cS[r >> BSH], 1);
        partS[posS] = r;
    }
}

// one block per bucket: exact per-node counts/ranks in LDS -> rowptr + final csr
__global__ void bucketC_kernel(const int2* __restrict__ part, const int* __restrict__ goff,
                               int* __restrict__ rowptr, int* __restrict__ csr,
                               int P, int G, int N, int E) {
    __shared__ int cnt[512];
    __shared__ int excl[512];
    __shared__ int wsum[4];
    const int tid = threadIdx.x;  // 256
    const int b = blockIdx.x;
    const int base_node = b << BSH;
    const int nn = min(512, N - base_node);
    const int estart = goff[(size_t)b * G];
    const int eend = (b + 1 < P) ? goff[(size_t)(b + 1) * G] : E;

    cnt[tid] = 0; cnt[tid + 256] = 0;
    __syncthreads();
    for (int i = estart + tid; i < eend; i += 256)
        atomicAdd(&cnt[part[i].x - base_node], 1);
    __syncthreads();
    {
        const int lane = tid & 63, w = tid >> 6;
        const int a0 = cnt[2 * tid], a1 = cnt[2 * tid + 1];
        const int ps = a0 + a1;
        int inc = ps;
#pragma unroll
        for (int off = 1; off < 64; off <<= 1) {
            int t = __shfl_up(inc, off);
            if (lane >= off) inc += t;
        }
        if (lane == 63) wsum[w] = inc;
        __syncthreads();
        int wo = 0;
        for (int k = 0; k < w; ++k) wo += wsum[k];
        const int ep = wo + inc - ps;
        excl[2 * tid] = ep;
        excl[2 * tid + 1] = ep + a0;
    }
    __syncthreads();
    if (tid < nn) rowptr[base_node + tid] = estart + excl[tid];
    for (int ln = 256 + tid; ln < nn; ln += 256) rowptr[base_node + ln] = estart + excl[ln];
    if (b == P - 1 && tid == 0) rowptr[N] = E;
    cnt[tid] = 0; cnt[tid + 256] = 0;
    __syncthreads();
    for (int i = estart + tid; i < eend; i += 256) {
        const int2 e = part[i];
        const int ln = e.x - base_node;
        const int pos = atomicAdd(&cnt[ln], 1);
        csr[estart + excl[ln] + pos] = e.y;
    }
}

// one block per src bucket: out-degree counts in LDS -> dinv/dinv2/rdinv
__global__ void bucketD_kernel(const int* __restrict__ partS, const int* __restrict__ goffS,
                               float* __restrict__ dinv, float* __restrict__ dinv2,
                               float* __restrict__ rdinv, int P, int G, int N, int E) {
    __shared__ int cnt[512];
    const int tid = threadIdx.x;  // 256
    const int b = blockIdx.x;
    const int base_node = b << BSH;
    const int nn = min(512, N - base_node);
    const int estart = goffS[(size_t)b * G];
    const int eend = (b + 1 < P) ? goffS[(size_t)(b + 1) * G] : E;
    cnt[tid] = 0; cnt[tid + 256] = 0;
    __syncthreads();
    for (int i = estart + tid; i < eend; i += 256)
        atomicAdd(&cnt[partS[i] - base_node], 1);
    __syncthreads();
    for (int l = tid; l < nn; l += 256) {
        const int dI = cnt[l];
        const float d = (float)dI;
        const bool ok = dI > 0;
        dinv[base_node + l]  = ok ? rsqrtf(d) : 0.0f;
        dinv2[base_node + l] = ok ? 1.0f / d : 0.0f;
        rdinv[base_node + l] = ok ? sqrtf(d) : 0.0f;
    }
}

// S0 = bf16(dinv (.) x), vectorized
__global__ void init_s0_kernel(const float* __restrict__ dinv, const float* __restrict__ x,
                               unsigned short* __restrict__ S0b, int NF) {
    int i = blockIdx.x * blockDim.x + threadIdx.x;
    int j = i * 4;
    if (j >= NF) return;
    const float dv = dinv[j >> 6];
    const float4 v = *(const float4*)(x + j);
    ushort4 u;
    u.x = f_to_bf(dv * v.x); u.y = f_to_bf(dv * v.y);
    u.z = f_to_bf(dv * v.z); u.w = f_to_bf(dv * v.w);
    *(ushort4*)(S0b + j) = u;
}

// Group-per-node prop: 16-lane group g owns node wbase+j+g; lane owns the
// 4-feature slice [4*fl, 4*fl+4). Per edge: bpermute index + one wave-wide
// load fetching 4 rows (one per group) + masked float4 add. No reduction.
// FIRST: Sk = bf16(-dinv2 * sum);  else: Sk = bf16(-2*dinv2*sum - Sm2).
template <int FIRST>
__global__ __launch_bounds__(256, 8)
void prop_g4(const int* __restrict__ rowptr, const int* __restrict__ csr,
             const float* __restrict__ dinv2, const unsigned short* __restrict__ Sprev,
             const unsigned short* __restrict__ Sm2, unsigned short* __restrict__ Sk, int N) {
    const int lane = threadIdx.x & 63;
    const int g16 = lane & 48;       // group base lane (0,16,32,48)
    const int fl = lane & 15;        // feature slice index
    const int wave = threadIdx.x >> 6;
    const int nwaves = blockDim.x >> 6;
    const int wbase = (blockIdx.x * nwaves + wave) * PNPW;
    for (int j = 0; j < PNPW; j += 4) {
        const int n = wbase + j + (g16 >> 4);
        const bool nv = n < N;
        const int nc = nv ? n : N - 1;
        const int s = rowptr[nc];
        const int e = rowptr[nc + 1];
        const int len = e - s;
        float4 acc = {0.f, 0.f, 0.f, 0.f};
        for (int c = 0; c < len; c += 16) {
            const int ii = s + c + fl;
            const int idxv = csr[ii < e ? ii : e - 1];
            const int mm = min(16, len - c);
            for (int jj = 0; jj < mm; jj += 4) {
                const int i0 = __shfl(idxv, g16 + jj + 0);
                const int i1 = __shfl(idxv, g16 + jj + 1);
                const int i2 = __shfl(idxv, g16 + jj + 2);
                const int i3 = __shfl(idxv, g16 + jj + 3);
                const ushort4 u0 = *(const ushort4*)(Sprev + (size_t)i0 * F + fl * 4);
                const ushort4 u1 = *(const ushort4*)(Sprev + (size_t)i1 * F + fl * 4);
                const ushort4 u2 = *(const ushort4*)(Sprev + (size_t)i2 * F + fl * 4);
                const ushort4 u3 = *(const ushort4*)(Sprev + (size_t)i3 * F + fl * 4);
                {
                    const float4 v = bf4_to_f4(u0);
                    acc.x += v.x; acc.y += v.y; acc.z += v.z; acc.w += v.w;
                }
                if (jj + 1 < mm) {
                    const float4 v = bf4_to_f4(u1);
                    acc.x += v.x; acc.y += v.y; acc.z += v.z; acc.w += v.w;
                }
                if (jj + 2 < mm) {
                    const float4 v = bf4_to_f4(u2);
                    acc.x += v.x; acc.y += v.y; acc.z += v.z; acc.w += v.w;
                }
                if (jj + 3 < mm) {
                    const float4 v = bf4_to_f4(u3);
                    acc.x += v.x; acc.y += v.y; acc.z += v.z; acc.w += v.w;
                }
            }
        }
        if (nv) {
            const float d2 = dinv2[n];
            float4 sn;
            if (FIRST) {
                sn.x = -d2 * acc.x; sn.y = -d2 * acc.y;
                sn.z = -d2 * acc.z; sn.w = -d2 * acc.w;
            } else {
                const float4 m2 = bf4_to_f4(*(const ushort4*)(Sm2 + (size_t)n * F + fl * 4));
                sn.x = -2.f * d2 * acc.x - m2.x; sn.y = -2.f * d2 * acc.y - m2.y;
                sn.z = -2.f * d2 * acc.z - m2.z; sn.w = -2.f * d2 * acc.w - m2.w;
            }
            ushort4 o;
            o.x = f_to_bf(sn.x); o.y = f_to_bf(sn.y);
            o.z = f_to_bf(sn.z); o.w = f_to_bf(sn.w);
            *(ushort4*)(Sk + (size_t)n * F + fl * 4) = o;
        }
    }
}

// Pre-swizzle bf16(W) into MFMA B-fragment order.
__global__ void wfrag_kernel(const float* __restrict__ W, unsigned short* __restrict__ Wfrag) {
    const int idx = blockIdx.x * blockDim.x + threadIdx.x;  // 3072 entries
    if (idx >= 4 * 12 * 64) return;
    const int lane = idx & 63;
    const int s = (idx >> 6) % 12;
    const int ft = idx / (64 * 12);
    const int n = ft * 16 + (lane & 15);
    const int quad = lane >> 4;
    unsigned short v[8];
#pragma unroll
    for (int j = 0; j < 8; ++j) {
        const int kg = s * 32 + quad * 8 + j;
        const int kk = kg >> 6, f = kg & 63;
        v[j] = f_to_bf(W[kk * F * F + f * F + n]);
    }
    ushort4 lo = {v[0], v[1], v[2], v[3]};
    ushort4 hi = {v[4], v[5], v[6], v[7]};
    *(ushort4*)(Wfrag + (size_t)idx * 8) = lo;
    *(ushort4*)(Wfrag + (size_t)idx * 8 + 4) = hi;
}

// out = relu(b + x@W0 + rdinv (.) sum_{k=1..5} Sk@Wk)  [+ deg-0 fixup x@(W4-W2)]
__global__ __launch_bounds__(256, 4)
void mfma_out_kernel(const float* __restrict__ x, const unsigned short* __restrict__ Sstack,
                     const unsigned short* __restrict__ Wfrag, const float* __restrict__ rdinv,
                     const float* __restrict__ dinv2, const float* __restrict__ W,
                     const float* __restrict__ b, float* __restrict__ out, int N, int NF) {
    const int lane = threadIdx.x & 63;
    const int wave = threadIdx.x >> 6;      // feature tile
    const int quad = lane >> 4;
    const int tm = blockIdx.x * 16;
    const int ma = tm + (lane & 15);
    const int mac = ma < N ? ma : N - 1;

    floatx4 C0 = {0.f, 0.f, 0.f, 0.f};
    floatx4 C1 = {0.f, 0.f, 0.f, 0.f};
    const unsigned short* wf = Wfrag + ((size_t)(wave * 12) * 64 + lane) * 8;

    {
        const float* xr = x + (size_t)mac * F + quad * 8;
#pragma unroll
        for (int s = 0; s < 2; ++s) {
            const float4 a0 = *(const float4*)(xr + s * 32);
            const float4 a1 = *(const float4*)(xr + s * 32 + 4);
            short8 A;
            A[0] = (short)f_to_bf(a0.x); A[1] = (short)f_to_bf(a0.y);
            A[2] = (short)f_to_bf(a0.z); A[3] = (short)f_to_bf(a0.w);
            A[4] = (short)f_to_bf(a1.x); A[5] = (short)f_to_bf(a1.y);
            A[6] = (short)f_to_bf(a1.z); A[7] = (short)f_to_bf(a1.w);
            const short8 B = *(const short8*)(wf + (size_t)s * 64 * 8);
            C0 = __builtin_amdgcn_mfma_f32_16x16x32_bf16(A, B, C0, 0, 0, 0);
        }
    }
#pragma unroll
    for (int s = 2; s < 12; ++s) {
        const int kk = s >> 1, f0 = (s & 1) * 32;
        const short8 A = *(const short8*)(Sstack + (size_t)kk * NF + (size_t)mac * F + f0 + quad * 8);
        const short8 B = *(const short8*)(wf + (size_t)s * 64 * 8);
        C1 = __builtin_amdgcn_mfma_f32_16x16x32_bf16(A, B, C1, 0, 0, 0);
    }

    const int n = wave * 16 + (lane & 15);
    const float bl = b[n];
#pragma unroll
    for (int r = 0; r < 4; ++r) {
        const int m = tm + quad * 4 + r;
        if (m >= N) continue;
        float v = C0[r] + rdinv[m] * C1[r];
        if (dinv2[m] == 0.0f) {  // rare deg-0 rows: Tx pattern {x,0,-x,0,x,0}
            const float* xr = x + (size_t)m * F;
            float fx = 0.f;
            for (int f = 0; f < F; ++f)
                fx += xr[f] * (W[4 * F * F + f * F + n] - W[2 * F * F + f * F + n]);
            v += fx;
        }
        out[(size_t)m * F + n] = fmaxf(v + bl, 0.f);
    }
}

extern "C" void kernel_launch(void* const* d_in, const int* in_sizes, int n_in,
                              void* d_out, int out_size, void* d_ws, size_t ws_size,
                              hipStream_t stream) {
    const float* x = (const float*)d_in[0];
    const int* ei = (const int*)d_in[1];
    const float* W = (const float*)d_in[2];
    const float* b = (const float*)d_in[3];

    const int N = in_sizes[0] / F;
    const int E = in_sizes[1] / 2;
    const int NF = N * F;
    const int* row = ei;      // sources j
    const int* col = ei + E;  // targets i

    const int P = (N + 511) >> BSH;           // buckets (<=256 for N<=131072)
    const int G = (E + EPB - 1) / EPB;        // partition blocks
    const int M = P * G;                      // scan length

    // workspace allocator (64B-aligned chunks)
    char* p = (char*)d_ws;
    auto alloc = [&](size_t bytes) {
        char* r = p;
        p += (bytes + 63) & ~(size_t)63;
        return r;
    };
    float* dinv   = (float*)alloc((size_t)N * sizeof(float));
    float* dinv2  = (float*)alloc((size_t)N * sizeof(float));
    float* rdinv  = (float*)alloc((size_t)N * sizeof(float));
    int*   rowptr = (int*)alloc((size_t)(N + 1) * sizeof(int));
    int*   bsum   = (int*)alloc(256 * sizeof(int));
    int*   boff   = (int*)alloc(256 * sizeof(int));
    int*   totS   = (int*)alloc(64);
    int*   gcH    = (int*)alloc((size_t)M * sizeof(int));
    int*   goH    = (int*)alloc((size_t)M * sizeof(int));
    int*   gcS    = (int*)alloc((size_t)M * sizeof(int));
    int*   goS    = (int*)alloc((size_t)M * sizeof(int));
    int*   csr    = (int*)alloc((size_t)E * sizeof(int));
    unsigned short* Sstack = (unsigned short*)alloc((size_t)6 * NF * sizeof(unsigned short));
    unsigned short* Wfrag  = (unsigned short*)alloc((size_t)4 * 12 * 64 * 8 * sizeof(unsigned short));
    // partH (E int2 = 12.8MB) aliases S0 (written by init_s0, after bucketC).
    // partS (E int  =  6.4MB) aliases S1 (written by prop1, after bucketD).
    int2* partH = (int2*)Sstack;
    int*  partS = (int*)(Sstack + (size_t)NF);
    float* out = (float*)d_out;

    const int B = 256;
    const int nsbM = (M + SCAN_ELEMS - 1) / SCAN_ELEMS;  // <=256 required
    const int pgrid = (N + 4 * PNPW - 1) / (4 * PNPW);   // 4 waves/block

    hist2_kernel<<<G, B, 0, stream>>>(row, col, gcH, gcS, P, G, E);
    scan1_kernel<<<nsbM, B, 0, stream>>>(gcH, bsum, M);
    scan2_kernel<<<1, B, 0, stream>>>(bsum, boff, rowptr + N, nsbM);  // total == E
    scan3_kernel<<<nsbM, B, 0, stream>>>(gcH, boff, goH, M);
    scan1_kernel<<<nsbM, B, 0, stream>>>(gcS, bsum, M);
    scan2_kernel<<<1, B, 0, stream>>>(bsum, boff, totS, nsbM);
    scan3_kernel<<<nsbM, B, 0, stream>>>(gcS, boff, goS, M);
    part2_kernel<<<G, B, 0, stream>>>(row, col, goH, goS, partH, partS, P, G, E);
    bucketC_kernel<<<P, B, 0, stream>>>(partH, goH, rowptr, csr, P, G, N, E);
    bucketD_kernel<<<P, B, 0, stream>>>(partS, goS, dinv, dinv2, rdinv, P, G, N, E);

    wfrag_kernel<<<(4 * 12 * 64 + B - 1) / B, B, 0, stream>>>(W, Wfrag);
    init_s0_kernel<<<(NF / 4 + B - 1) / B, B, 0, stream>>>(dinv, x, Sstack, NF);
    prop_g4<1><<<pgrid, B, 0, stream>>>(rowptr, csr, dinv2, Sstack, Sstack,
                                        Sstack + (size_t)1 * NF, N);
    for (int k = 2; k < 6; ++k) {
        prop_g4<0><<<pgrid, B, 0, stream>>>(
            rowptr, csr, dinv2, Sstack + (size_t)(k - 1) * NF,
            Sstack + (size_t)(k - 2) * NF, Sstack + (size_t)k * NF, N);
    }
    mfma_out_kernel<<<(N + 15) / 16, 256, 0, stream>>>(x, Sstack, Wfrag, rdinv, dinv2,
                                                       W, b, out, N, NF);
}

// Round 12
// 397.661 us; speedup vs baseline: 18.1685x; 1.0003x over previous
//
#include <hip/hip_runtime.h>

// ChebConv K=6, sym norm, lambda_max=2 => L_hat = -D^{-1/2} A D^{-1/2}
// N=100000, E=1600000, F=64.
// R12: (1) props gather an fp8-e4m3 copy of the previous level (64B rows,
// half the random-gather bytes); recurrence state/own-term/MFMA stay bf16.
// (2) mfma_out folds x@W0 into the rdinv-scaled accumulator via S0 ->
// reads only the bf16 S stack. Radix build unchanged. ws-size/builtin
// fallback to bf16 props (call-invariant branch).

constexpr int F = 64;
constexpr int SCAN_ELEMS = 1024;
constexpr int BSH = 9;        // bucket shift: 512 nodes per bucket
constexpr int EPB = 2048;     // edges per partition block
constexpr int PNPW = 8;       // nodes per wave (prop kernels)

typedef __attribute__((ext_vector_type(8))) short short8;
typedef __attribute__((ext_vector_type(4))) float floatx4;
typedef __attribute__((ext_vector_type(2))) float floatx2;

#if defined(__has_builtin)
#if __has_builtin(__builtin_amdgcn_cvt_pk_f32_fp8) && __has_builtin(__builtin_amdgcn_cvt_pk_fp8_f32)
#define HAVE_FP8 1
#endif
#endif
#ifndef HAVE_FP8
#define HAVE_FP8 0
#endif

__device__ __forceinline__ unsigned short f_to_bf(float f) {
    unsigned u = __float_as_uint(f);
    u += 0x7FFFu + ((u >> 16) & 1u);  // RNE
    return (unsigned short)(u >> 16);
}
__device__ __forceinline__ float bf_to_f(unsigned short s) {
    return __uint_as_float(((unsigned)s) << 16);
}
__device__ __forceinline__ float4 bf4_to_f4(ushort4 u) {
    float4 f;
    f.x = bf_to_f(u.x); f.y = bf_to_f(u.y); f.z = bf_to_f(u.z); f.w = bf_to_f(u.w);
    return f;
}

#if HAVE_FP8
__device__ __forceinline__ float4 fp8x4_to_f4(unsigned u) {
    floatx2 lo = __builtin_amdgcn_cvt_pk_f32_fp8((int)u, false);
    floatx2 hi = __builtin_amdgcn_cvt_pk_f32_fp8((int)u, true);
    float4 f;
    f.x = lo.x; f.y = lo.y; f.z = hi.x; f.w = hi.y;
    return f;
}
__device__ __forceinline__ unsigned f4_to_fp8x4(float a, float b, float c, float d) {
    int pk = 0;
    pk = __builtin_amdgcn_cvt_pk_fp8_f32(a, b, pk, false);
    pk = __builtin_amdgcn_cvt_pk_fp8_f32(c, d, pk, true);
    return (unsigned)pk;
}
#else
__device__ __forceinline__ float4 fp8x4_to_f4(unsigned u) { return make_float4(0, 0, 0, 0); }
__device__ __forceinline__ unsigned f4_to_fp8x4(float a, float b, float c, float d) { return 0; }
#endif

// ---- fused dst/src bucket histograms ----
__global__ void hist2_kernel(const int* __restrict__ row, const int* __restrict__ col,
                             int* __restrict__ gcH, int* __restrict__ gcS,
                             int P, int G, int E) {
    __shared__ int hH[256], hS[256];
    const int tid = threadIdx.x, blk = blockIdx.x;
    hH[tid] = 0; hS[tid] = 0;
    __syncthreads();
    const int start = blk * EPB + tid * 8;
    if (start + 7 < E) {
        const int4 c0 = *(const int4*)(col + start);
        const int4 c1 = *(const int4*)(col + start + 4);
        const int4 r0 = *(const int4*)(row + start);
        const int4 r1 = *(const int4*)(row + start + 4);
        atomicAdd(&hH[c0.x >> BSH], 1); atomicAdd(&hH[c0.y >> BSH], 1);
        atomicAdd(&hH[c0.z >> BSH], 1); atomicAdd(&hH[c0.w >> BSH], 1);
        atomicAdd(&hH[c1.x >> BSH], 1); atomicAdd(&hH[c1.y >> BSH], 1);
        atomicAdd(&hH[c1.z >> BSH], 1); atomicAdd(&hH[c1.w >> BSH], 1);
        atomicAdd(&hS[r0.x >> BSH], 1); atomicAdd(&hS[r0.y >> BSH], 1);
        atomicAdd(&hS[r0.z >> BSH], 1); atomicAdd(&hS[r0.w >> BSH], 1);
        atomicAdd(&hS[r1.x >> BSH], 1); atomicAdd(&hS[r1.y >> BSH], 1);
        atomicAdd(&hS[r1.z >> BSH], 1); atomicAdd(&hS[r1.w >> BSH], 1);
    } else {
        for (int k = start; k < E && k < start + 8; ++k) {
            atomicAdd(&hH[col[k] >> BSH], 1);
            atomicAdd(&hS[row[k] >> BSH], 1);
        }
    }
    __syncthreads();
    if (tid < P) {
        gcH[(size_t)tid * G + blk] = hH[tid];
        gcS[(size_t)tid * G + blk] = hS[tid];
    }
}

__device__ __forceinline__ int4 load_cnt4(const int* __restrict__ cnt, int i, int N) {
    int4 v = make_int4(0, 0, 0, 0);
    if (i + 3 < N) {
        v = *(const int4*)(cnt + i);
    } else {
        if (i + 0 < N) v.x = cnt[i + 0];
        if (i + 1 < N) v.y = cnt[i + 1];
        if (i + 2 < N) v.z = cnt[i + 2];
        if (i + 3 < N) v.w = cnt[i + 3];
    }
    return v;
}

__global__ void scan1_kernel(const int* __restrict__ cnt, int* __restrict__ bsum, int N) {
    const int tid = threadIdx.x;
    const int i = blockIdx.x * SCAN_ELEMS + tid * 4;
    int4 v = load_cnt4(cnt, i, N);
    int s = v.x + v.y + v.z + v.w;
#pragma unroll
    for (int off = 1; off < 64; off <<= 1) s += __shfl_xor(s, off);
    __shared__ int ws[4];
    if ((tid & 63) == 0) ws[tid >> 6] = s;
    __syncthreads();
    if (tid == 0) bsum[blockIdx.x] = ws[0] + ws[1] + ws[2] + ws[3];
}

__global__ void scan2_kernel(const int* __restrict__ bsum, int* __restrict__ boff,
                             int* __restrict__ total_out, int nb) {
    const int tid = threadIdx.x;  // 256
    const int lane = tid & 63, w = tid >> 6;
    int v = (tid < nb) ? bsum[tid] : 0;
    int inc = v;
#pragma unroll
    for (int off = 1; off < 64; off <<= 1) {
        int t = __shfl_up(inc, off);
        if (lane >= off) inc += t;
    }
    __shared__ int wsum[4];
    if (lane == 63) wsum[w] = inc;
    __syncthreads();
    int wo = 0;
    for (int k = 0; k < w; ++k) wo += wsum[k];
    const int excl = wo + inc - v;
    if (tid < nb) boff[tid] = excl;
    if (tid == nb - 1) *total_out = excl + v;
}

__global__ void scan3_kernel(const int* __restrict__ cnt, const int* __restrict__ boff,
                             int* __restrict__ dst, int N) {
    const int tid = threadIdx.x;
    const int lane = tid & 63, w = tid >> 6;
    const int i = blockIdx.x * SCAN_ELEMS + tid * 4;
    int4 v = load_cnt4(cnt, i, N);
    const int s = v.x + v.y + v.z + v.w;
    int inc = s;
#pragma unroll
    for (int off = 1; off < 64; off <<= 1) {
        int t = __shfl_up(inc, off);
        if (lane >= off) inc += t;
    }
    __shared__ int wsum[4];
    if (lane == 63) wsum[w] = inc;
    __syncthreads();
    int wo = 0;
    for (int k = 0; k < w; ++k) wo += wsum[k];
    const int r0 = boff[blockIdx.x] + wo + inc - s;
    const int r1 = r0 + v.x, r2 = r1 + v.y, r3 = r2 + v.z;
    if (i + 3 < N) {
        *(int4*)(dst + i) = make_int4(r0, r1, r2, r3);
    } else {
        if (i + 0 < N) dst[i + 0] = r0;
        if (i + 1 < N) dst[i + 1] = r1;
        if (i + 2 < N) dst[i + 2] = r2;
        if (i + 3 < N) dst[i + 3] = r3;
    }
}

// fused scatter into dst-partitioned (dst,src) pairs AND src-partitioned src list
__global__ void part2_kernel(const int* __restrict__ row, const int* __restrict__ col,
                             const int* __restrict__ goH, const int* __restrict__ goS,
                             int2* __restrict__ partH, int* __restrict__ partS,
                             int P, int G, int E) {
    __shared__ int cH[256], cS[256];
    const int tid = threadIdx.x, blk = blockIdx.x;
    if (tid < P) {
        cH[tid] = goH[(size_t)tid * G + blk];
        cS[tid] = goS[(size_t)tid * G + blk];
    }
    __syncthreads();
    const int start = blk * EPB + tid * 8;
    for (int k = start; k < E && k < start + 8; ++k) {
        const int c = col[k], r = row[k];
        const int posH = atomicAdd(&cH[c >> BSH], 1);
        partH[posH] = make_int2(c, r);
        const int posS = atomicAdd(&cS[r >> BSH], 1);
        partS[posS] = r;
    }
}

// one block per bucket: exact per-node counts/ranks in LDS -> rowptr + final csr
__global__ void bucketC_kernel(const int2* __restrict__ part, const int* __restrict__ goff,
                               int* __restrict__ rowptr, int* __restrict__ csr,
                               int P, int G, int N, int E) {
    __shared__ int cnt[512];
    __shared__ int excl[512];
    __shared__ int wsum[4];
    const int tid = threadIdx.x;  // 256
    const int b = blockIdx.x;
    const int base_node = b << BSH;
    const int nn = min(512, N - base_node);
    const int estart = goff[(size_t)b * G];
    const int eend = (b + 1 < P) ? goff[(size_t)(b + 1) * G] : E;

    cnt[tid] = 0; cnt[tid + 256] = 0;
    __syncthreads();
    for (int i = estart + tid; i < eend; i += 256)
        atomicAdd(&cnt[part[i].x - base_node], 1);
    __syncthreads();
    {
        const int lane = tid & 63, w = tid >> 6;
        const int a0 = cnt[2 * tid], a1 = cnt[2 * tid + 1];
        const int ps = a0 + a1;
        int inc = ps;
#pragma unroll
        for (int off = 1; off < 64; off <<= 1) {
            int t = __shfl_up(inc, off);
            if (lane >= off) inc += t;
        }
        if (lane == 63) wsum[w] = inc;
        __syncthreads();
        int wo = 0;
        for (int k = 0; k < w; ++k) wo += wsum[k];
        const int ep = wo + inc - ps;
        excl[2 * tid] = ep;
        excl[2 * tid + 1] = ep + a0;
    }
    __syncthreads();
    if (tid < nn) rowptr[base_node + tid] = estart + excl[tid];
    for (int ln = 256 + tid; ln < nn; ln += 256) rowptr[base_node + ln] = estart + excl[ln];
    if (b == P - 1 && tid == 0) rowptr[N] = E;
    cnt[tid] = 0; cnt[tid + 256] = 0;
    __syncthreads();
    for (int i = estart + tid; i < eend; i += 256) {
        const int2 e = part[i];
        const int ln = e.x - base_node;
        const int pos = atomicAdd(&cnt[ln], 1);
        csr[estart + excl[ln] + pos] = e.y;
    }
}

// one block per src bucket: out-degree counts in LDS -> dinv/dinv2/rdinv
__global__ void bucketD_kernel(const int* __restrict__ partS, const int* __restrict__ goffS,
                               float* __restrict__ dinv, float* __restrict__ dinv2,
                               float* __restrict__ rdinv, int P, int G, int N, int E) {
    __shared__ int cnt[512];
    const int tid = threadIdx.x;  // 256
    const int b = blockIdx.x;
    const int base_node = b << BSH;
    const int nn = min(512, N - base_node);
    const int estart = goffS[(size_t)b * G];
    const int eend = (b + 1 < P) ? goffS[(size_t)(b + 1) * G] : E;
    cnt[tid] = 0; cnt[tid + 256] = 0;
    __syncthreads();
    for (int i = estart + tid; i < eend; i += 256)
        atomicAdd(&cnt[partS[i] - base_node], 1);
    __syncthreads();
    for (int l = tid; l < nn; l += 256) {
        const int dI = cnt[l];
        const float d = (float)dI;
        const bool ok = dI > 0;
        dinv[base_node + l]  = ok ? rsqrtf(d) : 0.0f;
        dinv2[base_node + l] = ok ? 1.0f / d : 0.0f;
        rdinv[base_node + l] = ok ? sqrtf(d) : 0.0f;
    }
}

// S0 = bf16(dinv (.) x) [+ fp8 copy], vectorized
__global__ void init_s0_kernel(const float* __restrict__ dinv, const float* __restrict__ x,
                               unsigned short* __restrict__ S0b, unsigned char* __restrict__ S0f8,
                               int NF, int write8) {
    int i = blockIdx.x * blockDim.x + threadIdx.x;
    int j = i * 4;
    if (j >= NF) return;
    const float dv = dinv[j >> 6];
    const float4 v = *(const float4*)(x + j);
    const float a = dv * v.x, bb = dv * v.y, c = dv * v.z, d = dv * v.w;
    ushort4 u;
    u.x = f_to_bf(a); u.y = f_to_bf(bb); u.z = f_to_bf(c); u.w = f_to_bf(d);
    *(ushort4*)(S0b + j) = u;
    if (write8) *(unsigned*)(S0f8 + j) = f4_to_fp8x4(a, bb, c, d);
}

// ---- Path B prop: bf16 gather (R11) ----
template <int FIRST>
__global__ __launch_bounds__(256, 8)
void prop_g4(const int* __restrict__ rowptr, const int* __restrict__ csr,
             const float* __restrict__ dinv2, const unsigned short* __restrict__ Sprev,
             const unsigned short* __restrict__ Sm2, unsigned short* __restrict__ Sk, int N) {
    const int lane = threadIdx.x & 63;
    const int g16 = lane & 48;
    const int fl = lane & 15;
    const int wave = threadIdx.x >> 6;
    const int wbase = (blockIdx.x * 4 + wave) * PNPW;
    for (int j = 0; j < PNPW; j += 4) {
        const int n = wbase + j + (g16 >> 4);
        const bool nv = n < N;
        const int nc = nv ? n : N - 1;
        const int s = rowptr[nc], e = rowptr[nc + 1];
        const int len = e - s;
        float4 acc = {0.f, 0.f, 0.f, 0.f};
        for (int c = 0; c < len; c += 16) {
            const int ii = s + c + fl;
            const int idxv = csr[ii < e ? ii : e - 1];
            const int mm = min(16, len - c);
            for (int jj = 0; jj < mm; jj += 4) {
                const int i0 = __shfl(idxv, g16 + jj + 0);
                const int i1 = __shfl(idxv, g16 + jj + 1);
                const int i2 = __shfl(idxv, g16 + jj + 2);
                const int i3 = __shfl(idxv, g16 + jj + 3);
                const ushort4 u0 = *(const ushort4*)(Sprev + (size_t)i0 * F + fl * 4);
                const ushort4 u1 = *(const ushort4*)(Sprev + (size_t)i1 * F + fl * 4);
                const ushort4 u2 = *(const ushort4*)(Sprev + (size_t)i2 * F + fl * 4);
                const ushort4 u3 = *(const ushort4*)(Sprev + (size_t)i3 * F + fl * 4);
                {
                    const float4 v = bf4_to_f4(u0);
                    acc.x += v.x; acc.y += v.y; acc.z += v.z; acc.w += v.w;
                }
                if (jj + 1 < mm) {
                    const float4 v = bf4_to_f4(u1);
                    acc.x += v.x; acc.y += v.y; acc.z += v.z; acc.w += v.w;
                }
                if (jj + 2 < mm) {
                    const float4 v = bf4_to_f4(u2);
                    acc.x += v.x; acc.y += v.y; acc.z += v.z; acc.w += v.w;
                }
                if (jj + 3 < mm) {
                    const float4 v = bf4_to_f4(u3);
                    acc.x += v.x; acc.y += v.y; acc.z += v.z; acc.w += v.w;
                }
            }
        }
        if (nv) {
            const float d2 = dinv2[n];
            float4 sn;
            if (FIRST) {
                sn.x = -d2 * acc.x; sn.y = -d2 * acc.y;
                sn.z = -d2 * acc.z; sn.w = -d2 * acc.w;
            } else {
                const float4 m2 = bf4_to_f4(*(const ushort4*)(Sm2 + (size_t)n * F + fl * 4));
                sn.x = -2.f * d2 * acc.x - m2.x; sn.y = -2.f * d2 * acc.y - m2.y;
                sn.z = -2.f * d2 * acc.z - m2.z; sn.w = -2.f * d2 * acc.w - m2.w;
            }
            ushort4 o;
            o.x = f_to_bf(sn.x); o.y = f_to_bf(sn.y);
            o.z = f_to_bf(sn.z); o.w = f_to_bf(sn.w);
            *(ushort4*)(Sk + (size_t)n * F + fl * 4) = o;
        }
    }
}

// ---- Path A prop: fp8 gather, bf16 state; writes bf16 (+ optional fp8 copy) ----
template <int FIRST, int W8>
__global__ __launch_bounds__(256, 8)
void prop_f8(const int* __restrict__ rowptr, const int* __restrict__ csr,
             const float* __restrict__ dinv2, const unsigned char* __restrict__ S8prev,
             const unsigned short* __restrict__ Sm2, unsigned short* __restrict__ Sk,
             unsigned char* __restrict__ Sk8, int N) {
    const int lane = threadIdx.x & 63;
    const int g16 = lane & 48;
    const int fl = lane & 15;
    const int wave = threadIdx.x >> 6;
    const int wbase = (blockIdx.x * 4 + wave) * PNPW;
    for (int j = 0; j < PNPW; j += 4) {
        const int n = wbase + j + (g16 >> 4);
        const bool nv = n < N;
        const int nc = nv ? n : N - 1;
        const int s = rowptr[nc], e = rowptr[nc + 1];
        const int len = e - s;
        float4 acc = {0.f, 0.f, 0.f, 0.f};
        for (int c = 0; c < len; c += 16) {
            const int ii = s + c + fl;
            const int idxv = csr[ii < e ? ii : e - 1];
            const int mm = min(16, len - c);
            for (int jj = 0; jj < mm; jj += 4) {
                const int i0 = __shfl(idxv, g16 + jj + 0);
                const int i1 = __shfl(idxv, g16 + jj + 1);
                const int i2 = __shfl(idxv, g16 + jj + 2);
                const int i3 = __shfl(idxv, g16 + jj + 3);
                const unsigned u0 = *(const unsigned*)(S8prev + (size_t)i0 * F + fl * 4);
                const unsigned u1 = *(const unsigned*)(S8prev + (size_t)i1 * F + fl * 4);
                const unsigned u2 = *(const unsigned*)(S8prev + (size_t)i2 * F + fl * 4);
                const unsigned u3 = *(const unsigned*)(S8prev + (size_t)i3 * F + fl * 4);
                {
                    const float4 v = fp8x4_to_f4(u0);
                    acc.x += v.x; acc.y += v.y; acc.z += v.z; acc.w += v.w;
                }
                if (jj + 1 < mm) {
                    const float4 v = fp8x4_to_f4(u1);
                    acc.x += v.x; acc.y += v.y; acc.z += v.z; acc.w += v.w;
                }
                if (jj + 2 < mm) {
                    const float4 v = fp8x4_to_f4(u2);
                    acc.x += v.x; acc.y += v.y; acc.z += v.z; acc.w += v.w;
                }
                if (jj + 3 < mm) {
                    const float4 v = fp8x4_to_f4(u3);
                    acc.x += v.x; acc.y += v.y; acc.z += v.z; acc.w += v.w;
                }
            }
        }
        if (nv) {
            const float d2 = dinv2[n];
            float4 sn;
            if (FIRST) {
                sn.x = -d2 * acc.x; sn.y = -d2 * acc.y;
                sn.z = -d2 * acc.z; sn.w = -d2 * acc.w;
            } else {
                const float4 m2 = bf4_to_f4(*(const ushort4*)(Sm2 + (size_t)n * F + fl * 4));
                sn.x = -2.f * d2 * acc.x - m2.x; sn.y = -2.f * d2 * acc.y - m2.y;
                sn.z = -2.f * d2 * acc.z - m2.z; sn.w = -2.f * d2 * acc.w - m2.w;
            }
            ushort4 o;
            o.x = f_to_bf(sn.x); o.y = f_to_bf(sn.y);
            o.z = f_to_bf(sn.z); o.w = f_to_bf(sn.w);
            *(ushort4*)(Sk + (size_t)n * F + fl * 4) = o;
            if (W8) *(unsigned*)(Sk8 + (size_t)n * F + fl * 4) = f4_to_fp8x4(sn.x, sn.y, sn.z, sn.w);
        }
    }
}

// Pre-swizzle bf16(W) into MFMA B-fragment order.
__global__ void wfrag_kernel(const float* __restrict__ W, unsigned short* __restrict__ Wfrag) {
    const int idx = blockIdx.x * blockDim.x + threadIdx.x;  // 3072 entries
    if (idx >= 4 * 12 * 64) return;
    const int lane = idx & 63;
    const int s = (idx >> 6) % 12;
    const int ft = idx / (64 * 12);
    const int n = ft * 16 + (lane & 15);
    const int quad = lane >> 4;
    unsigned short v[8];
#pragma unroll
    for (int j = 0; j < 8; ++j) {
        const int kg = s * 32 + quad * 8 + j;
        const int kk = kg >> 6, f = kg & 63;
        v[j] = f_to_bf(W[kk * F * F + f * F + n]);
    }
    ushort4 lo = {v[0], v[1], v[2], v[3]};
    ushort4 hi = {v[4], v[5], v[6], v[7]};
    *(ushort4*)(Wfrag + (size_t)idx * 8) = lo;
    *(ushort4*)(Wfrag + (size_t)idx * 8 + 4) = hi;
}

// out = relu(b + rdinv (.) sum_{k=0..5} Sk@Wk)   [x@W0 folded: x = rdinv*S0]
// deg-0 fixup: out = relu(b + x@(W0 - W2 + W4)).
__global__ __launch_bounds__(256, 4)
void mfma_out_kernel(const float* __restrict__ x, const unsigned short* __restrict__ Sstack,
                     const unsigned short* __restrict__ Wfrag, const float* __restrict__ rdinv,
                     const float* __restrict__ dinv2, const float* __restrict__ W,
                     const float* __restrict__ b, float* __restrict__ out, int N, int NF) {
    const int lane = threadIdx.x & 63;
    const int wave = threadIdx.x >> 6;      // feature tile
    const int quad = lane >> 4;
    const int tm = blockIdx.x * 16;
    const int ma = tm + (lane & 15);
    const int mac = ma < N ? ma : N - 1;

    floatx4 C = {0.f, 0.f, 0.f, 0.f};
    const unsigned short* wf = Wfrag + ((size_t)(wave * 12) * 64 + lane) * 8;
    const unsigned short* sa = Sstack + (size_t)mac * F + quad * 8;

#pragma unroll
    for (int s = 0; s < 12; ++s) {
        const int kk = s >> 1, f0 = (s & 1) * 32;
        const short8 A = *(const short8*)(sa + (size_t)kk * NF + f0);
        const short8 B = *(const short8*)(wf + (size_t)s * 64 * 8);
        C = __builtin_amdgcn_mfma_f32_16x16x32_bf16(A, B, C, 0, 0, 0);
    }

    const int n = wave * 16 + (lane & 15);
    const float bl = b[n];
#pragma unroll
    for (int r = 0; r < 4; ++r) {
        const int m = tm + quad * 4 + r;
        if (m >= N) continue;
        float v = rdinv[m] * C[r];
        if (dinv2[m] == 0.0f) {  // rare deg-0 rows: out = b + x@(W0 - W2 + W4)
            const float* xr = x + (size_t)m * F;
            float fx = 0.f;
            for (int f = 0; f < F; ++f)
                fx += xr[f] * (W[0 * F * F + f * F + n] - W[2 * F * F + f * F + n] +
                               W[4 * F * F + f * F + n]);
            v = fx;
        }
        out[(size_t)m * F + n] = fmaxf(v + bl, 0.f);
    }
}

extern "C" void kernel_launch(void* const* d_in, const int* in_sizes, int n_in,
                              void* d_out, int out_size, void* d_ws, size_t ws_size,
                              hipStream_t stream) {
    const float* x = (const float*)d_in[0];
    const int* ei = (const int*)d_in[1];
    const float* W = (const float*)d_in[2];
    const float* b = (const float*)d_in[3];

    const int N = in_sizes[0] / F;
    const int E = in_sizes[1] / 2;
    const int NF = N * F;
    const int* row = ei;      // sources j
    const int* col = ei + E;  // targets i

    const int P = (N + 511) >> BSH;           // buckets (<=256 for N<=131072)
    const int G = (E + EPB - 1) / EPB;        // partition blocks
    const int M = P * G;                      // scan length

    // workspace allocator (64B-aligned chunks)
    char* p = (char*)d_ws;
    auto alloc = [&](size_t bytes) {
        char* r = p;
        p += (bytes + 63) & ~(size_t)63;
        return r;
    };
    float* dinv   = (float*)alloc((size_t)N * sizeof(float));
    float* dinv2  = (float*)alloc((size_t)N * sizeof(float));
    float* rdinv  = (float*)alloc((size_t)N * sizeof(float));
    int*   rowptr = (int*)alloc((size_t)(N + 1) * sizeof(int));
    int*   bsum   = (int*)alloc(256 * sizeof(int));
    int*   boff   = (int*)alloc(256 * sizeof(int));
    int*   totS   = (int*)alloc(64);
    int*   gcH    = (int*)alloc((size_t)M * sizeof(int));
    int*   goH    = (int*)alloc((size_t)M * sizeof(int));
    int*   gcS    = (int*)alloc((size_t)M * sizeof(int));
    int*   goS    = (int*)alloc((size_t)M * sizeof(int));
    int*   csr    = (int*)alloc((size_t)E * sizeof(int));
    unsigned short* Sstack = (unsigned short*)alloc((size_t)6 * NF * sizeof(unsigned short));
    unsigned short* Wfrag  = (unsigned short*)alloc((size_t)4 * 12 * 64 * 8 * sizeof(unsigned short));
    unsigned char* F8A = (unsigned char*)alloc((size_t)NF);   // fp8 ping
    unsigned char* F8B = (unsigned char*)alloc((size_t)NF);   // fp8 pong
    const size_t needed = (size_t)(p - (char*)d_ws);
    const bool pathA = HAVE_FP8 && ws_size >= needed;
    // partH (E int2) aliases S0 (dead before init_s0); partS (E int) aliases S1.
    int2* partH = (int2*)Sstack;
    int*  partS = (int*)(Sstack + (size_t)NF);
    float* out = (float*)d_out;

    const int B = 256;
    const int nsbM = (M + SCAN_ELEMS - 1) / SCAN_ELEMS;  // <=256 required
    const int pgrid = (N + 4 * PNPW - 1) / (4 * PNPW);   // 4 waves/block

    hist2_kernel<<<G, B, 0, stream>>>(row, col, gcH, gcS, P, G, E);
    scan1_kernel<<<nsbM, B, 0, stream>>>(gcH, bsum, M);
    scan2_kernel<<<1, B, 0, stream>>>(bsum, boff, rowptr + N, nsbM);  // total == E
    scan3_kernel<<<nsbM, B, 0, stream>>>(gcH, boff, goH, M);
    scan1_kernel<<<nsbM, B, 0, stream>>>(gcS, bsum, M);
    scan2_kernel<<<1, B, 0, stream>>>(bsum, boff, totS, nsbM);
    scan3_kernel<<<nsbM, B, 0, stream>>>(gcS, boff, goS, M);
    part2_kernel<<<G, B, 0, stream>>>(row, col, goH, goS, partH, partS, P, G, E);
    bucketC_kernel<<<P, B, 0, stream>>>(partH, goH, rowptr, csr, P, G, N, E);
    bucketD_kernel<<<P, B, 0, stream>>>(partS, goS, dinv, dinv2, rdinv, P, G, N, E);

    wfrag_kernel<<<(4 * 12 * 64 + B - 1) / B, B, 0, stream>>>(W, Wfrag);
    init_s0_kernel<<<(NF / 4 + B - 1) / B, B, 0, stream>>>(dinv, x, Sstack, F8A, NF,
                                                           pathA ? 1 : 0);
    unsigned short* S1 = Sstack + (size_t)1 * NF;
    unsigned short* S2 = Sstack + (size_t)2 * NF;
    unsigned short* S3 = Sstack + (size_t)3 * NF;
    unsigned short* S4 = Sstack + (size_t)4 * NF;
    unsigned short* S5 = Sstack + (size_t)5 * NF;
    if (pathA) {
        prop_f8<1, 1><<<pgrid, B, 0, stream>>>(rowptr, csr, dinv2, F8A, Sstack, S1, F8B, N);
        prop_f8<0, 1><<<pgrid, B, 0, stream>>>(rowptr, csr, dinv2, F8B, Sstack, S2, F8A, N);
        prop_f8<0, 1><<<pgrid, B, 0, stream>>>(rowptr, csr, dinv2, F8A, S1, S3, F8B, N);
        prop_f8<0, 1><<<pgrid, B, 0, stream>>>(rowptr, csr, dinv2, F8B, S2, S4, F8A, N);
        prop_f8<0, 0><<<pgrid, B, 0, stream>>>(rowptr, csr, dinv2, F8A, S3, S5, F8B, N);
    } else {
        prop_g4<1><<<pgrid, B, 0, stream>>>(rowptr, csr, dinv2, Sstack, Sstack, S1, N);
        prop_g4<0><<<pgrid, B, 0, stream>>>(rowptr, csr, dinv2, S1, Sstack, S2, N);
        prop_g4<0><<<pgrid, B, 0, stream>>>(rowptr, csr, dinv2, S2, S1, S3, N);
        prop_g4<0><<<pgrid, B, 0, stream>>>(rowptr, csr, dinv2, S3, S2, S4, N);
        prop_g4<0><<<pgrid, B, 0, stream>>>(rowptr, csr, dinv2, S4, S3, S5, N);
    }
    mfma_out_kernel<<<(N + 15) / 16, 256, 0, stream>>>(x, Sstack, Wfrag, rdinv, dinv2,
                                                       W, b, out, N, NF);
}